// Round 8
// baseline (1628.524 us; speedup 1.0000x reference)
//
#include <hip/hip_runtime.h>
#include <math.h>

// ---------------------------------------------------------------------------
// Round 8: 8-phase 256x256x64 GEMM (m201 template): 4 phases/K-tile, 16 MFMA
// per phase, 1 half-tile stage per phase 3-deep, counted vmcnt(6) at phase
// ends (never 0 in steady state), setprio around MFMA clusters.
// ---------------------------------------------------------------------------

namespace {
constexpr int S_   = 4096;
constexpr int D_   = 1536;
constexpr int H_   = 12;
constexpr int L_   = 512;
constexpr int TOPK = 8;
constexpr int FF_  = 8960;
constexpr float EPS_   = 1e-6f;
constexpr float SCALE_ = 0.08838834764831845f;   // 128^-0.5
}

typedef __attribute__((ext_vector_type(8))) short short8;
typedef __attribute__((ext_vector_type(4))) float f32x4;

#define AS_GLOBAL __attribute__((address_space(1)))
#define AS_LDS    __attribute__((address_space(3)))

__device__ __forceinline__ short f2bf(float x) {
    uint32_t u = __float_as_uint(x);
    uint32_t r = (u + 0x7FFFu + ((u >> 16) & 1u)) >> 16;
    return (short)r;
}
__device__ __forceinline__ float bf2f(short s) {
    return __uint_as_float(((uint32_t)(uint16_t)s) << 16);
}
__device__ __forceinline__ float gelu_tanh(float x) {
    const float t = tanhf(0.7978845608028654f * (x + 0.044715f * x * x * x));
    return 0.5f * x * (1.f + t);
}

// ---------------------------- reductions -----------------------------------
__device__ __forceinline__ float block_sum_256(float v, float* red) {
#pragma unroll
    for (int off = 32; off > 0; off >>= 1) v += __shfl_down(v, off, 64);
    const int lane = threadIdx.x & 63, w = threadIdx.x >> 6;
    if (lane == 0) red[w] = v;
    __syncthreads();
    v = red[0] + red[1] + red[2] + red[3];
    __syncthreads();
    return v;
}

// ================= 8-phase 256x256x64 8-wave MFMA GEMM =====================
// C(M,N) = A(M,K) @ Bt(N,K)^T. 512 thr; waves: wm=wid>>2 (2 M-halves of 128
// rows), wn=wid&3 (4 N-quarters of 64). Per-wave 128x64 out, acc[8][4].
// LDS: As/Bs[buf*2+half][128*64] bf16, 4 x 16KB each = 128 KB total.
// K-tile t lives in buf t&1. Per tile, 4 phases (C-quadrant snake
// Q00,Q01,Q11,Q10; 16 MFMA each):
//  ph1: read a0(8)+b0(4); stage (t+1).B0 ; bar; lgkm0; MFMA; vmcnt(6); bar
//  ph2: read b1(4)      ; stage (t+1).B1 ; bar; lgkm0; MFMA; vmcnt(6); bar
//  ph3: read a1(8)      ; stage (t+1).A1 ; bar; lgkm0; MFMA;            bar
//  ph4:                 ; stage (t+2).A0 ; bar;        MFMA; vmcnt(6); bar
// Stage order A0@(t-2)p4, B0@(t-1)p1, B1@(t-1)p2, A1@(t-1)p3 gives exactly
// 3 half-tiles (6 loads/thread) outstanding at each vmcnt point; a region is
// re-staged only >=1 barrier after its last ds_read. Tail (t+2>=nk): vmcnt(0).
// Unit swizzle u_phys = u ^ (row&7), both-sides (pre-swizzled global source).
// EPI: 0 C=acc+bias ; 1 C+=acc ; 2 Cb=bf16(gelu(acc+bias)) ; 3 Cb=bf16(acc+b)
//      4 fused QKVG (N=6144): seg 0,1 -> f32 C+seg*SD ; seg 2,3 -> bf16 Cb
//      5 corr: A=Nb,Alo=Nlo; B k<1536 -> {Wql|Wkl}, k>=1536 -> {Wqh|Wkh};
//              row stride 1536; C(:,seg) += acc (seg = col>=1536)
template <int EPI>
__global__ __launch_bounds__(512, 2) void gemm8p(
    const short* __restrict__ A, const short* __restrict__ Bt,
    const float* __restrict__ bias, float* __restrict__ C,
    short* __restrict__ Cb, int M, int N, int K,
    const short* __restrict__ Alo, const short* __restrict__ B2,
    const short* __restrict__ B3, const short* __restrict__ B4)
{
    __shared__ __align__(16) short As[4][128 * 64];
    __shared__ __align__(16) short Bs[4][128 * 64];
    const int tid = threadIdx.x;
    const int wid = tid >> 6, lane = tid & 63;
    const int wm = wid >> 2, wn = wid & 3;
    const int g16 = lane >> 4, l15 = lane & 15;

    // bijective XCD swizzle
    const int nwg = gridDim.x * gridDim.y;
    const int bid = blockIdx.y * gridDim.x + blockIdx.x;
    const int qq = nwg >> 3, r8 = nwg & 7;
    const int xcd = bid & 7, lid = bid >> 3;
    const int swz = ((xcd < r8) ? xcd * (qq + 1) : r8 * (qq + 1) + (xcd - r8) * qq) + lid;
    const int m0 = (swz / gridDim.x) * 256, n0 = (swz % gridDim.x) * 256;
    const int nseg = (n0 >= 1536) ? 1 : 0;       // EPI5 only

    f32x4 acc[8][4];
#pragma unroll
    for (int i = 0; i < 8; i++)
#pragma unroll
        for (int j = 0; j < 4; j++) acc[i][j] = (f32x4){0.f, 0.f, 0.f, 0.f};

    int sr[2], su[2];
#pragma unroll
    for (int i = 0; i < 2; i++) {
        const int u = tid + 512 * i;
        sr[i] = u >> 3;
        su[i] = (u & 7) ^ (sr[i] & 7);
    }

    const int lda = (EPI == 5) ? 1536 : K;
    auto STAGEA = [&](int buf, int half, int kt) {
        const short* src = A;
        int kl = kt;
        if (EPI == 5) { const int ks = (kt >= 1536); src = ks ? Alo : A; kl = kt - ks * 1536; }
#pragma unroll
        for (int i = 0; i < 2; i++) {
            const int u = tid + 512 * i;
            __builtin_amdgcn_global_load_lds(
                (const AS_GLOBAL short*)(src + (size_t)(m0 + half * 128 + sr[i]) * lda + kl + su[i] * 8),
                (AS_LDS short*)(&As[buf * 2 + half][u * 8]), 16, 0, 0);
        }
    };
    auto STAGEB = [&](int buf, int half, int kt) {
        const short* src = Bt;
        int kl = kt, nb = n0;
        if (EPI == 5) {
            const int ks = (kt >= 1536);
            src = nseg ? (ks ? B4 : B3) : (ks ? B2 : Bt);
            kl = kt - ks * 1536;
            nb = n0 - nseg * 1536;
        }
#pragma unroll
        for (int i = 0; i < 2; i++) {
            const int u = tid + 512 * i;
            __builtin_amdgcn_global_load_lds(
                (const AS_GLOBAL short*)(src + (size_t)(nb + half * 128 + sr[i]) * lda + kl + su[i] * 8),
                (AS_LDS short*)(&Bs[buf * 2 + half][u * 8]), 16, 0, 0);
        }
    };

    const int nk = K >> 6;
    // prologue: t0.{A0,B0,B1,A1}, t1.A0  (issue order = steady-state order)
    STAGEA(0, 0, 0); STAGEB(0, 0, 0); STAGEB(0, 1, 0); STAGEA(0, 1, 0);
    if (nk > 1) STAGEA(1, 0, 64);
    asm volatile("s_waitcnt vmcnt(6)" ::: "memory");
    __builtin_amdgcn_s_barrier();

    short8 a0[4][2], a1[4][2], b0[2][2], b1[2][2];

    for (int t = 0; t < nk; ++t) {
        const int p = t & 1, pn = p ^ 1;
        const int kt1 = (t + 1) << 6, kt2 = (t + 2) << 6;
        const bool s1 = (t + 1 < nk), s2 = (t + 2 < nk);
        const short* Ah = &As[p * 2 + wm][0];
        const short* Bh = &Bs[p * 2 + (wn >> 1)][0];
        const int br = (wn & 1) * 64;

        // ---------------- phase 1: Q(0,0) ----------------
#pragma unroll
        for (int mi = 0; mi < 4; mi++)
#pragma unroll
            for (int kk = 0; kk < 2; kk++) {
                const int row = mi * 16 + l15;
                a0[mi][kk] = *(const short8*)(Ah + row * 64 + (((kk * 4 + g16) ^ (row & 7)) * 8));
            }
#pragma unroll
        for (int ni = 0; ni < 2; ni++)
#pragma unroll
            for (int kk = 0; kk < 2; kk++) {
                const int row = br + ni * 16 + l15;
                b0[ni][kk] = *(const short8*)(Bh + row * 64 + (((kk * 4 + g16) ^ (row & 7)) * 8));
            }
        if (s1) STAGEB(pn, 0, kt1);
        __builtin_amdgcn_s_barrier();
        asm volatile("s_waitcnt lgkmcnt(0)" ::: "memory");
        __builtin_amdgcn_sched_barrier(0);
        __builtin_amdgcn_s_setprio(1);
#pragma unroll
        for (int mi = 0; mi < 4; mi++)
#pragma unroll
            for (int ni = 0; ni < 2; ni++)
#pragma unroll
                for (int kk = 0; kk < 2; kk++)
                    acc[mi][ni] = __builtin_amdgcn_mfma_f32_16x16x32_bf16(
                        a0[mi][kk], b0[ni][kk], acc[mi][ni], 0, 0, 0);
        __builtin_amdgcn_s_setprio(0);
        if (s2) asm volatile("s_waitcnt vmcnt(6)" ::: "memory");
        else    asm volatile("s_waitcnt vmcnt(0)" ::: "memory");
        __builtin_amdgcn_s_barrier();

        // ---------------- phase 2: Q(0,1) ----------------
#pragma unroll
        for (int ni = 0; ni < 2; ni++)
#pragma unroll
            for (int kk = 0; kk < 2; kk++) {
                const int row = br + 32 + ni * 16 + l15;
                b1[ni][kk] = *(const short8*)(Bh + row * 64 + (((kk * 4 + g16) ^ (row & 7)) * 8));
            }
        if (s1) STAGEB(pn, 1, kt1);
        __builtin_amdgcn_s_barrier();
        asm volatile("s_waitcnt lgkmcnt(0)" ::: "memory");
        __builtin_amdgcn_sched_barrier(0);
        __builtin_amdgcn_s_setprio(1);
#pragma unroll
        for (int mi = 0; mi < 4; mi++)
#pragma unroll
            for (int ni = 0; ni < 2; ni++)
#pragma unroll
                for (int kk = 0; kk < 2; kk++)
                    acc[mi][2 + ni] = __builtin_amdgcn_mfma_f32_16x16x32_bf16(
                        a0[mi][kk], b1[ni][kk], acc[mi][2 + ni], 0, 0, 0);
        __builtin_amdgcn_s_setprio(0);
        if (s2) asm volatile("s_waitcnt vmcnt(6)" ::: "memory");
        else    asm volatile("s_waitcnt vmcnt(0)" ::: "memory");
        __builtin_amdgcn_s_barrier();

        // ---------------- phase 3: Q(1,1) ----------------
#pragma unroll
        for (int mi = 0; mi < 4; mi++)
#pragma unroll
            for (int kk = 0; kk < 2; kk++) {
                const int row = 64 + mi * 16 + l15;
                a1[mi][kk] = *(const short8*)(Ah + row * 64 + (((kk * 4 + g16) ^ (row & 7)) * 8));
            }
        if (s1) STAGEA(pn, 1, kt1);
        __builtin_amdgcn_s_barrier();
        asm volatile("s_waitcnt lgkmcnt(0)" ::: "memory");
        __builtin_amdgcn_sched_barrier(0);
        __builtin_amdgcn_s_setprio(1);
#pragma unroll
        for (int mi = 0; mi < 4; mi++)
#pragma unroll
            for (int ni = 0; ni < 2; ni++)
#pragma unroll
                for (int kk = 0; kk < 2; kk++)
                    acc[4 + mi][2 + ni] = __builtin_amdgcn_mfma_f32_16x16x32_bf16(
                        a1[mi][kk], b1[ni][kk], acc[4 + mi][2 + ni], 0, 0, 0);
        __builtin_amdgcn_s_setprio(0);
        __builtin_amdgcn_s_barrier();

        // ---------------- phase 4: Q(1,0) ----------------
        if (s2) STAGEA(p, 0, kt2);          // tile t+2 -> buf p (A0 read done ph1)
        __builtin_amdgcn_s_barrier();
        __builtin_amdgcn_s_setprio(1);
#pragma unroll
        for (int mi = 0; mi < 4; mi++)
#pragma unroll
            for (int ni = 0; ni < 2; ni++)
#pragma unroll
                for (int kk = 0; kk < 2; kk++)
                    acc[4 + mi][ni] = __builtin_amdgcn_mfma_f32_16x16x32_bf16(
                        a1[mi][kk], b0[ni][kk], acc[4 + mi][ni], 0, 0, 0);
        __builtin_amdgcn_s_setprio(0);
        if (s1) {
            if (s2) asm volatile("s_waitcnt vmcnt(6)" ::: "memory");
            else    asm volatile("s_waitcnt vmcnt(0)" ::: "memory");
            __builtin_amdgcn_s_barrier();
        }
    }

    const size_t SD = (size_t)S_ * D_;
#pragma unroll
    for (int mi = 0; mi < 8; mi++) {
#pragma unroll
        for (int ni = 0; ni < 4; ni++) {
            const int col = n0 + wn * 64 + ni * 16 + l15;
            const float bv = (EPI == 1 || EPI == 5) ? 0.f : bias[col];
#pragma unroll
            for (int rr = 0; rr < 4; rr++) {
                const int row = m0 + wm * 128 + mi * 16 + g16 * 4 + rr;
                float v = acc[mi][ni][rr];
                if (EPI == 4) {
                    const int seg = col / 1536, cl = col - seg * 1536;
                    const float y = v + bv;
                    if (seg < 2) C[(size_t)seg * SD + (size_t)row * 1536 + cl] = y;
                    else Cb[(size_t)(seg - 2) * SD + (size_t)row * 1536 + cl] = f2bf(y);
                } else if (EPI == 5) {
                    const int seg = (col >= 1536) ? 1 : 0, cl = col - seg * 1536;
                    C[(size_t)seg * SD + (size_t)row * 1536 + cl] += v;
                } else {
                    const size_t o = (size_t)row * N + col;
                    if (EPI == 0) C[o] = v + bv;
                    else if (EPI == 1) C[o] += v;
                    else if (EPI == 2) Cb[o] = f2bf(gelu_tanh(v + bv));
                    else Cb[o] = f2bf(v + bv);
                }
            }
        }
    }
}

// ---------------------- weight transpose / convert -------------------------
template <int SPLIT>
__global__ __launch_bounds__(256) void transpose_w(
    const float* __restrict__ W, short* __restrict__ Th, short* __restrict__ Tl,
    int Kd, int Nd)
{
    __shared__ float tile[64][65];
    const int k0 = blockIdx.y * 64, n0 = blockIdx.x * 64;
    for (int f = threadIdx.x; f < 1024; f += 256) {
        const int rr = f >> 4, c4 = (f & 15) * 4;
        const float4 v = *(const float4*)(W + (size_t)(k0 + rr) * Nd + n0 + c4);
        tile[rr][c4 + 0] = v.x; tile[rr][c4 + 1] = v.y;
        tile[rr][c4 + 2] = v.z; tile[rr][c4 + 3] = v.w;
    }
    __syncthreads();
    for (int f = threadIdx.x; f < 1024; f += 256) {
        const int nn = f >> 4, k4 = (f & 15) * 4;
        short4 hv, lv;
        float w0 = tile[k4 + 0][nn], w1 = tile[k4 + 1][nn];
        float w2 = tile[k4 + 2][nn], w3 = tile[k4 + 3][nn];
        hv.x = f2bf(w0); hv.y = f2bf(w1); hv.z = f2bf(w2); hv.w = f2bf(w3);
        *(short4*)(Th + (size_t)(n0 + nn) * Kd + k0 + k4) = hv;
        if (SPLIT) {
            lv.x = f2bf(w0 - bf2f(hv.x)); lv.y = f2bf(w1 - bf2f(hv.y));
            lv.z = f2bf(w2 - bf2f(hv.z)); lv.w = f2bf(w3 - bf2f(hv.w));
            *(short4*)(Tl + (size_t)(n0 + nn) * Kd + k0 + k4) = lv;
        }
    }
}

__global__ void cvt_bf16_kernel(const float* __restrict__ x, short* __restrict__ y, int n4)
{
    const int i = blockIdx.x * 256 + threadIdx.x;
    if (i >= n4) return;
    const float4 v = *(const float4*)(x + (size_t)i * 4);
    short4 o; o.x = f2bf(v.x); o.y = f2bf(v.y); o.z = f2bf(v.z); o.w = f2bf(v.w);
    *(short4*)(y + (size_t)i * 4) = o;
}

__global__ void fill_bcat(const float* __restrict__ bq, const float* __restrict__ bk,
                          const float* __restrict__ bv, const float* __restrict__ bg,
                          float* __restrict__ bcat)
{
    const int i = blockIdx.x * 256 + threadIdx.x;
    if (i >= 6144) return;
    const int seg = i / 1536, c = i - seg * 1536;
    const float* src = (seg == 0) ? bq : (seg == 1) ? bk : (seg == 2) ? bv : bg;
    bcat[i] = src[c];
}

// --------------------- LayerNorm (bf16 out, optional split) -----------------
template <int ADD1, int SPLIT>
__global__ __launch_bounds__(256) void ln_bf16(
    const float* __restrict__ x, short* __restrict__ hi, short* __restrict__ lo,
    const float* __restrict__ g, const float* __restrict__ b)
{
    __shared__ float red[4];
    const size_t s = blockIdx.x;
    const float* xr = x + s * D_;
    float v[6];
    float sm = 0.f;
#pragma unroll
    for (int i = 0; i < 6; i++) { v[i] = xr[threadIdx.x + 256 * i]; sm += v[i]; }
    sm = block_sum_256(sm, red);
    const float mean = sm * (1.f / D_);
    float vs = 0.f;
#pragma unroll
    for (int i = 0; i < 6; i++) { const float d = v[i] - mean; vs += d * d; }
    vs = block_sum_256(vs, red);
    const float rs = rsqrtf(vs * (1.f / D_) + EPS_);
#pragma unroll
    for (int i = 0; i < 6; i++) {
        const int d = threadIdx.x + 256 * i;
        const float y = (v[i] - mean) * rs * (g[d] + (float)ADD1) + b[d];
        const short h = f2bf(y);
        hi[s * D_ + d] = h;
        if (SPLIT) lo[s * D_ + d] = f2bf(y - bf2f(h));
    }
}

__global__ __launch_bounds__(256) void rms_kernel(float* __restrict__ x,
                                                  const float* __restrict__ w)
{
    __shared__ float red[4];
    const size_t s = blockIdx.x;
    float* xr = x + s * D_;
    float v[6];
    float ss = 0.f;
#pragma unroll
    for (int i = 0; i < 6; i++) { v[i] = xr[threadIdx.x + 256 * i]; ss += v[i] * v[i]; }
    ss = block_sum_256(ss, red);
    const float rs = rsqrtf(ss * (1.f / D_) + EPS_);
#pragma unroll
    for (int i = 0; i < 6; i++) {
        const int d = threadIdx.x + 256 * i;
        xr[d] = v[i] * rs * w[d];
    }
}

// ------------------------------- RoPE --------------------------------------
__global__ void rope_kernel(float* __restrict__ x,
                            const float* __restrict__ cosT,
                            const float* __restrict__ sinT)
{
    const int idx = blockIdx.x * 256 + threadIdx.x;
    if (idx >= S_ * (D_ / 2)) return;
    const int s = idx / (D_ / 2), r = idx % (D_ / 2);
    const int h = r >> 6, i = r & 63;
    const size_t base = (size_t)s * D_ + h * 128 + 2 * i;
    const float x1 = x[base], x2 = x[base + 1];
    const float c = cosT[s * 64 + i], sn = sinT[s * 64 + i];
    x[base]     = x1 * c - x2 * sn;
    x[base + 1] = x2 * c + x1 * sn;
}

// --------------------------- elementwise -----------------------------------
__global__ void add_kernel(const float* __restrict__ a, const float* __restrict__ b,
                           float* __restrict__ o, int n)
{
    const int i = blockIdx.x * 256 + threadIdx.x;
    if (i < n) o[i] = a[i] + b[i];
}

__global__ void residgate_kernel(const float* __restrict__ h, const float* __restrict__ x,
                                 const float* __restrict__ gate, float* __restrict__ o)
{
    const int i = blockIdx.x * 256 + threadIdx.x;
    if (i < S_ * D_) { const int d = i % D_; o[i] = h[i] + x[i] * gate[d]; }
}

// ------------------------- VSA coarse path ---------------------------------
__global__ __launch_bounds__(128) void blockmean_f32(const float* __restrict__ q,
                                                     float* __restrict__ qc)
{
    const int hb = blockIdx.x;
    const int h = hb >> 6, j = hb & 63;
    const int d = threadIdx.x;
    float sum = 0.f;
    for (int t = 0; t < 64; t++)
        sum += q[(size_t)(j * 64 + t) * D_ + h * 128 + d];
    qc[(size_t)hb * 128 + d] = sum * (1.f / 64.f);
}

__global__ __launch_bounds__(128) void blockmean_bf16(const short* __restrict__ q,
                                                      float* __restrict__ qc)
{
    const int hb = blockIdx.x;
    const int h = hb >> 6, j = hb & 63;
    const int d = threadIdx.x;
    float sum = 0.f;
    for (int t = 0; t < 64; t++)
        sum += bf2f(q[(size_t)(j * 64 + t) * D_ + h * 128 + d]);
    qc[(size_t)hb * 128 + d] = sum * (1.f / 64.f);
}

__global__ __launch_bounds__(64) void coarse_kernel(
    const float* __restrict__ qc, const float* __restrict__ kc,
    const float* __restrict__ vc, float* __restrict__ oc, int* __restrict__ idxout)
{
    const int hb = blockIdx.x;
    const int h = hb >> 6, i = hb & 63;
    const int lane = threadIdx.x;
    __shared__ float p[64];

    const float* qv = qc + (size_t)hb * 128;
    const float* kv = kc + (size_t)((h << 6) + lane) * 128;
    float sc = 0.f;
    for (int d = 0; d < 128; d++) sc = fmaf(qv[d], kv[d], sc);
    sc *= SCALE_;

    float mx = sc;
#pragma unroll
    for (int off = 32; off > 0; off >>= 1) mx = fmaxf(mx, __shfl_xor(mx, off, 64));
    const float e = expf(sc - mx);
    float sumv = e;
#pragma unroll
    for (int off = 32; off > 0; off >>= 1) sumv += __shfl_xor(sumv, off, 64);
    const float pv = e / sumv;
    p[lane] = pv;
    __syncthreads();

    float o0 = 0.f, o1 = 0.f;
    for (int j = 0; j < 64; j++) {
        const float pj = p[j];
        const float* vr = vc + (size_t)((h << 6) + j) * 128;
        o0 = fmaf(pj, vr[lane], o0);
        o1 = fmaf(pj, vr[lane + 64], o1);
    }
    oc[(size_t)hb * 128 + lane]      = o0;
    oc[(size_t)hb * 128 + lane + 64] = o1;

    float v = pv;
    for (int t = 0; t < TOPK; t++) {
        float bv = v; int bi = lane;
#pragma unroll
        for (int off = 32; off > 0; off >>= 1) {
            const float ov = __shfl_xor(bv, off, 64);
            const int   oi = __shfl_xor(bi, off, 64);
            if (ov > bv || (ov == bv && oi < bi)) { bv = ov; bi = oi; }
        }
        if (lane == 0) idxout[hb * TOPK + t] = bi;
        if (lane == bi) v = -1.f;
    }
}

// ---------------------- MFMA flash attention -------------------------------
template <int MODE>
__global__ __launch_bounds__(256) void attn_mfma(
    const float* __restrict__ Qf, const float* __restrict__ Kf,
    const short* __restrict__ Vbb, const float* __restrict__ Vff,
    const short* __restrict__ Gb, const float* __restrict__ ocp,
    const int* __restrict__ idxp, short* __restrict__ Ob)
{
    const int hb = blockIdx.x, h = hb >> 6, ib = hb & 63;
    const int tid = threadIdx.x, wid = tid >> 6, lane = tid & 63;
    const int g16 = lane >> 4, l15 = lane & 15;

    __shared__ __align__(16) short Ks[64 * 128];
    __shared__ __align__(16) short Vst[128 * 64];
    __shared__ __align__(16) short Ps[64 * 80];
    __shared__ int sel[8];
    if (tid < 8) sel[tid] = (MODE == 0) ? idxp[hb * 8 + tid] : tid;

    short8 qa[4];
    {
        const float* qrow = Qf + (size_t)(ib * 64 + wid * 16 + l15) * D_ + h * 128;
#pragma unroll
        for (int kk = 0; kk < 4; kk++) {
            const float4 f0 = *(const float4*)(qrow + kk * 32 + g16 * 8);
            const float4 f1 = *(const float4*)(qrow + kk * 32 + g16 * 8 + 4);
            short8 v;
            v[0] = f2bf(f0.x); v[1] = f2bf(f0.y); v[2] = f2bf(f0.z); v[3] = f2bf(f0.w);
            v[4] = f2bf(f1.x); v[5] = f2bf(f1.y); v[6] = f2bf(f1.z); v[7] = f2bf(f1.w);
            qa[kk] = v;
        }
    }

    f32x4 o[8];
#pragma unroll
    for (int n2 = 0; n2 < 8; n2++) o[n2] = (f32x4){0.f, 0.f, 0.f, 0.f};
    float mrow[4] = {-3e38f, -3e38f, -3e38f, -3e38f};
    float lrow[4] = {0.f, 0.f, 0.f, 0.f};
    __syncthreads();

    for (int t = 0; t < 8; t++) {
        const int jb = sel[t];
#pragma unroll
        for (int it = 0; it < 4; it++) {
            const int c = tid + 256 * it;
            const int key = c >> 4, d8 = (c & 15) * 8;
            const float* src = Kf + (size_t)(jb * 64 + key) * D_ + h * 128 + d8;
            const float4 f0 = *(const float4*)src;
            const float4 f1 = *(const float4*)(src + 4);
            short8 v;
            v[0] = f2bf(f0.x); v[1] = f2bf(f0.y); v[2] = f2bf(f0.z); v[3] = f2bf(f0.w);
            v[4] = f2bf(f1.x); v[5] = f2bf(f1.y); v[6] = f2bf(f1.z); v[7] = f2bf(f1.w);
            const int byte = (key * 256 + d8 * 2) ^ ((key & 7) << 4);
            *(short8*)((char*)Ks + byte) = v;
        }
#pragma unroll
        for (int it = 0; it < 4; it++) {
            const int c = tid + 256 * it;
            const int key = c & 63, d8 = (c >> 6) * 8;
            float vv[8];
            if (MODE == 0) {
                const short8 v = *(const short8*)(Vbb + (size_t)(jb * 64 + key) * D_ + h * 128 + d8);
#pragma unroll
                for (int j = 0; j < 8; j++) vv[j] = bf2f(v[j]);
            } else {
                const float* src = Vff + (size_t)(jb * 64 + key) * D_ + h * 128 + d8;
                const float4 f0 = *(const float4*)src;
                const float4 f1 = *(const float4*)(src + 4);
                vv[0] = f0.x; vv[1] = f0.y; vv[2] = f0.z; vv[3] = f0.w;
                vv[4] = f1.x; vv[5] = f1.y; vv[6] = f1.z; vv[7] = f1.w;
            }
#pragma unroll
            for (int j = 0; j < 8; j++) {
                const int dim = d8 + j;
                const int byte = (dim * 128 + key * 2) ^ ((dim & 7) << 4);
                *(short*)((char*)Vst + byte) = f2bf(vv[j]);
            }
        }
        __syncthreads();

        f32x4 s[4];
#pragma unroll
        for (int nt = 0; nt < 4; nt++) {
            f32x4 acc = (f32x4){0.f, 0.f, 0.f, 0.f};
            const int key = nt * 16 + l15;
#pragma unroll
            for (int kk = 0; kk < 4; kk++) {
                const int byte = (key * 256 + (kk * 32 + g16 * 8) * 2) ^ ((key & 7) << 4);
                const short8 b = *(const short8*)((char*)Ks + byte);
                acc = __builtin_amdgcn_mfma_f32_16x16x32_bf16(qa[kk], b, acc, 0, 0, 0);
            }
            s[nt] = acc;
        }
#pragma unroll
        for (int nt = 0; nt < 4; nt++)
#pragma unroll
            for (int rr = 0; rr < 4; rr++) s[nt][rr] *= SCALE_;

        float alpha[4];
#pragma unroll
        for (int rr = 0; rr < 4; rr++) {
            float v = fmaxf(fmaxf(s[0][rr], s[1][rr]), fmaxf(s[2][rr], s[3][rr]));
            v = fmaxf(v, __shfl_xor(v, 1, 64));
            v = fmaxf(v, __shfl_xor(v, 2, 64));
            v = fmaxf(v, __shfl_xor(v, 4, 64));
            v = fmaxf(v, __shfl_xor(v, 8, 64));
            const float mn = fmaxf(mrow[rr], v);
            alpha[rr] = expf(mrow[rr] - mn);
            mrow[rr] = mn;
        }
        float rs[4] = {0.f, 0.f, 0.f, 0.f};
#pragma unroll
        for (int nt = 0; nt < 4; nt++)
#pragma unroll
            for (int rr = 0; rr < 4; rr++) {
                const float p = expf(s[nt][rr] - mrow[rr]);
                s[nt][rr] = p;
                rs[rr] += p;
            }
#pragma unroll
        for (int rr = 0; rr < 4; rr++) {
            float v = rs[rr];
            v += __shfl_xor(v, 1, 64);
            v += __shfl_xor(v, 2, 64);
            v += __shfl_xor(v, 4, 64);
            v += __shfl_xor(v, 8, 64);
            lrow[rr] = lrow[rr] * alpha[rr] + v;
        }
#pragma unroll
        for (int n2 = 0; n2 < 8; n2++)
#pragma unroll
            for (int rr = 0; rr < 4; rr++) o[n2][rr] *= alpha[rr];

#pragma unroll
        for (int nt = 0; nt < 4; nt++)
#pragma unroll
            for (int rr = 0; rr < 4; rr++)
                Ps[(wid * 16 + g16 * 4 + rr) * 80 + nt * 16 + l15] = f2bf(s[nt][rr]);

#pragma unroll
        for (int kk2 = 0; kk2 < 2; kk2++) {
            const short8 pa = *(const short8*)(Ps + (wid * 16 + l15) * 80 + kk2 * 32 + g16 * 8);
#pragma unroll
            for (int n2 = 0; n2 < 8; n2++) {
                const int dim = n2 * 16 + l15;
                const int byte = (dim * 128 + (kk2 * 32 + g16 * 8) * 2) ^ ((dim & 7) << 4);
                const short8 vb = *(const short8*)((char*)Vst + byte);
                o[n2] = __builtin_amdgcn_mfma_f32_16x16x32_bf16(pa, vb, o[n2], 0, 0, 0);
            }
        }
        __syncthreads();
    }

#pragma unroll
    for (int n2 = 0; n2 < 8; n2++) {
        const int col = n2 * 16 + l15;
        const float ocv = (MODE == 0) ? ocp[(size_t)hb * 128 + col] : 0.f;
#pragma unroll
        for (int rr = 0; rr < 4; rr++) {
            const int row = ib * 64 + wid * 16 + g16 * 4 + rr;
            float val = o[n2][rr] / lrow[rr];
            if (MODE == 0)
                val += ocv * bf2f(Gb[(size_t)row * D_ + h * 128 + col]);
            Ob[(size_t)row * D_ + h * 128 + col] = f2bf(val);
        }
    }
}

// ---------------------------------------------------------------------------
extern "C" void kernel_launch(void* const* d_in, const int* in_sizes, int n_in,
                              void* d_out, int out_size, void* d_ws, size_t ws_size,
                              hipStream_t stream)
{
    const float* h_in = (const float*)d_in[0];
    const float* enc  = (const float*)d_in[1];
    const float* temb = (const float*)d_in[2];
    const float* cosT = (const float*)d_in[3];
    const float* sinT = (const float*)d_in[4];
    const float* sst  = (const float*)d_in[5];
    const float* Wq = (const float*)d_in[6];   const float* bq = (const float*)d_in[7];
    const float* Wk = (const float*)d_in[8];   const float* bk = (const float*)d_in[9];
    const float* Wv = (const float*)d_in[10];  const float* bv = (const float*)d_in[11];
    const float* Wg = (const float*)d_in[12];  const float* bg = (const float*)d_in[13];
    const float* Wo = (const float*)d_in[14];  const float* bo = (const float*)d_in[15];
    const float* nq_w  = (const float*)d_in[16];
    const float* nk_w  = (const float*)d_in[17];
    const float* ln1_w = (const float*)d_in[18];
    const float* ln1_b = (const float*)d_in[19];
    const float* cWq = (const float*)d_in[20]; const float* cbq = (const float*)d_in[21];
    const float* cWk = (const float*)d_in[22]; const float* cbk = (const float*)d_in[23];
    const float* cWv = (const float*)d_in[24]; const float* cbv = (const float*)d_in[25];
    const float* cWo = (const float*)d_in[26]; const float* cbo = (const float*)d_in[27];
    const float* cnq_w = (const float*)d_in[28];
    const float* cnk_w = (const float*)d_in[29];
    const float* W1 = (const float*)d_in[30];  const float* b1 = (const float*)d_in[31];
    const float* W2 = (const float*)d_in[32];  const float* b2 = (const float*)d_in[33];
    float* out = (float*)d_out;

    char* base = (char*)d_ws;
    size_t off = 0;
    auto alloc = [&](size_t bytes) {
        char* p = base + off;
        off += (bytes + 255) & ~(size_t)255;
        return p;
    };
    const size_t SD = (size_t)S_ * D_;
    float* e_   = (float*)alloc(6 * D_ * 4);
    float* Q_   = (float*)alloc(SD * 4);       // Q_ and K_ adjacent (EPI4/5)
    float* K_   = (float*)alloc(SD * 4);
    float* CK_  = (float*)alloc((size_t)L_ * D_ * 4);
    float* CV_  = (float*)alloc((size_t)L_ * D_ * 4);
    float* qc_  = (float*)alloc((size_t)H_ * 64 * 128 * 4);
    float* kc_  = (float*)alloc((size_t)H_ * 64 * 128 * 4);
    float* vc_  = (float*)alloc((size_t)H_ * 64 * 128 * 4);
    float* oc_  = (float*)alloc((size_t)H_ * 64 * 128 * 4);
    int*   idx_ = (int*)alloc((size_t)H_ * 64 * TOPK * 4);
    short* Nb   = (short*)alloc(SD * 2);
    // ---- FFC alias region: Nlo .. Wkl (~80 MB, all dead by FFN) ----
    short* Nlo  = (short*)alloc(SD * 2);
    short* Vb   = (short*)alloc(SD * 2);       // Vb and Gb adjacent (EPI4)
    short* Gb   = (short*)alloc(SD * 2);
    short* attn_b = (short*)alloc(SD * 2);
    short* enc_b  = (short*)alloc((size_t)L_ * D_ * 2);
    const size_t WDD = (size_t)D_ * D_;
    short* Wqh = (short*)alloc(WDD * 2);       // Wqh,Wkh,Wvt,Wgt contiguous =
    short* Wkh = (short*)alloc(WDD * 2);       // N=6144 concat B for fused proj
    short* Wvt = (short*)alloc(WDD * 2);
    short* Wgt = (short*)alloc(WDD * 2);
    short* Wql = (short*)alloc(WDD * 2);
    short* Wkl = (short*)alloc(WDD * 2);
    // ---- end alias region ----
    short* Wot = (short*)alloc(WDD * 2);
    short* cWqt = (short*)alloc(WDD * 2); short* cWkt = (short*)alloc(WDD * 2);
    short* cWvt = (short*)alloc(WDD * 2); short* cWot = (short*)alloc(WDD * 2);
    short* W1t = (short*)alloc((size_t)D_ * FF_ * 2);
    short* W2t = (short*)alloc((size_t)D_ * FF_ * 2);
    float* bcat = (float*)alloc(6144 * 4);
    short* FFC = Nlo;   // S x FF bf16 (73.4 MB) over dead region (80 MB)

    const dim3 b256(256);
    const dim3 b512(512);
    const int nSD = S_ * D_;
    const dim3 gSD((nSD + 255) / 256);
    const dim3 gDD(D_ / 64, D_ / 64);
    const dim3 gN1536(D_ / 256, S_ / 256);     // (6,16)

    add_kernel<<<dim3((6 * D_ + 255) / 256), b256, 0, stream>>>(sst, temb, e_, 6 * D_);
    ln_bf16<1, 1><<<dim3(S_), b256, 0, stream>>>(h_in, Nb, Nlo, e_ + D_, e_);
    fill_bcat<<<dim3(24), b256, 0, stream>>>(bq, bk, bv, bg, bcat);

    transpose_w<1><<<gDD, b256, 0, stream>>>(Wq, Wqh, Wql, D_, D_);
    transpose_w<1><<<gDD, b256, 0, stream>>>(Wk, Wkh, Wkl, D_, D_);
    transpose_w<0><<<gDD, b256, 0, stream>>>(Wv, Wvt, nullptr, D_, D_);
    transpose_w<0><<<gDD, b256, 0, stream>>>(Wg, Wgt, nullptr, D_, D_);
    transpose_w<0><<<gDD, b256, 0, stream>>>(Wo, Wot, nullptr, D_, D_);
    transpose_w<0><<<gDD, b256, 0, stream>>>(cWq, cWqt, nullptr, D_, D_);
    transpose_w<0><<<gDD, b256, 0, stream>>>(cWk, cWkt, nullptr, D_, D_);
    transpose_w<0><<<gDD, b256, 0, stream>>>(cWv, cWvt, nullptr, D_, D_);
    transpose_w<0><<<gDD, b256, 0, stream>>>(cWo, cWot, nullptr, D_, D_);
    transpose_w<0><<<dim3(FF_ / 64, D_ / 64), b256, 0, stream>>>(W1, W1t, nullptr, D_, FF_);
    transpose_w<0><<<dim3(D_ / 64, FF_ / 64), b256, 0, stream>>>(W2, W2t, nullptr, FF_, D_);
    cvt_bf16_kernel<<<dim3((L_ * D_ / 4 + 255) / 256), b256, 0, stream>>>(enc, enc_b, L_ * D_ / 4);

    // fused QKVG projection (hi) + K-concat correction (q,k exactness)
    gemm8p<4><<<dim3(6144 / 256, S_ / 256), b512, 0, stream>>>(
        Nb, Wqh, bcat, Q_, Vb, S_, 6144, D_, nullptr, nullptr, nullptr, nullptr);
    gemm8p<5><<<dim3(3072 / 256, S_ / 256), b512, 0, stream>>>(
        Nb, Wql, nullptr, Q_, nullptr, S_, 3072, 3072, Nlo, Wqh, Wkl, Wkh);

    rms_kernel<<<dim3(S_), b256, 0, stream>>>(Q_, nq_w);
    rms_kernel<<<dim3(S_), b256, 0, stream>>>(K_, nk_w);
    {
        const dim3 g((S_ * (D_ / 2) + 255) / 256);
        rope_kernel<<<g, b256, 0, stream>>>(Q_, cosT, sinT);
        rope_kernel<<<g, b256, 0, stream>>>(K_, cosT, sinT);
    }

    blockmean_f32<<<dim3(H_ * 64), dim3(128), 0, stream>>>(Q_, qc_);
    blockmean_f32<<<dim3(H_ * 64), dim3(128), 0, stream>>>(K_, kc_);
    blockmean_bf16<<<dim3(H_ * 64), dim3(128), 0, stream>>>(Vb, vc_);
    coarse_kernel<<<dim3(H_ * 64), dim3(64), 0, stream>>>(qc_, kc_, vc_, oc_, idx_);

    attn_mfma<0><<<dim3(H_ * 64), b256, 0, stream>>>(
        Q_, K_, Vb, nullptr, Gb, oc_, idx_, attn_b);

    gemm8p<0><<<gN1536, b512, 0, stream>>>(attn_b, Wot, bo, Q_, nullptr, S_, D_, D_,
                                           nullptr, nullptr, nullptr, nullptr);
    residgate_kernel<<<gSD, b256, 0, stream>>>(h_in, Q_, e_ + 2 * D_, K_);

    ln_bf16<0, 0><<<dim3(S_), b256, 0, stream>>>(K_, Nb, nullptr, ln1_w, ln1_b);
    gemm8p<0><<<gN1536, b512, 0, stream>>>(Nb, cWqt, cbq, Q_, nullptr, S_, D_, D_,
                                           nullptr, nullptr, nullptr, nullptr);
    rms_kernel<<<dim3(S_), b256, 0, stream>>>(Q_, cnq_w);

    const dim3 gLenc(D_ / 256, L_ / 256);      // (6,2)
    gemm8p<0><<<gLenc, b512, 0, stream>>>(enc_b, cWkt, cbk, CK_, nullptr, L_, D_, D_,
                                          nullptr, nullptr, nullptr, nullptr);
    rms_kernel<<<dim3(L_), b256, 0, stream>>>(CK_, cnk_w);
    gemm8p<0><<<gLenc, b512, 0, stream>>>(enc_b, cWvt, cbv, CV_, nullptr, L_, D_, D_,
                                          nullptr, nullptr, nullptr, nullptr);

    attn_mfma<1><<<dim3(H_ * 64), b256, 0, stream>>>(
        Q_, CK_, nullptr, CV_, nullptr, nullptr, nullptr, attn_b);
    gemm8p<0><<<gN1536, b512, 0, stream>>>(attn_b, cWot, cbo, Q_, nullptr, S_, D_, D_,
                                           nullptr, nullptr, nullptr, nullptr);
    add_kernel<<<gSD, b256, 0, stream>>>(K_, Q_, K_, nSD);

    ln_bf16<1, 0><<<dim3(S_), b256, 0, stream>>>(K_, Nb, nullptr, e_ + 4 * D_, e_ + 3 * D_);
    gemm8p<2><<<dim3(FF_ / 256, S_ / 256), b512, 0, stream>>>(
        Nb, W1t, b1, nullptr, FFC, S_, FF_, D_, nullptr, nullptr, nullptr, nullptr);
    gemm8p<0><<<gN1536, b512, 0, stream>>>(FFC, W2t, b2, Q_, nullptr, S_, D_, FF_,
                                           nullptr, nullptr, nullptr, nullptr);

    residgate_kernel<<<gSD, b256, 0, stream>>>(K_, Q_, e_ + 5 * D_, out);
}

// Round 9
// 1489.500 us; speedup vs baseline: 1.0933x; 1.0933x over previous
//
#include <hip/hip_runtime.h>
#include <math.h>

// ---------------------------------------------------------------------------
// Round 9: GEMM = r6 geometry (256x128x64, 8 waves, 96KB dbuf -> 192+ block
// grids for N=1536) + r7 counted-vmcnt pipeline (issue-early, vmcnt(6),
// setprio). Fused QKVG proj + corr kept. rms+rope fused for Q,K.
// ---------------------------------------------------------------------------

namespace {
constexpr int S_   = 4096;
constexpr int D_   = 1536;
constexpr int H_   = 12;
constexpr int L_   = 512;
constexpr int TOPK = 8;
constexpr int FF_  = 8960;
constexpr float EPS_   = 1e-6f;
constexpr float SCALE_ = 0.08838834764831845f;   // 128^-0.5
}

typedef __attribute__((ext_vector_type(8))) short short8;
typedef __attribute__((ext_vector_type(4))) float f32x4;

#define AS_GLOBAL __attribute__((address_space(1)))
#define AS_LDS    __attribute__((address_space(3)))

__device__ __forceinline__ short f2bf(float x) {
    uint32_t u = __float_as_uint(x);
    uint32_t r = (u + 0x7FFFu + ((u >> 16) & 1u)) >> 16;
    return (short)r;
}
__device__ __forceinline__ float bf2f(short s) {
    return __uint_as_float(((uint32_t)(uint16_t)s) << 16);
}
__device__ __forceinline__ float gelu_tanh(float x) {
    const float t = tanhf(0.7978845608028654f * (x + 0.044715f * x * x * x));
    return 0.5f * x * (1.f + t);
}

// ---------------------------- reductions -----------------------------------
__device__ __forceinline__ float block_sum_256(float v, float* red) {
#pragma unroll
    for (int off = 32; off > 0; off >>= 1) v += __shfl_down(v, off, 64);
    const int lane = threadIdx.x & 63, w = threadIdx.x >> 6;
    if (lane == 0) red[w] = v;
    __syncthreads();
    v = red[0] + red[1] + red[2] + red[3];
    __syncthreads();
    return v;
}

// ===================== 256x128x64 8-wave MFMA GEMM =========================
// C(M,N) = A(M,K) @ Bt(N,K)^T. 512 thr, 8 waves: wm=wid>>1 (4 M-quarters of
// 64), wn=wid&1 (2 N-halves of 64). Per-wave 64x64 out, acc[4][4].
// LDS: A[2][256x64] 64KB + B[2][128x64] 32KB = 96 KB double-buffered.
// Pipeline/K-tile: STAGE(t+1) (6 loads/thr); vmcnt(6) [tail: 0]; barrier;
// 16x ds_read_b128; lgkmcnt(0)+schedbar; barrier; setprio(1) 32 MFMA
// setprio(0). Counted vmcnt keeps next tile's loads in flight across the
// barrier. Unit swizzle u_phys = u ^ (row&7), both sides.
// EPI: 0 C=acc+bias ; 1 C+=acc ; 2 Cb=bf16(gelu(acc+bias)) ; 3 Cb=bf16(acc+b)
//      4 fused QKVG (N=6144): seg 0,1 -> f32 C+seg*SD ; seg 2,3 -> bf16 Cb
//      5 corr: A=Nb,Alo=Nlo; B k<1536 -> {Wql|Wkl}, k>=1536 -> {Wqh|Wkh};
//              row stride 1536; C(:,seg) += acc (seg = col>=1536)
template <int EPI>
__global__ __launch_bounds__(512, 2) void gemm9(
    const short* __restrict__ A, const short* __restrict__ Bt,
    const float* __restrict__ bias, float* __restrict__ C,
    short* __restrict__ Cb, int M, int N, int K,
    const short* __restrict__ Alo, const short* __restrict__ B2,
    const short* __restrict__ B3, const short* __restrict__ B4)
{
    __shared__ __align__(16) short As[2][256 * 64];
    __shared__ __align__(16) short Bs[2][128 * 64];
    const int tid = threadIdx.x;
    const int wid = tid >> 6, lane = tid & 63;
    const int wm = wid >> 1, wn = wid & 1;
    const int g16 = lane >> 4, l15 = lane & 15;

    // bijective XCD swizzle
    const int nwg = gridDim.x * gridDim.y;
    const int bid = blockIdx.y * gridDim.x + blockIdx.x;
    const int qq = nwg >> 3, r8 = nwg & 7;
    const int xcd = bid & 7, lid = bid >> 3;
    const int swz = ((xcd < r8) ? xcd * (qq + 1) : r8 * (qq + 1) + (xcd - r8) * qq) + lid;
    const int m0 = (swz / gridDim.x) * 256, n0 = (swz % gridDim.x) * 128;
    const int nseg = (n0 >= 1536) ? 1 : 0;       // EPI5 only

    f32x4 acc[4][4];
#pragma unroll
    for (int i = 0; i < 4; i++)
#pragma unroll
        for (int j = 0; j < 4; j++) acc[i][j] = (f32x4){0.f, 0.f, 0.f, 0.f};

    // staging maps: A 2048 units (4/thr), B 1024 units (2/thr)
    int ar[4], au[4], br[2], bu[2];
#pragma unroll
    for (int i = 0; i < 4; i++) {
        const int c = tid + 512 * i;
        ar[i] = c >> 3;
        au[i] = (c & 7) ^ (ar[i] & 7);
    }
#pragma unroll
    for (int i = 0; i < 2; i++) {
        const int c = tid + 512 * i;
        br[i] = c >> 3;
        bu[i] = (c & 7) ^ (br[i] & 7);
    }

    const int lda = (EPI == 5) ? 1536 : K;
    auto STAGE = [&](int buf, int kt) {
        const short* asrc = A;
        const short* bsrc = Bt;
        int kl = kt, nb = n0;
        if (EPI == 5) {
            const int ks = (kt >= 1536);
            asrc = ks ? Alo : A;
            bsrc = nseg ? (ks ? B4 : B3) : (ks ? B2 : Bt);
            kl = kt - ks * 1536;
            nb = n0 - nseg * 1536;
        }
#pragma unroll
        for (int i = 0; i < 4; i++)
            __builtin_amdgcn_global_load_lds(
                (const AS_GLOBAL short*)(asrc + (size_t)(m0 + ar[i]) * lda + kl + au[i] * 8),
                (AS_LDS short*)(&As[buf][(tid + 512 * i) * 8]), 16, 0, 0);
#pragma unroll
        for (int i = 0; i < 2; i++)
            __builtin_amdgcn_global_load_lds(
                (const AS_GLOBAL short*)(bsrc + (size_t)(nb + br[i]) * lda + kl + bu[i] * 8),
                (AS_LDS short*)(&Bs[buf][(tid + 512 * i) * 8]), 16, 0, 0);
    };

    const int nk = K >> 6;
    STAGE(0, 0);

    int cur = 0;
    for (int t = 0; t < nk; ++t) {
        if (t + 1 < nk) {
            STAGE(cur ^ 1, (t + 1) << 6);
            asm volatile("s_waitcnt vmcnt(6)" ::: "memory");
        } else {
            asm volatile("s_waitcnt vmcnt(0)" ::: "memory");
        }
        __builtin_amdgcn_s_barrier();              // tile t fully in LDS
        __builtin_amdgcn_sched_barrier(0);

        short8 a[4][2], b[4][2];
#pragma unroll
        for (int mi = 0; mi < 4; mi++) {
            const int row = wm * 64 + mi * 16 + l15;
#pragma unroll
            for (int kk = 0; kk < 2; kk++) {
                const int u = (kk * 4 + g16) ^ (row & 7);
                a[mi][kk] = *(const short8*)(As[cur] + row * 64 + u * 8);
            }
        }
#pragma unroll
        for (int ni = 0; ni < 4; ni++) {
            const int row = wn * 64 + ni * 16 + l15;
#pragma unroll
            for (int kk = 0; kk < 2; kk++) {
                const int u = (kk * 4 + g16) ^ (row & 7);
                b[ni][kk] = *(const short8*)(Bs[cur] + row * 64 + u * 8);
            }
        }
        asm volatile("s_waitcnt lgkmcnt(0)" ::: "memory");
        __builtin_amdgcn_sched_barrier(0);
        __builtin_amdgcn_s_barrier();              // all waves done reading
        __builtin_amdgcn_sched_barrier(0);

        __builtin_amdgcn_s_setprio(1);
#pragma unroll
        for (int mi = 0; mi < 4; mi++)
#pragma unroll
            for (int ni = 0; ni < 4; ni++)
#pragma unroll
                for (int kk = 0; kk < 2; kk++)
                    acc[mi][ni] = __builtin_amdgcn_mfma_f32_16x16x32_bf16(
                        a[mi][kk], b[ni][kk], acc[mi][ni], 0, 0, 0);
        __builtin_amdgcn_s_setprio(0);

        cur ^= 1;
    }

    const size_t SD = (size_t)S_ * D_;
#pragma unroll
    for (int mi = 0; mi < 4; mi++) {
#pragma unroll
        for (int ni = 0; ni < 4; ni++) {
            const int col = n0 + wn * 64 + ni * 16 + l15;
            const float bv = (EPI == 1 || EPI == 5) ? 0.f : bias[col];
#pragma unroll
            for (int rr = 0; rr < 4; rr++) {
                const int row = m0 + wm * 64 + mi * 16 + g16 * 4 + rr;
                float v = acc[mi][ni][rr];
                if (EPI == 4) {
                    const int seg = col / 1536, cl = col - seg * 1536;
                    const float y = v + bv;
                    if (seg < 2) C[(size_t)seg * SD + (size_t)row * 1536 + cl] = y;
                    else Cb[(size_t)(seg - 2) * SD + (size_t)row * 1536 + cl] = f2bf(y);
                } else if (EPI == 5) {
                    const int seg = (col >= 1536) ? 1 : 0, cl = col - seg * 1536;
                    C[(size_t)seg * SD + (size_t)row * 1536 + cl] += v;
                } else {
                    const size_t o = (size_t)row * N + col;
                    if (EPI == 0) C[o] = v + bv;
                    else if (EPI == 1) C[o] += v;
                    else if (EPI == 2) Cb[o] = f2bf(gelu_tanh(v + bv));
                    else Cb[o] = f2bf(v + bv);
                }
            }
        }
    }
}

// ---------------------- weight transpose / convert -------------------------
template <int SPLIT>
__global__ __launch_bounds__(256) void transpose_w(
    const float* __restrict__ W, short* __restrict__ Th, short* __restrict__ Tl,
    int Kd, int Nd)
{
    __shared__ float tile[64][65];
    const int k0 = blockIdx.y * 64, n0 = blockIdx.x * 64;
    for (int f = threadIdx.x; f < 1024; f += 256) {
        const int rr = f >> 4, c4 = (f & 15) * 4;
        const float4 v = *(const float4*)(W + (size_t)(k0 + rr) * Nd + n0 + c4);
        tile[rr][c4 + 0] = v.x; tile[rr][c4 + 1] = v.y;
        tile[rr][c4 + 2] = v.z; tile[rr][c4 + 3] = v.w;
    }
    __syncthreads();
    for (int f = threadIdx.x; f < 1024; f += 256) {
        const int nn = f >> 4, k4 = (f & 15) * 4;
        short4 hv, lv;
        float w0 = tile[k4 + 0][nn], w1 = tile[k4 + 1][nn];
        float w2 = tile[k4 + 2][nn], w3 = tile[k4 + 3][nn];
        hv.x = f2bf(w0); hv.y = f2bf(w1); hv.z = f2bf(w2); hv.w = f2bf(w3);
        *(short4*)(Th + (size_t)(n0 + nn) * Kd + k0 + k4) = hv;
        if (SPLIT) {
            lv.x = f2bf(w0 - bf2f(hv.x)); lv.y = f2bf(w1 - bf2f(hv.y));
            lv.z = f2bf(w2 - bf2f(hv.z)); lv.w = f2bf(w3 - bf2f(hv.w));
            *(short4*)(Tl + (size_t)(n0 + nn) * Kd + k0 + k4) = lv;
        }
    }
}

__global__ void cvt_bf16_kernel(const float* __restrict__ x, short* __restrict__ y, int n4)
{
    const int i = blockIdx.x * 256 + threadIdx.x;
    if (i >= n4) return;
    const float4 v = *(const float4*)(x + (size_t)i * 4);
    short4 o; o.x = f2bf(v.x); o.y = f2bf(v.y); o.z = f2bf(v.z); o.w = f2bf(v.w);
    *(short4*)(y + (size_t)i * 4) = o;
}

__global__ void fill_bcat(const float* __restrict__ bq, const float* __restrict__ bk,
                          const float* __restrict__ bv, const float* __restrict__ bg,
                          float* __restrict__ bcat)
{
    const int i = blockIdx.x * 256 + threadIdx.x;
    if (i >= 6144) return;
    const int seg = i / 1536, c = i - seg * 1536;
    const float* src = (seg == 0) ? bq : (seg == 1) ? bk : (seg == 2) ? bv : bg;
    bcat[i] = src[c];
}

// --------------------- LayerNorm (bf16 out, optional split) -----------------
template <int ADD1, int SPLIT>
__global__ __launch_bounds__(256) void ln_bf16(
    const float* __restrict__ x, short* __restrict__ hi, short* __restrict__ lo,
    const float* __restrict__ g, const float* __restrict__ b)
{
    __shared__ float red[4];
    const size_t s = blockIdx.x;
    const float* xr = x + s * D_;
    float v[6];
    float sm = 0.f;
#pragma unroll
    for (int i = 0; i < 6; i++) { v[i] = xr[threadIdx.x + 256 * i]; sm += v[i]; }
    sm = block_sum_256(sm, red);
    const float mean = sm * (1.f / D_);
    float vs = 0.f;
#pragma unroll
    for (int i = 0; i < 6; i++) { const float d = v[i] - mean; vs += d * d; }
    vs = block_sum_256(vs, red);
    const float rs = rsqrtf(vs * (1.f / D_) + EPS_);
#pragma unroll
    for (int i = 0; i < 6; i++) {
        const int d = threadIdx.x + 256 * i;
        const float y = (v[i] - mean) * rs * (g[d] + (float)ADD1) + b[d];
        const short h = f2bf(y);
        hi[s * D_ + d] = h;
        if (SPLIT) lo[s * D_ + d] = f2bf(y - bf2f(h));
    }
}

__global__ __launch_bounds__(256) void rms_kernel(float* __restrict__ x,
                                                  const float* __restrict__ w)
{
    __shared__ float red[4];
    const size_t s = blockIdx.x;
    float* xr = x + s * D_;
    float v[6];
    float ss = 0.f;
#pragma unroll
    for (int i = 0; i < 6; i++) { v[i] = xr[threadIdx.x + 256 * i]; ss += v[i] * v[i]; }
    ss = block_sum_256(ss, red);
    const float rs = rsqrtf(ss * (1.f / D_) + EPS_);
#pragma unroll
    for (int i = 0; i < 6; i++) {
        const int d = threadIdx.x + 256 * i;
        xr[d] = v[i] * rs * w[d];
    }
}

// --------------- fused RMS + RoPE for Q and K (in-place) -------------------
// one block per token s; pair p = (h*64+i) -> elements (2p, 2p+1)
__global__ __launch_bounds__(256) void rmsrope_qk(
    float* __restrict__ Q, float* __restrict__ K,
    const float* __restrict__ nqw, const float* __restrict__ nkw,
    const float* __restrict__ cosT, const float* __restrict__ sinT)
{
    __shared__ float red[4];
    const size_t s = blockIdx.x;
    const int tid = threadIdx.x;

#pragma unroll
    for (int m = 0; m < 2; m++) {
        float* X = m ? K : Q;
        const float* w = m ? nkw : nqw;
        float2 v[3];
        float ss = 0.f;
#pragma unroll
        for (int j = 0; j < 3; j++) {
            v[j] = *(const float2*)(X + s * D_ + 2 * (tid + 256 * j));
            ss += v[j].x * v[j].x + v[j].y * v[j].y;
        }
        ss = block_sum_256(ss, red);
        const float rs = rsqrtf(ss * (1.f / D_) + EPS_);
#pragma unroll
        for (int j = 0; j < 3; j++) {
            const int p = tid + 256 * j;
            const int i = p & 63;
            const float c = cosT[s * 64 + i], sn = sinT[s * 64 + i];
            const float x1 = v[j].x * rs * w[2 * p];
            const float x2 = v[j].y * rs * w[2 * p + 1];
            float2 o;
            o.x = x1 * c - x2 * sn;
            o.y = x2 * c + x1 * sn;
            *(float2*)(X + s * D_ + 2 * p) = o;
        }
    }
}

// --------------------------- elementwise -----------------------------------
__global__ void add_kernel(const float* __restrict__ a, const float* __restrict__ b,
                           float* __restrict__ o, int n)
{
    const int i = blockIdx.x * 256 + threadIdx.x;
    if (i < n) o[i] = a[i] + b[i];
}

__global__ void residgate_kernel(const float* __restrict__ h, const float* __restrict__ x,
                                 const float* __restrict__ gate, float* __restrict__ o)
{
    const int i = blockIdx.x * 256 + threadIdx.x;
    if (i < S_ * D_) { const int d = i % D_; o[i] = h[i] + x[i] * gate[d]; }
}

// ------------------------- VSA coarse path ---------------------------------
__global__ __launch_bounds__(128) void blockmean_f32(const float* __restrict__ q,
                                                     float* __restrict__ qc)
{
    const int hb = blockIdx.x;
    const int h = hb >> 6, j = hb & 63;
    const int d = threadIdx.x;
    float sum = 0.f;
    for (int t = 0; t < 64; t++)
        sum += q[(size_t)(j * 64 + t) * D_ + h * 128 + d];
    qc[(size_t)hb * 128 + d] = sum * (1.f / 64.f);
}

__global__ __launch_bounds__(128) void blockmean_bf16(const short* __restrict__ q,
                                                      float* __restrict__ qc)
{
    const int hb = blockIdx.x;
    const int h = hb >> 6, j = hb & 63;
    const int d = threadIdx.x;
    float sum = 0.f;
    for (int t = 0; t < 64; t++)
        sum += bf2f(q[(size_t)(j * 64 + t) * D_ + h * 128 + d]);
    qc[(size_t)hb * 128 + d] = sum * (1.f / 64.f);
}

__global__ __launch_bounds__(64) void coarse_kernel(
    const float* __restrict__ qc, const float* __restrict__ kc,
    const float* __restrict__ vc, float* __restrict__ oc, int* __restrict__ idxout)
{
    const int hb = blockIdx.x;
    const int h = hb >> 6, i = hb & 63;
    const int lane = threadIdx.x;
    __shared__ float p[64];

    const float* qv = qc + (size_t)hb * 128;
    const float* kv = kc + (size_t)((h << 6) + lane) * 128;
    float sc = 0.f;
    for (int d = 0; d < 128; d++) sc = fmaf(qv[d], kv[d], sc);
    sc *= SCALE_;

    float mx = sc;
#pragma unroll
    for (int off = 32; off > 0; off >>= 1) mx = fmaxf(mx, __shfl_xor(mx, off, 64));
    const float e = expf(sc - mx);
    float sumv = e;
#pragma unroll
    for (int off = 32; off > 0; off >>= 1) sumv += __shfl_xor(sumv, off, 64);
    const float pv = e / sumv;
    p[lane] = pv;
    __syncthreads();

    float o0 = 0.f, o1 = 0.f;
    for (int j = 0; j < 64; j++) {
        const float pj = p[j];
        const float* vr = vc + (size_t)((h << 6) + j) * 128;
        o0 = fmaf(pj, vr[lane], o0);
        o1 = fmaf(pj, vr[lane + 64], o1);
    }
    oc[(size_t)hb * 128 + lane]      = o0;
    oc[(size_t)hb * 128 + lane + 64] = o1;

    float v = pv;
    for (int t = 0; t < TOPK; t++) {
        float bv = v; int bi = lane;
#pragma unroll
        for (int off = 32; off > 0; off >>= 1) {
            const float ov = __shfl_xor(bv, off, 64);
            const int   oi = __shfl_xor(bi, off, 64);
            if (ov > bv || (ov == bv && oi < bi)) { bv = ov; bi = oi; }
        }
        if (lane == 0) idxout[hb * TOPK + t] = bi;
        if (lane == bi) v = -1.f;
    }
}

// ---------------------- MFMA flash attention -------------------------------
template <int MODE>
__global__ __launch_bounds__(256) void attn_mfma(
    const float* __restrict__ Qf, const float* __restrict__ Kf,
    const short* __restrict__ Vbb, const float* __restrict__ Vff,
    const short* __restrict__ Gb, const float* __restrict__ ocp,
    const int* __restrict__ idxp, short* __restrict__ Ob)
{
    const int hb = blockIdx.x, h = hb >> 6, ib = hb & 63;
    const int tid = threadIdx.x, wid = tid >> 6, lane = tid & 63;
    const int g16 = lane >> 4, l15 = lane & 15;

    __shared__ __align__(16) short Ks[64 * 128];
    __shared__ __align__(16) short Vst[128 * 64];
    __shared__ __align__(16) short Ps[64 * 80];
    __shared__ int sel[8];
    if (tid < 8) sel[tid] = (MODE == 0) ? idxp[hb * 8 + tid] : tid;

    short8 qa[4];
    {
        const float* qrow = Qf + (size_t)(ib * 64 + wid * 16 + l15) * D_ + h * 128;
#pragma unroll
        for (int kk = 0; kk < 4; kk++) {
            const float4 f0 = *(const float4*)(qrow + kk * 32 + g16 * 8);
            const float4 f1 = *(const float4*)(qrow + kk * 32 + g16 * 8 + 4);
            short8 v;
            v[0] = f2bf(f0.x); v[1] = f2bf(f0.y); v[2] = f2bf(f0.z); v[3] = f2bf(f0.w);
            v[4] = f2bf(f1.x); v[5] = f2bf(f1.y); v[6] = f2bf(f1.z); v[7] = f2bf(f1.w);
            qa[kk] = v;
        }
    }

    f32x4 o[8];
#pragma unroll
    for (int n2 = 0; n2 < 8; n2++) o[n2] = (f32x4){0.f, 0.f, 0.f, 0.f};
    float mrow[4] = {-3e38f, -3e38f, -3e38f, -3e38f};
    float lrow[4] = {0.f, 0.f, 0.f, 0.f};
    __syncthreads();

    for (int t = 0; t < 8; t++) {
        const int jb = sel[t];
#pragma unroll
        for (int it = 0; it < 4; it++) {
            const int c = tid + 256 * it;
            const int key = c >> 4, d8 = (c & 15) * 8;
            const float* src = Kf + (size_t)(jb * 64 + key) * D_ + h * 128 + d8;
            const float4 f0 = *(const float4*)src;
            const float4 f1 = *(const float4*)(src + 4);
            short8 v;
            v[0] = f2bf(f0.x); v[1] = f2bf(f0.y); v[2] = f2bf(f0.z); v[3] = f2bf(f0.w);
            v[4] = f2bf(f1.x); v[5] = f2bf(f1.y); v[6] = f2bf(f1.z); v[7] = f2bf(f1.w);
            const int byte = (key * 256 + d8 * 2) ^ ((key & 7) << 4);
            *(short8*)((char*)Ks + byte) = v;
        }
#pragma unroll
        for (int it = 0; it < 4; it++) {
            const int c = tid + 256 * it;
            const int key = c & 63, d8 = (c >> 6) * 8;
            float vv[8];
            if (MODE == 0) {
                const short8 v = *(const short8*)(Vbb + (size_t)(jb * 64 + key) * D_ + h * 128 + d8);
#pragma unroll
                for (int j = 0; j < 8; j++) vv[j] = bf2f(v[j]);
            } else {
                const float* src = Vff + (size_t)(jb * 64 + key) * D_ + h * 128 + d8;
                const float4 f0 = *(const float4*)src;
                const float4 f1 = *(const float4*)(src + 4);
                vv[0] = f0.x; vv[1] = f0.y; vv[2] = f0.z; vv[3] = f0.w;
                vv[4] = f1.x; vv[5] = f1.y; vv[6] = f1.z; vv[7] = f1.w;
            }
#pragma unroll
            for (int j = 0; j < 8; j++) {
                const int dim = d8 + j;
                const int byte = (dim * 128 + key * 2) ^ ((dim & 7) << 4);
                *(short*)((char*)Vst + byte) = f2bf(vv[j]);
            }
        }
        __syncthreads();

        f32x4 s[4];
#pragma unroll
        for (int nt = 0; nt < 4; nt++) {
            f32x4 acc = (f32x4){0.f, 0.f, 0.f, 0.f};
            const int key = nt * 16 + l15;
#pragma unroll
            for (int kk = 0; kk < 4; kk++) {
                const int byte = (key * 256 + (kk * 32 + g16 * 8) * 2) ^ ((key & 7) << 4);
                const short8 b = *(const short8*)((char*)Ks + byte);
                acc = __builtin_amdgcn_mfma_f32_16x16x32_bf16(qa[kk], b, acc, 0, 0, 0);
            }
            s[nt] = acc;
        }
#pragma unroll
        for (int nt = 0; nt < 4; nt++)
#pragma unroll
            for (int rr = 0; rr < 4; rr++) s[nt][rr] *= SCALE_;

        float alpha[4];
#pragma unroll
        for (int rr = 0; rr < 4; rr++) {
            float v = fmaxf(fmaxf(s[0][rr], s[1][rr]), fmaxf(s[2][rr], s[3][rr]));
            v = fmaxf(v, __shfl_xor(v, 1, 64));
            v = fmaxf(v, __shfl_xor(v, 2, 64));
            v = fmaxf(v, __shfl_xor(v, 4, 64));
            v = fmaxf(v, __shfl_xor(v, 8, 64));
            const float mn = fmaxf(mrow[rr], v);
            alpha[rr] = expf(mrow[rr] - mn);
            mrow[rr] = mn;
        }
        float rs[4] = {0.f, 0.f, 0.f, 0.f};
#pragma unroll
        for (int nt = 0; nt < 4; nt++)
#pragma unroll
            for (int rr = 0; rr < 4; rr++) {
                const float p = expf(s[nt][rr] - mrow[rr]);
                s[nt][rr] = p;
                rs[rr] += p;
            }
#pragma unroll
        for (int rr = 0; rr < 4; rr++) {
            float v = rs[rr];
            v += __shfl_xor(v, 1, 64);
            v += __shfl_xor(v, 2, 64);
            v += __shfl_xor(v, 4, 64);
            v += __shfl_xor(v, 8, 64);
            lrow[rr] = lrow[rr] * alpha[rr] + v;
        }
#pragma unroll
        for (int n2 = 0; n2 < 8; n2++)
#pragma unroll
            for (int rr = 0; rr < 4; rr++) o[n2][rr] *= alpha[rr];

#pragma unroll
        for (int nt = 0; nt < 4; nt++)
#pragma unroll
            for (int rr = 0; rr < 4; rr++)
                Ps[(wid * 16 + g16 * 4 + rr) * 80 + nt * 16 + l15] = f2bf(s[nt][rr]);

#pragma unroll
        for (int kk2 = 0; kk2 < 2; kk2++) {
            const short8 pa = *(const short8*)(Ps + (wid * 16 + l15) * 80 + kk2 * 32 + g16 * 8);
#pragma unroll
            for (int n2 = 0; n2 < 8; n2++) {
                const int dim = n2 * 16 + l15;
                const int byte = (dim * 128 + (kk2 * 32 + g16 * 8) * 2) ^ ((dim & 7) << 4);
                const short8 vb = *(const short8*)((char*)Vst + byte);
                o[n2] = __builtin_amdgcn_mfma_f32_16x16x32_bf16(pa, vb, o[n2], 0, 0, 0);
            }
        }
        __syncthreads();
    }

#pragma unroll
    for (int n2 = 0; n2 < 8; n2++) {
        const int col = n2 * 16 + l15;
        const float ocv = (MODE == 0) ? ocp[(size_t)hb * 128 + col] : 0.f;
#pragma unroll
        for (int rr = 0; rr < 4; rr++) {
            const int row = ib * 64 + wid * 16 + g16 * 4 + rr;
            float val = o[n2][rr] / lrow[rr];
            if (MODE == 0)
                val += ocv * bf2f(Gb[(size_t)row * D_ + h * 128 + col]);
            Ob[(size_t)row * D_ + h * 128 + col] = f2bf(val);
        }
    }
}

// ---------------------------------------------------------------------------
extern "C" void kernel_launch(void* const* d_in, const int* in_sizes, int n_in,
                              void* d_out, int out_size, void* d_ws, size_t ws_size,
                              hipStream_t stream)
{
    const float* h_in = (const float*)d_in[0];
    const float* enc  = (const float*)d_in[1];
    const float* temb = (const float*)d_in[2];
    const float* cosT = (const float*)d_in[3];
    const float* sinT = (const float*)d_in[4];
    const float* sst  = (const float*)d_in[5];
    const float* Wq = (const float*)d_in[6];   const float* bq = (const float*)d_in[7];
    const float* Wk = (const float*)d_in[8];   const float* bk = (const float*)d_in[9];
    const float* Wv = (const float*)d_in[10];  const float* bv = (const float*)d_in[11];
    const float* Wg = (const float*)d_in[12];  const float* bg = (const float*)d_in[13];
    const float* Wo = (const float*)d_in[14];  const float* bo = (const float*)d_in[15];
    const float* nq_w  = (const float*)d_in[16];
    const float* nk_w  = (const float*)d_in[17];
    const float* ln1_w = (const float*)d_in[18];
    const float* ln1_b = (const float*)d_in[19];
    const float* cWq = (const float*)d_in[20]; const float* cbq = (const float*)d_in[21];
    const float* cWk = (const float*)d_in[22]; const float* cbk = (const float*)d_in[23];
    const float* cWv = (const float*)d_in[24]; const float* cbv = (const float*)d_in[25];
    const float* cWo = (const float*)d_in[26]; const float* cbo = (const float*)d_in[27];
    const float* cnq_w = (const float*)d_in[28];
    const float* cnk_w = (const float*)d_in[29];
    const float* W1 = (const float*)d_in[30];  const float* b1 = (const float*)d_in[31];
    const float* W2 = (const float*)d_in[32];  const float* b2 = (const float*)d_in[33];
    float* out = (float*)d_out;

    char* base = (char*)d_ws;
    size_t off = 0;
    auto alloc = [&](size_t bytes) {
        char* p = base + off;
        off += (bytes + 255) & ~(size_t)255;
        return p;
    };
    const size_t SD = (size_t)S_ * D_;
    float* e_   = (float*)alloc(6 * D_ * 4);
    float* Q_   = (float*)alloc(SD * 4);       // Q_ and K_ adjacent (EPI4/5)
    float* K_   = (float*)alloc(SD * 4);
    float* CK_  = (float*)alloc((size_t)L_ * D_ * 4);
    float* CV_  = (float*)alloc((size_t)L_ * D_ * 4);
    float* qc_  = (float*)alloc((size_t)H_ * 64 * 128 * 4);
    float* kc_  = (float*)alloc((size_t)H_ * 64 * 128 * 4);
    float* vc_  = (float*)alloc((size_t)H_ * 64 * 128 * 4);
    float* oc_  = (float*)alloc((size_t)H_ * 64 * 128 * 4);
    int*   idx_ = (int*)alloc((size_t)H_ * 64 * TOPK * 4);
    short* Nb   = (short*)alloc(SD * 2);
    // ---- FFC alias region: Nlo .. Wkl (~80 MB, all dead by FFN) ----
    short* Nlo  = (short*)alloc(SD * 2);
    short* Vb   = (short*)alloc(SD * 2);       // Vb and Gb adjacent (EPI4)
    short* Gb   = (short*)alloc(SD * 2);
    short* attn_b = (short*)alloc(SD * 2);
    short* enc_b  = (short*)alloc((size_t)L_ * D_ * 2);
    const size_t WDD = (size_t)D_ * D_;
    short* Wqh = (short*)alloc(WDD * 2);       // Wqh,Wkh,Wvt,Wgt contiguous =
    short* Wkh = (short*)alloc(WDD * 2);       // N=6144 concat B for fused proj
    short* Wvt = (short*)alloc(WDD * 2);
    short* Wgt = (short*)alloc(WDD * 2);
    short* Wql = (short*)alloc(WDD * 2);
    short* Wkl = (short*)alloc(WDD * 2);
    // ---- end alias region ----
    short* Wot = (short*)alloc(WDD * 2);
    short* cWqt = (short*)alloc(WDD * 2); short* cWkt = (short*)alloc(WDD * 2);
    short* cWvt = (short*)alloc(WDD * 2); short* cWot = (short*)alloc(WDD * 2);
    short* W1t = (short*)alloc((size_t)D_ * FF_ * 2);
    short* W2t = (short*)alloc((size_t)D_ * FF_ * 2);
    float* bcat = (float*)alloc(6144 * 4);
    short* FFC = Nlo;   // S x FF bf16 (73.4 MB) over dead region (80 MB)

    const dim3 b256(256);
    const dim3 b512(512);
    const int nSD = S_ * D_;
    const dim3 gSD((nSD + 255) / 256);
    const dim3 gDD(D_ / 64, D_ / 64);
    const dim3 gN1536(D_ / 128, S_ / 256);     // (12,16) = 192 blocks

    add_kernel<<<dim3((6 * D_ + 255) / 256), b256, 0, stream>>>(sst, temb, e_, 6 * D_);
    ln_bf16<1, 1><<<dim3(S_), b256, 0, stream>>>(h_in, Nb, Nlo, e_ + D_, e_);
    fill_bcat<<<dim3(24), b256, 0, stream>>>(bq, bk, bv, bg, bcat);

    transpose_w<1><<<gDD, b256, 0, stream>>>(Wq, Wqh, Wql, D_, D_);
    transpose_w<1><<<gDD, b256, 0, stream>>>(Wk, Wkh, Wkl, D_, D_);
    transpose_w<0><<<gDD, b256, 0, stream>>>(Wv, Wvt, nullptr, D_, D_);
    transpose_w<0><<<gDD, b256, 0, stream>>>(Wg, Wgt, nullptr, D_, D_);
    transpose_w<0><<<gDD, b256, 0, stream>>>(Wo, Wot, nullptr, D_, D_);
    transpose_w<0><<<gDD, b256, 0, stream>>>(cWq, cWqt, nullptr, D_, D_);
    transpose_w<0><<<gDD, b256, 0, stream>>>(cWk, cWkt, nullptr, D_, D_);
    transpose_w<0><<<gDD, b256, 0, stream>>>(cWv, cWvt, nullptr, D_, D_);
    transpose_w<0><<<gDD, b256, 0, stream>>>(cWo, cWot, nullptr, D_, D_);
    transpose_w<0><<<dim3(FF_ / 64, D_ / 64), b256, 0, stream>>>(W1, W1t, nullptr, D_, FF_);
    transpose_w<0><<<dim3(D_ / 64, FF_ / 64), b256, 0, stream>>>(W2, W2t, nullptr, FF_, D_);
    cvt_bf16_kernel<<<dim3((L_ * D_ / 4 + 255) / 256), b256, 0, stream>>>(enc, enc_b, L_ * D_ / 4);

    // fused QKVG projection (hi) + K-concat correction (q,k exactness)
    gemm9<4><<<dim3(6144 / 128, S_ / 256), b512, 0, stream>>>(
        Nb, Wqh, bcat, Q_, Vb, S_, 6144, D_, nullptr, nullptr, nullptr, nullptr);
    gemm9<5><<<dim3(3072 / 128, S_ / 256), b512, 0, stream>>>(
        Nb, Wql, nullptr, Q_, nullptr, S_, 3072, 3072, Nlo, Wqh, Wkl, Wkh);

    // fused rms + rope for q,k
    rmsrope_qk<<<dim3(S_), b256, 0, stream>>>(Q_, K_, nq_w, nk_w, cosT, sinT);

    blockmean_f32<<<dim3(H_ * 64), dim3(128), 0, stream>>>(Q_, qc_);
    blockmean_f32<<<dim3(H_ * 64), dim3(128), 0, stream>>>(K_, kc_);
    blockmean_bf16<<<dim3(H_ * 64), dim3(128), 0, stream>>>(Vb, vc_);
    coarse_kernel<<<dim3(H_ * 64), dim3(64), 0, stream>>>(qc_, kc_, vc_, oc_, idx_);

    attn_mfma<0><<<dim3(H_ * 64), b256, 0, stream>>>(
        Q_, K_, Vb, nullptr, Gb, oc_, idx_, attn_b);

    gemm9<0><<<gN1536, b512, 0, stream>>>(attn_b, Wot, bo, Q_, nullptr, S_, D_, D_,
                                          nullptr, nullptr, nullptr, nullptr);
    residgate_kernel<<<gSD, b256, 0, stream>>>(h_in, Q_, e_ + 2 * D_, K_);

    ln_bf16<0, 0><<<dim3(S_), b256, 0, stream>>>(K_, Nb, nullptr, ln1_w, ln1_b);
    gemm9<0><<<gN1536, b512, 0, stream>>>(Nb, cWqt, cbq, Q_, nullptr, S_, D_, D_,
                                          nullptr, nullptr, nullptr, nullptr);
    rms_kernel<<<dim3(S_), b256, 0, stream>>>(Q_, cnq_w);

    const dim3 gLenc(D_ / 128, L_ / 256);      // (12,2)
    gemm9<0><<<gLenc, b512, 0, stream>>>(enc_b, cWkt, cbk, CK_, nullptr, L_, D_, D_,
                                         nullptr, nullptr, nullptr, nullptr);
    rms_kernel<<<dim3(L_), b256, 0, stream>>>(CK_, cnk_w);
    gemm9<0><<<gLenc, b512, 0, stream>>>(enc_b, cWvt, cbv, CV_, nullptr, L_, D_, D_,
                                         nullptr, nullptr, nullptr, nullptr);

    attn_mfma<1><<<dim3(H_ * 64), b256, 0, stream>>>(
        Q_, CK_, nullptr, CV_, nullptr, nullptr, nullptr, attn_b);
    gemm9<0><<<gN1536, b512, 0, stream>>>(attn_b, cWot, cbo, Q_, nullptr, S_, D_, D_,
                                          nullptr, nullptr, nullptr, nullptr);
    add_kernel<<<gSD, b256, 0, stream>>>(K_, Q_, K_, nSD);

    ln_bf16<1, 0><<<dim3(S_), b256, 0, stream>>>(K_, Nb, nullptr, e_ + 4 * D_, e_ + 3 * D_);
    gemm9<2><<<dim3(FF_ / 128, S_ / 256), b512, 0, stream>>>(
        Nb, W1t, b1, nullptr, FFC, S_, FF_, D_, nullptr, nullptr, nullptr, nullptr);
    gemm9<0><<<gN1536, b512, 0, stream>>>(FFC, W2t, b2, Q_, nullptr, S_, D_, FF_,
                                          nullptr, nullptr, nullptr, nullptr);

    residgate_kernel<<<gSD, b256, 0, stream>>>(K_, Q_, e_ + 5 * D_, out);
}

// Round 10
// 1373.207 us; speedup vs baseline: 1.1859x; 1.0847x over previous
//
#include <hip/hip_runtime.h>
#include <math.h>

// ---------------------------------------------------------------------------
// Round 10: GEMM -> 128x128x64, 4 waves, 64KB dbuf => 2 blocks/CU (TLP is the
// measured dominant variable: r5's 3-blk/CU = 28%/CU beat every 1-blk/CU
// schedule at 12-17%). Counted vmcnt(8) + issue-early + setprio retained.
// ---------------------------------------------------------------------------

namespace {
constexpr int S_   = 4096;
constexpr int D_   = 1536;
constexpr int H_   = 12;
constexpr int L_   = 512;
constexpr int TOPK = 8;
constexpr int FF_  = 8960;
constexpr float EPS_   = 1e-6f;
constexpr float SCALE_ = 0.08838834764831845f;   // 128^-0.5
}

typedef __attribute__((ext_vector_type(8))) short short8;
typedef __attribute__((ext_vector_type(4))) float f32x4;

#define AS_GLOBAL __attribute__((address_space(1)))
#define AS_LDS    __attribute__((address_space(3)))

__device__ __forceinline__ short f2bf(float x) {
    uint32_t u = __float_as_uint(x);
    uint32_t r = (u + 0x7FFFu + ((u >> 16) & 1u)) >> 16;
    return (short)r;
}
__device__ __forceinline__ float bf2f(short s) {
    return __uint_as_float(((uint32_t)(uint16_t)s) << 16);
}
__device__ __forceinline__ float gelu_tanh(float x) {
    const float t = tanhf(0.7978845608028654f * (x + 0.044715f * x * x * x));
    return 0.5f * x * (1.f + t);
}

// ---------------------------- reductions -----------------------------------
__device__ __forceinline__ float block_sum_256(float v, float* red) {
#pragma unroll
    for (int off = 32; off > 0; off >>= 1) v += __shfl_down(v, off, 64);
    const int lane = threadIdx.x & 63, w = threadIdx.x >> 6;
    if (lane == 0) red[w] = v;
    __syncthreads();
    v = red[0] + red[1] + red[2] + red[3];
    __syncthreads();
    return v;
}

// ===================== 128x128x64 4-wave MFMA GEMM =========================
// C(M,N) = A(M,K) @ Bt(N,K)^T. 256 thr, 4 waves (2x2), per-wave 64x64 out.
// LDS: A[2][128x64] + B[2][128x64] = 64 KB -> 2 blocks/CU (the TLP lever).
// Pipeline/K-tile: STAGE(t+1) (8 loads/thr); vmcnt(8) [tail 0]; barrier;
// 16x ds_read_b128; lgkmcnt(0)+schedbar; barrier; setprio(1) 32 MFMA
// setprio(0). Unit swizzle u_phys = u ^ (row&7), both sides.
// EPI: 0 C=acc+bias ; 1 C+=acc ; 2 Cb=bf16(gelu(acc+bias)) ; 3 Cb=bf16(acc+b)
//      4 fused QKVG (N=6144): seg 0,1 -> f32 C+seg*SD ; seg 2,3 -> bf16 Cb
//      5 corr: A=Nb,Alo=Nlo; B k<1536 -> {Wql|Wkl}, k>=1536 -> {Wqh|Wkh};
//              row stride 1536; C(:,seg) += acc (seg = col>=1536)
template <int EPI>
__global__ __launch_bounds__(256, 2) void gemm10(
    const short* __restrict__ A, const short* __restrict__ Bt,
    const float* __restrict__ bias, float* __restrict__ C,
    short* __restrict__ Cb, int M, int N, int K,
    const short* __restrict__ Alo, const short* __restrict__ B2,
    const short* __restrict__ B3, const short* __restrict__ B4)
{
    __shared__ __align__(16) short As[2][128 * 64];
    __shared__ __align__(16) short Bs[2][128 * 64];
    const int tid = threadIdx.x;
    const int wid = tid >> 6, lane = tid & 63;
    const int wm = wid >> 1, wn = wid & 1;
    const int g16 = lane >> 4, l15 = lane & 15;

    // bijective XCD swizzle
    const int nwg = gridDim.x * gridDim.y;
    const int bid = blockIdx.y * gridDim.x + blockIdx.x;
    const int qq = nwg >> 3, r8 = nwg & 7;
    const int xcd = bid & 7, lid = bid >> 3;
    const int swz = ((xcd < r8) ? xcd * (qq + 1) : r8 * (qq + 1) + (xcd - r8) * qq) + lid;
    const int m0 = (swz / gridDim.x) * 128, n0 = (swz % gridDim.x) * 128;
    const int nseg = (n0 >= 1536) ? 1 : 0;       // EPI5 only

    f32x4 acc[4][4];
#pragma unroll
    for (int i = 0; i < 4; i++)
#pragma unroll
        for (int j = 0; j < 4; j++) acc[i][j] = (f32x4){0.f, 0.f, 0.f, 0.f};

    // staging map: 1024 16B-units per matrix tile, 4/thread each for A and B
    int sr[4], su[4];
#pragma unroll
    for (int i = 0; i < 4; i++) {
        const int c = tid + 256 * i;
        sr[i] = c >> 3;
        su[i] = (c & 7) ^ (sr[i] & 7);
    }

    const int lda = (EPI == 5) ? 1536 : K;
    auto STAGE = [&](int buf, int kt) {
        const short* asrc = A;
        const short* bsrc = Bt;
        int kl = kt, nb = n0;
        if (EPI == 5) {
            const int ks = (kt >= 1536);
            asrc = ks ? Alo : A;
            bsrc = nseg ? (ks ? B4 : B3) : (ks ? B2 : Bt);
            kl = kt - ks * 1536;
            nb = n0 - nseg * 1536;
        }
#pragma unroll
        for (int i = 0; i < 4; i++)
            __builtin_amdgcn_global_load_lds(
                (const AS_GLOBAL short*)(asrc + (size_t)(m0 + sr[i]) * lda + kl + su[i] * 8),
                (AS_LDS short*)(&As[buf][(tid + 256 * i) * 8]), 16, 0, 0);
#pragma unroll
        for (int i = 0; i < 4; i++)
            __builtin_amdgcn_global_load_lds(
                (const AS_GLOBAL short*)(bsrc + (size_t)(nb + sr[i]) * lda + kl + su[i] * 8),
                (AS_LDS short*)(&Bs[buf][(tid + 256 * i) * 8]), 16, 0, 0);
    };

    const int nk = K >> 6;
    STAGE(0, 0);

    int cur = 0;
    for (int t = 0; t < nk; ++t) {
        if (t + 1 < nk) {
            STAGE(cur ^ 1, (t + 1) << 6);
            asm volatile("s_waitcnt vmcnt(8)" ::: "memory");
        } else {
            asm volatile("s_waitcnt vmcnt(0)" ::: "memory");
        }
        __builtin_amdgcn_s_barrier();              // tile t fully in LDS
        __builtin_amdgcn_sched_barrier(0);

        short8 a[4][2], b[4][2];
#pragma unroll
        for (int mi = 0; mi < 4; mi++) {
            const int row = wm * 64 + mi * 16 + l15;
#pragma unroll
            for (int kk = 0; kk < 2; kk++) {
                const int u = (kk * 4 + g16) ^ (row & 7);
                a[mi][kk] = *(const short8*)(As[cur] + row * 64 + u * 8);
            }
        }
#pragma unroll
        for (int ni = 0; ni < 4; ni++) {
            const int row = wn * 64 + ni * 16 + l15;
#pragma unroll
            for (int kk = 0; kk < 2; kk++) {
                const int u = (kk * 4 + g16) ^ (row & 7);
                b[ni][kk] = *(const short8*)(Bs[cur] + row * 64 + u * 8);
            }
        }
        asm volatile("s_waitcnt lgkmcnt(0)" ::: "memory");
        __builtin_amdgcn_sched_barrier(0);
        __builtin_amdgcn_s_barrier();              // all waves done reading
        __builtin_amdgcn_sched_barrier(0);

        __builtin_amdgcn_s_setprio(1);
#pragma unroll
        for (int mi = 0; mi < 4; mi++)
#pragma unroll
            for (int ni = 0; ni < 4; ni++)
#pragma unroll
                for (int kk = 0; kk < 2; kk++)
                    acc[mi][ni] = __builtin_amdgcn_mfma_f32_16x16x32_bf16(
                        a[mi][kk], b[ni][kk], acc[mi][ni], 0, 0, 0);
        __builtin_amdgcn_s_setprio(0);

        cur ^= 1;
    }

    const size_t SD = (size_t)S_ * D_;
#pragma unroll
    for (int mi = 0; mi < 4; mi++) {
#pragma unroll
        for (int ni = 0; ni < 4; ni++) {
            const int col = n0 + wn * 64 + ni * 16 + l15;
            const float bv = (EPI == 1 || EPI == 5) ? 0.f : bias[col];
#pragma unroll
            for (int rr = 0; rr < 4; rr++) {
                const int row = m0 + wm * 64 + mi * 16 + g16 * 4 + rr;
                float v = acc[mi][ni][rr];
                if (EPI == 4) {
                    const int seg = col / 1536, cl = col - seg * 1536;
                    const float y = v + bv;
                    if (seg < 2) C[(size_t)seg * SD + (size_t)row * 1536 + cl] = y;
                    else Cb[(size_t)(seg - 2) * SD + (size_t)row * 1536 + cl] = f2bf(y);
                } else if (EPI == 5) {
                    const int seg = (col >= 1536) ? 1 : 0, cl = col - seg * 1536;
                    C[(size_t)seg * SD + (size_t)row * 1536 + cl] += v;
                } else {
                    const size_t o = (size_t)row * N + col;
                    if (EPI == 0) C[o] = v + bv;
                    else if (EPI == 1) C[o] += v;
                    else if (EPI == 2) Cb[o] = f2bf(gelu_tanh(v + bv));
                    else Cb[o] = f2bf(v + bv);
                }
            }
        }
    }
}

// ---------------------- weight transpose / convert -------------------------
template <int SPLIT>
__global__ __launch_bounds__(256) void transpose_w(
    const float* __restrict__ W, short* __restrict__ Th, short* __restrict__ Tl,
    int Kd, int Nd)
{
    __shared__ float tile[64][65];
    const int k0 = blockIdx.y * 64, n0 = blockIdx.x * 64;
    for (int f = threadIdx.x; f < 1024; f += 256) {
        const int rr = f >> 4, c4 = (f & 15) * 4;
        const float4 v = *(const float4*)(W + (size_t)(k0 + rr) * Nd + n0 + c4);
        tile[rr][c4 + 0] = v.x; tile[rr][c4 + 1] = v.y;
        tile[rr][c4 + 2] = v.z; tile[rr][c4 + 3] = v.w;
    }
    __syncthreads();
    for (int f = threadIdx.x; f < 1024; f += 256) {
        const int nn = f >> 4, k4 = (f & 15) * 4;
        short4 hv, lv;
        float w0 = tile[k4 + 0][nn], w1 = tile[k4 + 1][nn];
        float w2 = tile[k4 + 2][nn], w3 = tile[k4 + 3][nn];
        hv.x = f2bf(w0); hv.y = f2bf(w1); hv.z = f2bf(w2); hv.w = f2bf(w3);
        *(short4*)(Th + (size_t)(n0 + nn) * Kd + k0 + k4) = hv;
        if (SPLIT) {
            lv.x = f2bf(w0 - bf2f(hv.x)); lv.y = f2bf(w1 - bf2f(hv.y));
            lv.z = f2bf(w2 - bf2f(hv.z)); lv.w = f2bf(w3 - bf2f(hv.w));
            *(short4*)(Tl + (size_t)(n0 + nn) * Kd + k0 + k4) = lv;
        }
    }
}

__global__ void cvt_bf16_kernel(const float* __restrict__ x, short* __restrict__ y, int n4)
{
    const int i = blockIdx.x * 256 + threadIdx.x;
    if (i >= n4) return;
    const float4 v = *(const float4*)(x + (size_t)i * 4);
    short4 o; o.x = f2bf(v.x); o.y = f2bf(v.y); o.z = f2bf(v.z); o.w = f2bf(v.w);
    *(short4*)(y + (size_t)i * 4) = o;
}

__global__ void fill_bcat(const float* __restrict__ bq, const float* __restrict__ bk,
                          const float* __restrict__ bv, const float* __restrict__ bg,
                          float* __restrict__ bcat)
{
    const int i = blockIdx.x * 256 + threadIdx.x;
    if (i >= 6144) return;
    const int seg = i / 1536, c = i - seg * 1536;
    const float* src = (seg == 0) ? bq : (seg == 1) ? bk : (seg == 2) ? bv : bg;
    bcat[i] = src[c];
}

// --------------------- LayerNorm (bf16 out, optional split) -----------------
template <int ADD1, int SPLIT>
__global__ __launch_bounds__(256) void ln_bf16(
    const float* __restrict__ x, short* __restrict__ hi, short* __restrict__ lo,
    const float* __restrict__ g, const float* __restrict__ b)
{
    __shared__ float red[4];
    const size_t s = blockIdx.x;
    const float* xr = x + s * D_;
    float v[6];
    float sm = 0.f;
#pragma unroll
    for (int i = 0; i < 6; i++) { v[i] = xr[threadIdx.x + 256 * i]; sm += v[i]; }
    sm = block_sum_256(sm, red);
    const float mean = sm * (1.f / D_);
    float vs = 0.f;
#pragma unroll
    for (int i = 0; i < 6; i++) { const float d = v[i] - mean; vs += d * d; }
    vs = block_sum_256(vs, red);
    const float rs = rsqrtf(vs * (1.f / D_) + EPS_);
#pragma unroll
    for (int i = 0; i < 6; i++) {
        const int d = threadIdx.x + 256 * i;
        const float y = (v[i] - mean) * rs * (g[d] + (float)ADD1) + b[d];
        const short h = f2bf(y);
        hi[s * D_ + d] = h;
        if (SPLIT) lo[s * D_ + d] = f2bf(y - bf2f(h));
    }
}

__global__ __launch_bounds__(256) void rms_kernel(float* __restrict__ x,
                                                  const float* __restrict__ w)
{
    __shared__ float red[4];
    const size_t s = blockIdx.x;
    float* xr = x + s * D_;
    float v[6];
    float ss = 0.f;
#pragma unroll
    for (int i = 0; i < 6; i++) { v[i] = xr[threadIdx.x + 256 * i]; ss += v[i] * v[i]; }
    ss = block_sum_256(ss, red);
    const float rs = rsqrtf(ss * (1.f / D_) + EPS_);
#pragma unroll
    for (int i = 0; i < 6; i++) {
        const int d = threadIdx.x + 256 * i;
        xr[d] = v[i] * rs * w[d];
    }
}

// --------------- fused RMS + RoPE for Q and K (in-place) -------------------
__global__ __launch_bounds__(256) void rmsrope_qk(
    float* __restrict__ Q, float* __restrict__ K,
    const float* __restrict__ nqw, const float* __restrict__ nkw,
    const float* __restrict__ cosT, const float* __restrict__ sinT)
{
    __shared__ float red[4];
    const size_t s = blockIdx.x;
    const int tid = threadIdx.x;

#pragma unroll
    for (int m = 0; m < 2; m++) {
        float* X = m ? K : Q;
        const float* w = m ? nkw : nqw;
        float2 v[3];
        float ss = 0.f;
#pragma unroll
        for (int j = 0; j < 3; j++) {
            v[j] = *(const float2*)(X + s * D_ + 2 * (tid + 256 * j));
            ss += v[j].x * v[j].x + v[j].y * v[j].y;
        }
        ss = block_sum_256(ss, red);
        const float rs = rsqrtf(ss * (1.f / D_) + EPS_);
#pragma unroll
        for (int j = 0; j < 3; j++) {
            const int p = tid + 256 * j;
            const int i = p & 63;
            const float c = cosT[s * 64 + i], sn = sinT[s * 64 + i];
            const float x1 = v[j].x * rs * w[2 * p];
            const float x2 = v[j].y * rs * w[2 * p + 1];
            float2 o;
            o.x = x1 * c - x2 * sn;
            o.y = x2 * c + x1 * sn;
            *(float2*)(X + s * D_ + 2 * p) = o;
        }
    }
}

// --------------------------- elementwise -----------------------------------
__global__ void add_kernel(const float* __restrict__ a, const float* __restrict__ b,
                           float* __restrict__ o, int n)
{
    const int i = blockIdx.x * 256 + threadIdx.x;
    if (i < n) o[i] = a[i] + b[i];
}

__global__ void residgate_kernel(const float* __restrict__ h, const float* __restrict__ x,
                                 const float* __restrict__ gate, float* __restrict__ o)
{
    const int i = blockIdx.x * 256 + threadIdx.x;
    if (i < S_ * D_) { const int d = i % D_; o[i] = h[i] + x[i] * gate[d]; }
}

// ------------------------- VSA coarse path ---------------------------------
__global__ __launch_bounds__(128) void blockmean_f32(const float* __restrict__ q,
                                                     float* __restrict__ qc)
{
    const int hb = blockIdx.x;
    const int h = hb >> 6, j = hb & 63;
    const int d = threadIdx.x;
    float sum = 0.f;
    for (int t = 0; t < 64; t++)
        sum += q[(size_t)(j * 64 + t) * D_ + h * 128 + d];
    qc[(size_t)hb * 128 + d] = sum * (1.f / 64.f);
}

__global__ __launch_bounds__(128) void blockmean_bf16(const short* __restrict__ q,
                                                      float* __restrict__ qc)
{
    const int hb = blockIdx.x;
    const int h = hb >> 6, j = hb & 63;
    const int d = threadIdx.x;
    float sum = 0.f;
    for (int t = 0; t < 64; t++)
        sum += bf2f(q[(size_t)(j * 64 + t) * D_ + h * 128 + d]);
    qc[(size_t)hb * 128 + d] = sum * (1.f / 64.f);
}

__global__ __launch_bounds__(64) void coarse_kernel(
    const float* __restrict__ qc, const float* __restrict__ kc,
    const float* __restrict__ vc, float* __restrict__ oc, int* __restrict__ idxout)
{
    const int hb = blockIdx.x;
    const int h = hb >> 6, i = hb & 63;
    const int lane = threadIdx.x;
    __shared__ float p[64];

    const float* qv = qc + (size_t)hb * 128;
    const float* kv = kc + (size_t)((h << 6) + lane) * 128;
    float sc = 0.f;
    for (int d = 0; d < 128; d++) sc = fmaf(qv[d], kv[d], sc);
    sc *= SCALE_;

    float mx = sc;
#pragma unroll
    for (int off = 32; off > 0; off >>= 1) mx = fmaxf(mx, __shfl_xor(mx, off, 64));
    const float e = expf(sc - mx);
    float sumv = e;
#pragma unroll
    for (int off = 32; off > 0; off >>= 1) sumv += __shfl_xor(sumv, off, 64);
    const float pv = e / sumv;
    p[lane] = pv;
    __syncthreads();

    float o0 = 0.f, o1 = 0.f;
    for (int j = 0; j < 64; j++) {
        const float pj = p[j];
        const float* vr = vc + (size_t)((h << 6) + j) * 128;
        o0 = fmaf(pj, vr[lane], o0);
        o1 = fmaf(pj, vr[lane + 64], o1);
    }
    oc[(size_t)hb * 128 + lane]      = o0;
    oc[(size_t)hb * 128 + lane + 64] = o1;

    float v = pv;
    for (int t = 0; t < TOPK; t++) {
        float bv = v; int bi = lane;
#pragma unroll
        for (int off = 32; off > 0; off >>= 1) {
            const float ov = __shfl_xor(bv, off, 64);
            const int   oi = __shfl_xor(bi, off, 64);
            if (ov > bv || (ov == bv && oi < bi)) { bv = ov; bi = oi; }
        }
        if (lane == 0) idxout[hb * TOPK + t] = bi;
        if (lane == bi) v = -1.f;
    }
}

// ---------------------- MFMA flash attention -------------------------------
template <int MODE>
__global__ __launch_bounds__(256) void attn_mfma(
    const float* __restrict__ Qf, const float* __restrict__ Kf,
    const short* __restrict__ Vbb, const float* __restrict__ Vff,
    const short* __restrict__ Gb, const float* __restrict__ ocp,
    const int* __restrict__ idxp, short* __restrict__ Ob)
{
    const int hb = blockIdx.x, h = hb >> 6, ib = hb & 63;
    const int tid = threadIdx.x, wid = tid >> 6, lane = tid & 63;
    const int g16 = lane >> 4, l15 = lane & 15;

    __shared__ __align__(16) short Ks[64 * 128];
    __shared__ __align__(16) short Vst[128 * 64];
    __shared__ __align__(16) short Ps[64 * 80];
    __shared__ int sel[8];
    if (tid < 8) sel[tid] = (MODE == 0) ? idxp[hb * 8 + tid] : tid;

    short8 qa[4];
    {
        const float* qrow = Qf + (size_t)(ib * 64 + wid * 16 + l15) * D_ + h * 128;
#pragma unroll
        for (int kk = 0; kk < 4; kk++) {
            const float4 f0 = *(const float4*)(qrow + kk * 32 + g16 * 8);
            const float4 f1 = *(const float4*)(qrow + kk * 32 + g16 * 8 + 4);
            short8 v;
            v[0] = f2bf(f0.x); v[1] = f2bf(f0.y); v[2] = f2bf(f0.z); v[3] = f2bf(f0.w);
            v[4] = f2bf(f1.x); v[5] = f2bf(f1.y); v[6] = f2bf(f1.z); v[7] = f2bf(f1.w);
            qa[kk] = v;
        }
    }

    f32x4 o[8];
#pragma unroll
    for (int n2 = 0; n2 < 8; n2++) o[n2] = (f32x4){0.f, 0.f, 0.f, 0.f};
    float mrow[4] = {-3e38f, -3e38f, -3e38f, -3e38f};
    float lrow[4] = {0.f, 0.f, 0.f, 0.f};
    __syncthreads();

    for (int t = 0; t < 8; t++) {
        const int jb = sel[t];
#pragma unroll
        for (int it = 0; it < 4; it++) {
            const int c = tid + 256 * it;
            const int key = c >> 4, d8 = (c & 15) * 8;
            const float* src = Kf + (size_t)(jb * 64 + key) * D_ + h * 128 + d8;
            const float4 f0 = *(const float4*)src;
            const float4 f1 = *(const float4*)(src + 4);
            short8 v;
            v[0] = f2bf(f0.x); v[1] = f2bf(f0.y); v[2] = f2bf(f0.z); v[3] = f2bf(f0.w);
            v[4] = f2bf(f1.x); v[5] = f2bf(f1.y); v[6] = f2bf(f1.z); v[7] = f2bf(f1.w);
            const int byte = (key * 256 + d8 * 2) ^ ((key & 7) << 4);
            *(short8*)((char*)Ks + byte) = v;
        }
#pragma unroll
        for (int it = 0; it < 4; it++) {
            const int c = tid + 256 * it;
            const int key = c & 63, d8 = (c >> 6) * 8;
            float vv[8];
            if (MODE == 0) {
                const short8 v = *(const short8*)(Vbb + (size_t)(jb * 64 + key) * D_ + h * 128 + d8);
#pragma unroll
                for (int j = 0; j < 8; j++) vv[j] = bf2f(v[j]);
            } else {
                const float* src = Vff + (size_t)(jb * 64 + key) * D_ + h * 128 + d8;
                const float4 f0 = *(const float4*)src;
                const float4 f1 = *(const float4*)(src + 4);
                vv[0] = f0.x; vv[1] = f0.y; vv[2] = f0.z; vv[3] = f0.w;
                vv[4] = f1.x; vv[5] = f1.y; vv[6] = f1.z; vv[7] = f1.w;
            }
#pragma unroll
            for (int j = 0; j < 8; j++) {
                const int dim = d8 + j;
                const int byte = (dim * 128 + key * 2) ^ ((dim & 7) << 4);
                *(short*)((char*)Vst + byte) = f2bf(vv[j]);
            }
        }
        __syncthreads();

        f32x4 s[4];
#pragma unroll
        for (int nt = 0; nt < 4; nt++) {
            f32x4 acc = (f32x4){0.f, 0.f, 0.f, 0.f};
            const int key = nt * 16 + l15;
#pragma unroll
            for (int kk = 0; kk < 4; kk++) {
                const int byte = (key * 256 + (kk * 32 + g16 * 8) * 2) ^ ((key & 7) << 4);
                const short8 b = *(const short8*)((char*)Ks + byte);
                acc = __builtin_amdgcn_mfma_f32_16x16x32_bf16(qa[kk], b, acc, 0, 0, 0);
            }
            s[nt] = acc;
        }
#pragma unroll
        for (int nt = 0; nt < 4; nt++)
#pragma unroll
            for (int rr = 0; rr < 4; rr++) s[nt][rr] *= SCALE_;

        float alpha[4];
#pragma unroll
        for (int rr = 0; rr < 4; rr++) {
            float v = fmaxf(fmaxf(s[0][rr], s[1][rr]), fmaxf(s[2][rr], s[3][rr]));
            v = fmaxf(v, __shfl_xor(v, 1, 64));
            v = fmaxf(v, __shfl_xor(v, 2, 64));
            v = fmaxf(v, __shfl_xor(v, 4, 64));
            v = fmaxf(v, __shfl_xor(v, 8, 64));
            const float mn = fmaxf(mrow[rr], v);
            alpha[rr] = expf(mrow[rr] - mn);
            mrow[rr] = mn;
        }
        float rs[4] = {0.f, 0.f, 0.f, 0.f};
#pragma unroll
        for (int nt = 0; nt < 4; nt++)
#pragma unroll
            for (int rr = 0; rr < 4; rr++) {
                const float p = expf(s[nt][rr] - mrow[rr]);
                s[nt][rr] = p;
                rs[rr] += p;
            }
#pragma unroll
        for (int rr = 0; rr < 4; rr++) {
            float v = rs[rr];
            v += __shfl_xor(v, 1, 64);
            v += __shfl_xor(v, 2, 64);
            v += __shfl_xor(v, 4, 64);
            v += __shfl_xor(v, 8, 64);
            lrow[rr] = lrow[rr] * alpha[rr] + v;
        }
#pragma unroll
        for (int n2 = 0; n2 < 8; n2++)
#pragma unroll
            for (int rr = 0; rr < 4; rr++) o[n2][rr] *= alpha[rr];

#pragma unroll
        for (int nt = 0; nt < 4; nt++)
#pragma unroll
            for (int rr = 0; rr < 4; rr++)
                Ps[(wid * 16 + g16 * 4 + rr) * 80 + nt * 16 + l15] = f2bf(s[nt][rr]);

#pragma unroll
        for (int kk2 = 0; kk2 < 2; kk2++) {
            const short8 pa = *(const short8*)(Ps + (wid * 16 + l15) * 80 + kk2 * 32 + g16 * 8);
#pragma unroll
            for (int n2 = 0; n2 < 8; n2++) {
                const int dim = n2 * 16 + l15;
                const int byte = (dim * 128 + (kk2 * 32 + g16 * 8) * 2) ^ ((dim & 7) << 4);
                const short8 vb = *(const short8*)((char*)Vst + byte);
                o[n2] = __builtin_amdgcn_mfma_f32_16x16x32_bf16(pa, vb, o[n2], 0, 0, 0);
            }
        }
        __syncthreads();
    }

#pragma unroll
    for (int n2 = 0; n2 < 8; n2++) {
        const int col = n2 * 16 + l15;
        const float ocv = (MODE == 0) ? ocp[(size_t)hb * 128 + col] : 0.f;
#pragma unroll
        for (int rr = 0; rr < 4; rr++) {
            const int row = ib * 64 + wid * 16 + g16 * 4 + rr;
            float val = o[n2][rr] / lrow[rr];
            if (MODE == 0)
                val += ocv * bf2f(Gb[(size_t)row * D_ + h * 128 + col]);
            Ob[(size_t)row * D_ + h * 128 + col] = f2bf(val);
        }
    }
}

// ---------------------------------------------------------------------------
extern "C" void kernel_launch(void* const* d_in, const int* in_sizes, int n_in,
                              void* d_out, int out_size, void* d_ws, size_t ws_size,
                              hipStream_t stream)
{
    const float* h_in = (const float*)d_in[0];
    const float* enc  = (const float*)d_in[1];
    const float* temb = (const float*)d_in[2];
    const float* cosT = (const float*)d_in[3];
    const float* sinT = (const float*)d_in[4];
    const float* sst  = (const float*)d_in[5];
    const float* Wq = (const float*)d_in[6];   const float* bq = (const float*)d_in[7];
    const float* Wk = (const float*)d_in[8];   const float* bk = (const float*)d_in[9];
    const float* Wv = (const float*)d_in[10];  const float* bv = (const float*)d_in[11];
    const float* Wg = (const float*)d_in[12];  const float* bg = (const float*)d_in[13];
    const float* Wo = (const float*)d_in[14];  const float* bo = (const float*)d_in[15];
    const float* nq_w  = (const float*)d_in[16];
    const float* nk_w  = (const float*)d_in[17];
    const float* ln1_w = (const float*)d_in[18];
    const float* ln1_b = (const float*)d_in[19];
    const float* cWq = (const float*)d_in[20]; const float* cbq = (const float*)d_in[21];
    const float* cWk = (const float*)d_in[22]; const float* cbk = (const float*)d_in[23];
    const float* cWv = (const float*)d_in[24]; const float* cbv = (const float*)d_in[25];
    const float* cWo = (const float*)d_in[26]; const float* cbo = (const float*)d_in[27];
    const float* cnq_w = (const float*)d_in[28];
    const float* cnk_w = (const float*)d_in[29];
    const float* W1 = (const float*)d_in[30];  const float* b1 = (const float*)d_in[31];
    const float* W2 = (const float*)d_in[32];  const float* b2 = (const float*)d_in[33];
    float* out = (float*)d_out;

    char* base = (char*)d_ws;
    size_t off = 0;
    auto alloc = [&](size_t bytes) {
        char* p = base + off;
        off += (bytes + 255) & ~(size_t)255;
        return p;
    };
    const size_t SD = (size_t)S_ * D_;
    float* e_   = (float*)alloc(6 * D_ * 4);
    float* Q_   = (float*)alloc(SD * 4);       // Q_ and K_ adjacent (EPI4/5)
    float* K_   = (float*)alloc(SD * 4);
    float* CK_  = (float*)alloc((size_t)L_ * D_ * 4);
    float* CV_  = (float*)alloc((size_t)L_ * D_ * 4);
    float* qc_  = (float*)alloc((size_t)H_ * 64 * 128 * 4);
    float* kc_  = (float*)alloc((size_t)H_ * 64 * 128 * 4);
    float* vc_  = (float*)alloc((size_t)H_ * 64 * 128 * 4);
    float* oc_  = (float*)alloc((size_t)H_ * 64 * 128 * 4);
    int*   idx_ = (int*)alloc((size_t)H_ * 64 * TOPK * 4);
    short* Nb   = (short*)alloc(SD * 2);
    // ---- FFC alias region: Nlo .. Wkl (~80 MB, all dead by FFN) ----
    short* Nlo  = (short*)alloc(SD * 2);
    short* Vb   = (short*)alloc(SD * 2);       // Vb and Gb adjacent (EPI4)
    short* Gb   = (short*)alloc(SD * 2);
    short* attn_b = (short*)alloc(SD * 2);
    short* enc_b  = (short*)alloc((size_t)L_ * D_ * 2);
    const size_t WDD = (size_t)D_ * D_;
    short* Wqh = (short*)alloc(WDD * 2);       // Wqh,Wkh,Wvt,Wgt contiguous =
    short* Wkh = (short*)alloc(WDD * 2);       // N=6144 concat B for fused proj
    short* Wvt = (short*)alloc(WDD * 2);
    short* Wgt = (short*)alloc(WDD * 2);
    short* Wql = (short*)alloc(WDD * 2);
    short* Wkl = (short*)alloc(WDD * 2);
    // ---- end alias region ----
    short* Wot = (short*)alloc(WDD * 2);
    short* cWqt = (short*)alloc(WDD * 2); short* cWkt = (short*)alloc(WDD * 2);
    short* cWvt = (short*)alloc(WDD * 2); short* cWot = (short*)alloc(WDD * 2);
    short* W1t = (short*)alloc((size_t)D_ * FF_ * 2);
    short* W2t = (short*)alloc((size_t)D_ * FF_ * 2);
    float* bcat = (float*)alloc(6144 * 4);
    short* FFC = Nlo;   // S x FF bf16 (73.4 MB) over dead region (80 MB)

    const dim3 b256(256);
    const int nSD = S_ * D_;
    const dim3 gSD((nSD + 255) / 256);
    const dim3 gDD(D_ / 64, D_ / 64);
    const dim3 gN1536(D_ / 128, S_ / 128);     // (12,32) = 384 blocks

    add_kernel<<<dim3((6 * D_ + 255) / 256), b256, 0, stream>>>(sst, temb, e_, 6 * D_);
    ln_bf16<1, 1><<<dim3(S_), b256, 0, stream>>>(h_in, Nb, Nlo, e_ + D_, e_);
    fill_bcat<<<dim3(24), b256, 0, stream>>>(bq, bk, bv, bg, bcat);

    transpose_w<1><<<gDD, b256, 0, stream>>>(Wq, Wqh, Wql, D_, D_);
    transpose_w<1><<<gDD, b256, 0, stream>>>(Wk, Wkh, Wkl, D_, D_);
    transpose_w<0><<<gDD, b256, 0, stream>>>(Wv, Wvt, nullptr, D_, D_);
    transpose_w<0><<<gDD, b256, 0, stream>>>(Wg, Wgt, nullptr, D_, D_);
    transpose_w<0><<<gDD, b256, 0, stream>>>(Wo, Wot, nullptr, D_, D_);
    transpose_w<0><<<gDD, b256, 0, stream>>>(cWq, cWqt, nullptr, D_, D_);
    transpose_w<0><<<gDD, b256, 0, stream>>>(cWk, cWkt, nullptr, D_, D_);
    transpose_w<0><<<gDD, b256, 0, stream>>>(cWv, cWvt, nullptr, D_, D_);
    transpose_w<0><<<gDD, b256, 0, stream>>>(cWo, cWot, nullptr, D_, D_);
    transpose_w<0><<<dim3(FF_ / 64, D_ / 64), b256, 0, stream>>>(W1, W1t, nullptr, D_, FF_);
    transpose_w<0><<<dim3(D_ / 64, FF_ / 64), b256, 0, stream>>>(W2, W2t, nullptr, FF_, D_);
    cvt_bf16_kernel<<<dim3((L_ * D_ / 4 + 255) / 256), b256, 0, stream>>>(enc, enc_b, L_ * D_ / 4);

    // fused QKVG projection (hi) + K-concat correction (q,k exactness)
    gemm10<4><<<dim3(6144 / 128, S_ / 128), b256, 0, stream>>>(
        Nb, Wqh, bcat, Q_, Vb, S_, 6144, D_, nullptr, nullptr, nullptr, nullptr);
    gemm10<5><<<dim3(3072 / 128, S_ / 128), b256, 0, stream>>>(
        Nb, Wql, nullptr, Q_, nullptr, S_, 3072, 3072, Nlo, Wqh, Wkl, Wkh);

    // fused rms + rope for q,k
    rmsrope_qk<<<dim3(S_), b256, 0, stream>>>(Q_, K_, nq_w, nk_w, cosT, sinT);

    blockmean_f32<<<dim3(H_ * 64), dim3(128), 0, stream>>>(Q_, qc_);
    blockmean_f32<<<dim3(H_ * 64), dim3(128), 0, stream>>>(K_, kc_);
    blockmean_bf16<<<dim3(H_ * 64), dim3(128), 0, stream>>>(Vb, vc_);
    coarse_kernel<<<dim3(H_ * 64), dim3(64), 0, stream>>>(qc_, kc_, vc_, oc_, idx_);

    attn_mfma<0><<<dim3(H_ * 64), b256, 0, stream>>>(
        Q_, K_, Vb, nullptr, Gb, oc_, idx_, attn_b);

    gemm10<0><<<gN1536, b256, 0, stream>>>(attn_b, Wot, bo, Q_, nullptr, S_, D_, D_,
                                           nullptr, nullptr, nullptr, nullptr);
    residgate_kernel<<<gSD, b256, 0, stream>>>(h_in, Q_, e_ + 2 * D_, K_);

    ln_bf16<0, 0><<<dim3(S_), b256, 0, stream>>>(K_, Nb, nullptr, ln1_w, ln1_b);
    gemm10<0><<<gN1536, b256, 0, stream>>>(Nb, cWqt, cbq, Q_, nullptr, S_, D_, D_,
                                           nullptr, nullptr, nullptr, nullptr);
    rms_kernel<<<dim3(S_), b256, 0, stream>>>(Q_, cnq_w);

    const dim3 gLenc(D_ / 128, L_ / 128);      // (12,4)
    gemm10<0><<<gLenc, b256, 0, stream>>>(enc_b, cWkt, cbk, CK_, nullptr, L_, D_, D_,
                                          nullptr, nullptr, nullptr, nullptr);
    rms_kernel<<<dim3(L_), b256, 0, stream>>>(CK_, cnk_w);
    gemm10<0><<<gLenc, b256, 0, stream>>>(enc_b, cWvt, cbv, CV_, nullptr, L_, D_, D_,
                                          nullptr, nullptr, nullptr, nullptr);

    attn_mfma<1><<<dim3(H_ * 64), b256, 0, stream>>>(
        Q_, CK_, nullptr, CV_, nullptr, nullptr, nullptr, attn_b);
    gemm10<0><<<gN1536, b256, 0, stream>>>(attn_b, cWot, cbo, Q_, nullptr, S_, D_, D_,
                                           nullptr, nullptr, nullptr, nullptr);
    add_kernel<<<gSD, b256, 0, stream>>>(K_, Q_, K_, nSD);

    ln_bf16<1, 0><<<dim3(S_), b256, 0, stream>>>(K_, Nb, nullptr, e_ + 4 * D_, e_ + 3 * D_);
    gemm10<2><<<dim3(FF_ / 128, S_ / 128), b256, 0, stream>>>(
        Nb, W1t, b1, nullptr, FFC, S_, FF_, D_, nullptr, nullptr, nullptr, nullptr);
    gemm10<0><<<gN1536, b256, 0, stream>>>(FFC, W2t, b2, Q_, nullptr, S_, D_, FF_,
                                           nullptr, nullptr, nullptr, nullptr);

    residgate_kernel<<<gSD, b256, 0, stream>>>(K_, Q_, e_ + 5 * D_, out);
}

// Round 11
// 1370.056 us; speedup vs baseline: 1.1887x; 1.0023x over previous
//
#include <hip/hip_runtime.h>
#include <math.h>

// ---------------------------------------------------------------------------
// Round 11: round 10 + L2-blocked rasterization. After the bijective XCD
// swizzle, the linear tile index walks 4-row M-stripes (M fast, N slow) so
// consecutive blocks per XCD reuse the B-panel (4x) and a 1.6MB A-set in L2.
// r10 counters: W1 FETCH=443MB vs 40MB ideal (B streamed per block).
// ---------------------------------------------------------------------------

namespace {
constexpr int S_   = 4096;
constexpr int D_   = 1536;
constexpr int H_   = 12;
constexpr int L_   = 512;
constexpr int TOPK = 8;
constexpr int FF_  = 8960;
constexpr float EPS_   = 1e-6f;
constexpr float SCALE_ = 0.08838834764831845f;   // 128^-0.5
}

typedef __attribute__((ext_vector_type(8))) short short8;
typedef __attribute__((ext_vector_type(4))) float f32x4;

#define AS_GLOBAL __attribute__((address_space(1)))
#define AS_LDS    __attribute__((address_space(3)))

__device__ __forceinline__ short f2bf(float x) {
    uint32_t u = __float_as_uint(x);
    uint32_t r = (u + 0x7FFFu + ((u >> 16) & 1u)) >> 16;
    return (short)r;
}
__device__ __forceinline__ float bf2f(short s) {
    return __uint_as_float(((uint32_t)(uint16_t)s) << 16);
}
__device__ __forceinline__ float gelu_tanh(float x) {
    const float t = tanhf(0.7978845608028654f * (x + 0.044715f * x * x * x));
    return 0.5f * x * (1.f + t);
}

// ---------------------------- reductions -----------------------------------
__device__ __forceinline__ float block_sum_256(float v, float* red) {
#pragma unroll
    for (int off = 32; off > 0; off >>= 1) v += __shfl_down(v, off, 64);
    const int lane = threadIdx.x & 63, w = threadIdx.x >> 6;
    if (lane == 0) red[w] = v;
    __syncthreads();
    v = red[0] + red[1] + red[2] + red[3];
    __syncthreads();
    return v;
}

// ===================== 128x128x64 4-wave MFMA GEMM =========================
// Geometry/pipeline identical to r10 (2 blocks/CU, counted vmcnt(8),
// issue-early STAGE, setprio, both-sides swizzle). NEW: L2-blocked raster.
// EPI: 0 C=acc+bias ; 1 C+=acc ; 2 Cb=bf16(gelu(acc+bias)) ; 3 Cb=bf16(acc+b)
//      4 fused QKVG (N=6144): seg 0,1 -> f32 C+seg*SD ; seg 2,3 -> bf16 Cb
//      5 corr: A=Nb,Alo=Nlo; B k<1536 -> {Wql|Wkl}, k>=1536 -> {Wqh|Wkh};
//              row stride 1536; C(:,seg) += acc (seg = col>=1536)
template <int EPI>
__global__ __launch_bounds__(256, 2) void gemm11(
    const short* __restrict__ A, const short* __restrict__ Bt,
    const float* __restrict__ bias, float* __restrict__ C,
    short* __restrict__ Cb, int M, int N, int K,
    const short* __restrict__ Alo, const short* __restrict__ B2,
    const short* __restrict__ B3, const short* __restrict__ B4)
{
    __shared__ __align__(16) short As[2][128 * 64];
    __shared__ __align__(16) short Bs[2][128 * 64];
    const int tid = threadIdx.x;
    const int wid = tid >> 6, lane = tid & 63;
    const int wm = wid >> 1, wn = wid & 1;
    const int g16 = lane >> 4, l15 = lane & 15;

    // bijective XCD swizzle (contiguous chunk per XCD)
    const int gx = gridDim.x;
    const int nwg = gx * gridDim.y;
    const int bid = blockIdx.y * gx + blockIdx.x;
    const int qq = nwg >> 3, r8 = nwg & 7;
    const int xcd = bid & 7, lid = bid >> 3;
    const int swz = ((xcd < r8) ? xcd * (qq + 1) : r8 * (qq + 1) + (xcd - r8) * qq) + lid;
    // L2-blocked raster: 4-row M-stripes, M fast, N slow (Mt % 4 == 0).
    const int stripe = swz / (4 * gx);
    const int within = swz - stripe * (4 * gx);
    const int mI = stripe * 4 + (within & 3);
    const int nI = within >> 2;
    const int m0 = mI * 128, n0 = nI * 128;
    const int nseg = (n0 >= 1536) ? 1 : 0;       // EPI5 only

    f32x4 acc[4][4];
#pragma unroll
    for (int i = 0; i < 4; i++)
#pragma unroll
        for (int j = 0; j < 4; j++) acc[i][j] = (f32x4){0.f, 0.f, 0.f, 0.f};

    // staging map: 1024 16B-units per matrix tile, 4/thread each for A and B
    int sr[4], su[4];
#pragma unroll
    for (int i = 0; i < 4; i++) {
        const int c = tid + 256 * i;
        sr[i] = c >> 3;
        su[i] = (c & 7) ^ (sr[i] & 7);
    }

    const int lda = (EPI == 5) ? 1536 : K;
    auto STAGE = [&](int buf, int kt) {
        const short* asrc = A;
        const short* bsrc = Bt;
        int kl = kt, nb = n0;
        if (EPI == 5) {
            const int ks = (kt >= 1536);
            asrc = ks ? Alo : A;
            bsrc = nseg ? (ks ? B4 : B3) : (ks ? B2 : Bt);
            kl = kt - ks * 1536;
            nb = n0 - nseg * 1536;
        }
#pragma unroll
        for (int i = 0; i < 4; i++)
            __builtin_amdgcn_global_load_lds(
                (const AS_GLOBAL short*)(asrc + (size_t)(m0 + sr[i]) * lda + kl + su[i] * 8),
                (AS_LDS short*)(&As[buf][(tid + 256 * i) * 8]), 16, 0, 0);
#pragma unroll
        for (int i = 0; i < 4; i++)
            __builtin_amdgcn_global_load_lds(
                (const AS_GLOBAL short*)(bsrc + (size_t)(nb + sr[i]) * lda + kl + su[i] * 8),
                (AS_LDS short*)(&Bs[buf][(tid + 256 * i) * 8]), 16, 0, 0);
    };

    const int nk = K >> 6;
    STAGE(0, 0);

    int cur = 0;
    for (int t = 0; t < nk; ++t) {
        if (t + 1 < nk) {
            STAGE(cur ^ 1, (t + 1) << 6);
            asm volatile("s_waitcnt vmcnt(8)" ::: "memory");
        } else {
            asm volatile("s_waitcnt vmcnt(0)" ::: "memory");
        }
        __builtin_amdgcn_s_barrier();              // tile t fully in LDS
        __builtin_amdgcn_sched_barrier(0);

        short8 a[4][2], b[4][2];
#pragma unroll
        for (int mi = 0; mi < 4; mi++) {
            const int row = wm * 64 + mi * 16 + l15;
#pragma unroll
            for (int kk = 0; kk < 2; kk++) {
                const int u = (kk * 4 + g16) ^ (row & 7);
                a[mi][kk] = *(const short8*)(As[cur] + row * 64 + u * 8);
            }
        }
#pragma unroll
        for (int ni = 0; ni < 4; ni++) {
            const int row = wn * 64 + ni * 16 + l15;
#pragma unroll
            for (int kk = 0; kk < 2; kk++) {
                const int u = (kk * 4 + g16) ^ (row & 7);
                b[ni][kk] = *(const short8*)(Bs[cur] + row * 64 + u * 8);
            }
        }
        asm volatile("s_waitcnt lgkmcnt(0)" ::: "memory");
        __builtin_amdgcn_sched_barrier(0);
        __builtin_amdgcn_s_barrier();              // all waves done reading
        __builtin_amdgcn_sched_barrier(0);

        __builtin_amdgcn_s_setprio(1);
#pragma unroll
        for (int mi = 0; mi < 4; mi++)
#pragma unroll
            for (int ni = 0; ni < 4; ni++)
#pragma unroll
                for (int kk = 0; kk < 2; kk++)
                    acc[mi][ni] = __builtin_amdgcn_mfma_f32_16x16x32_bf16(
                        a[mi][kk], b[ni][kk], acc[mi][ni], 0, 0, 0);
        __builtin_amdgcn_s_setprio(0);

        cur ^= 1;
    }

    const size_t SD = (size_t)S_ * D_;
#pragma unroll
    for (int mi = 0; mi < 4; mi++) {
#pragma unroll
        for (int ni = 0; ni < 4; ni++) {
            const int col = n0 + wn * 64 + ni * 16 + l15;
            const float bv = (EPI == 1 || EPI == 5) ? 0.f : bias[col];
#pragma unroll
            for (int rr = 0; rr < 4; rr++) {
                const int row = m0 + wm * 64 + mi * 16 + g16 * 4 + rr;
                float v = acc[mi][ni][rr];
                if (EPI == 4) {
                    const int seg = col / 1536, cl = col - seg * 1536;
                    const float y = v + bv;
                    if (seg < 2) C[(size_t)seg * SD + (size_t)row * 1536 + cl] = y;
                    else Cb[(size_t)(seg - 2) * SD + (size_t)row * 1536 + cl] = f2bf(y);
                } else if (EPI == 5) {
                    const int seg = (col >= 1536) ? 1 : 0, cl = col - seg * 1536;
                    C[(size_t)seg * SD + (size_t)row * 1536 + cl] += v;
                } else {
                    const size_t o = (size_t)row * N + col;
                    if (EPI == 0) C[o] = v + bv;
                    else if (EPI == 1) C[o] += v;
                    else if (EPI == 2) Cb[o] = f2bf(gelu_tanh(v + bv));
                    else Cb[o] = f2bf(v + bv);
                }
            }
        }
    }
}

// ---------------------- weight transpose / convert -------------------------
template <int SPLIT>
__global__ __launch_bounds__(256) void transpose_w(
    const float* __restrict__ W, short* __restrict__ Th, short* __restrict__ Tl,
    int Kd, int Nd)
{
    __shared__ float tile[64][65];
    const int k0 = blockIdx.y * 64, n0 = blockIdx.x * 64;
    for (int f = threadIdx.x; f < 1024; f += 256) {
        const int rr = f >> 4, c4 = (f & 15) * 4;
        const float4 v = *(const float4*)(W + (size_t)(k0 + rr) * Nd + n0 + c4);
        tile[rr][c4 + 0] = v.x; tile[rr][c4 + 1] = v.y;
        tile[rr][c4 + 2] = v.z; tile[rr][c4 + 3] = v.w;
    }
    __syncthreads();
    for (int f = threadIdx.x; f < 1024; f += 256) {
        const int nn = f >> 4, k4 = (f & 15) * 4;
        short4 hv, lv;
        float w0 = tile[k4 + 0][nn], w1 = tile[k4 + 1][nn];
        float w2 = tile[k4 + 2][nn], w3 = tile[k4 + 3][nn];
        hv.x = f2bf(w0); hv.y = f2bf(w1); hv.z = f2bf(w2); hv.w = f2bf(w3);
        *(short4*)(Th + (size_t)(n0 + nn) * Kd + k0 + k4) = hv;
        if (SPLIT) {
            lv.x = f2bf(w0 - bf2f(hv.x)); lv.y = f2bf(w1 - bf2f(hv.y));
            lv.z = f2bf(w2 - bf2f(hv.z)); lv.w = f2bf(w3 - bf2f(hv.w));
            *(short4*)(Tl + (size_t)(n0 + nn) * Kd + k0 + k4) = lv;
        }
    }
}

__global__ void cvt_bf16_kernel(const float* __restrict__ x, short* __restrict__ y, int n4)
{
    const int i = blockIdx.x * 256 + threadIdx.x;
    if (i >= n4) return;
    const float4 v = *(const float4*)(x + (size_t)i * 4);
    short4 o; o.x = f2bf(v.x); o.y = f2bf(v.y); o.z = f2bf(v.z); o.w = f2bf(v.w);
    *(short4*)(y + (size_t)i * 4) = o;
}

__global__ void fill_bcat(const float* __restrict__ bq, const float* __restrict__ bk,
                          const float* __restrict__ bv, const float* __restrict__ bg,
                          float* __restrict__ bcat)
{
    const int i = blockIdx.x * 256 + threadIdx.x;
    if (i >= 6144) return;
    const int seg = i / 1536, c = i - seg * 1536;
    const float* src = (seg == 0) ? bq : (seg == 1) ? bk : (seg == 2) ? bv : bg;
    bcat[i] = src[c];
}

// --------------------- LayerNorm (bf16 out, optional split) -----------------
template <int ADD1, int SPLIT>
__global__ __launch_bounds__(256) void ln_bf16(
    const float* __restrict__ x, short* __restrict__ hi, short* __restrict__ lo,
    const float* __restrict__ g, const float* __restrict__ b)
{
    __shared__ float red[4];
    const size_t s = blockIdx.x;
    const float* xr = x + s * D_;
    float v[6];
    float sm = 0.f;
#pragma unroll
    for (int i = 0; i < 6; i++) { v[i] = xr[threadIdx.x + 256 * i]; sm += v[i]; }
    sm = block_sum_256(sm, red);
    const float mean = sm * (1.f / D_);
    float vs = 0.f;
#pragma unroll
    for (int i = 0; i < 6; i++) { const float d = v[i] - mean; vs += d * d; }
    vs = block_sum_256(vs, red);
    const float rs = rsqrtf(vs * (1.f / D_) + EPS_);
#pragma unroll
    for (int i = 0; i < 6; i++) {
        const int d = threadIdx.x + 256 * i;
        const float y = (v[i] - mean) * rs * (g[d] + (float)ADD1) + b[d];
        const short h = f2bf(y);
        hi[s * D_ + d] = h;
        if (SPLIT) lo[s * D_ + d] = f2bf(y - bf2f(h));
    }
}

__global__ __launch_bounds__(256) void rms_kernel(float* __restrict__ x,
                                                  const float* __restrict__ w)
{
    __shared__ float red[4];
    const size_t s = blockIdx.x;
    float* xr = x + s * D_;
    float v[6];
    float ss = 0.f;
#pragma unroll
    for (int i = 0; i < 6; i++) { v[i] = xr[threadIdx.x + 256 * i]; ss += v[i] * v[i]; }
    ss = block_sum_256(ss, red);
    const float rs = rsqrtf(ss * (1.f / D_) + EPS_);
#pragma unroll
    for (int i = 0; i < 6; i++) {
        const int d = threadIdx.x + 256 * i;
        xr[d] = v[i] * rs * w[d];
    }
}

// --------------- fused RMS + RoPE for Q and K (in-place) -------------------
__global__ __launch_bounds__(256) void rmsrope_qk(
    float* __restrict__ Q, float* __restrict__ K,
    const float* __restrict__ nqw, const float* __restrict__ nkw,
    const float* __restrict__ cosT, const float* __restrict__ sinT)
{
    __shared__ float red[4];
    const size_t s = blockIdx.x;
    const int tid = threadIdx.x;

#pragma unroll
    for (int m = 0; m < 2; m++) {
        float* X = m ? K : Q;
        const float* w = m ? nkw : nqw;
        float2 v[3];
        float ss = 0.f;
#pragma unroll
        for (int j = 0; j < 3; j++) {
            v[j] = *(const float2*)(X + s * D_ + 2 * (tid + 256 * j));
            ss += v[j].x * v[j].x + v[j].y * v[j].y;
        }
        ss = block_sum_256(ss, red);
        const float rs = rsqrtf(ss * (1.f / D_) + EPS_);
#pragma unroll
        for (int j = 0; j < 3; j++) {
            const int p = tid + 256 * j;
            const int i = p & 63;
            const float c = cosT[s * 64 + i], sn = sinT[s * 64 + i];
            const float x1 = v[j].x * rs * w[2 * p];
            const float x2 = v[j].y * rs * w[2 * p + 1];
            float2 o;
            o.x = x1 * c - x2 * sn;
            o.y = x2 * c + x1 * sn;
            *(float2*)(X + s * D_ + 2 * p) = o;
        }
    }
}

// --------------------------- elementwise -----------------------------------
__global__ void add_kernel(const float* __restrict__ a, const float* __restrict__ b,
                           float* __restrict__ o, int n)
{
    const int i = blockIdx.x * 256 + threadIdx.x;
    if (i < n) o[i] = a[i] + b[i];
}

__global__ void residgate_kernel(const float* __restrict__ h, const float* __restrict__ x,
                                 const float* __restrict__ gate, float* __restrict__ o)
{
    const int i = blockIdx.x * 256 + threadIdx.x;
    if (i < S_ * D_) { const int d = i % D_; o[i] = h[i] + x[i] * gate[d]; }
}

// ------------------------- VSA coarse path ---------------------------------
__global__ __launch_bounds__(128) void blockmean_f32(const float* __restrict__ q,
                                                     float* __restrict__ qc)
{
    const int hb = blockIdx.x;
    const int h = hb >> 6, j = hb & 63;
    const int d = threadIdx.x;
    float sum = 0.f;
    for (int t = 0; t < 64; t++)
        sum += q[(size_t)(j * 64 + t) * D_ + h * 128 + d];
    qc[(size_t)hb * 128 + d] = sum * (1.f / 64.f);
}

__global__ __launch_bounds__(128) void blockmean_bf16(const short* __restrict__ q,
                                                      float* __restrict__ qc)
{
    const int hb = blockIdx.x;
    const int h = hb >> 6, j = hb & 63;
    const int d = threadIdx.x;
    float sum = 0.f;
    for (int t = 0; t < 64; t++)
        sum += bf2f(q[(size_t)(j * 64 + t) * D_ + h * 128 + d]);
    qc[(size_t)hb * 128 + d] = sum * (1.f / 64.f);
}

__global__ __launch_bounds__(64) void coarse_kernel(
    const float* __restrict__ qc, const float* __restrict__ kc,
    const float* __restrict__ vc, float* __restrict__ oc, int* __restrict__ idxout)
{
    const int hb = blockIdx.x;
    const int h = hb >> 6, i = hb & 63;
    const int lane = threadIdx.x;
    __shared__ float p[64];

    const float* qv = qc + (size_t)hb * 128;
    const float* kv = kc + (size_t)((h << 6) + lane) * 128;
    float sc = 0.f;
    for (int d = 0; d < 128; d++) sc = fmaf(qv[d], kv[d], sc);
    sc *= SCALE_;

    float mx = sc;
#pragma unroll
    for (int off = 32; off > 0; off >>= 1) mx = fmaxf(mx, __shfl_xor(mx, off, 64));
    const float e = expf(sc - mx);
    float sumv = e;
#pragma unroll
    for (int off = 32; off > 0; off >>= 1) sumv += __shfl_xor(sumv, off, 64);
    const float pv = e / sumv;
    p[lane] = pv;
    __syncthreads();

    float o0 = 0.f, o1 = 0.f;
    for (int j = 0; j < 64; j++) {
        const float pj = p[j];
        const float* vr = vc + (size_t)((h << 6) + j) * 128;
        o0 = fmaf(pj, vr[lane], o0);
        o1 = fmaf(pj, vr[lane + 64], o1);
    }
    oc[(size_t)hb * 128 + lane]      = o0;
    oc[(size_t)hb * 128 + lane + 64] = o1;

    float v = pv;
    for (int t = 0; t < TOPK; t++) {
        float bv = v; int bi = lane;
#pragma unroll
        for (int off = 32; off > 0; off >>= 1) {
            const float ov = __shfl_xor(bv, off, 64);
            const int   oi = __shfl_xor(bi, off, 64);
            if (ov > bv || (ov == bv && oi < bi)) { bv = ov; bi = oi; }
        }
        if (lane == 0) idxout[hb * TOPK + t] = bi;
        if (lane == bi) v = -1.f;
    }
}

// ---------------------- MFMA flash attention -------------------------------
template <int MODE>
__global__ __launch_bounds__(256) void attn_mfma(
    const float* __restrict__ Qf, const float* __restrict__ Kf,
    const short* __restrict__ Vbb, const float* __restrict__ Vff,
    const short* __restrict__ Gb, const float* __restrict__ ocp,
    const int* __restrict__ idxp, short* __restrict__ Ob)
{
    const int hb = blockIdx.x, h = hb >> 6, ib = hb & 63;
    const int tid = threadIdx.x, wid = tid >> 6, lane = tid & 63;
    const int g16 = lane >> 4, l15 = lane & 15;

    __shared__ __align__(16) short Ks[64 * 128];
    __shared__ __align__(16) short Vst[128 * 64];
    __shared__ __align__(16) short Ps[64 * 80];
    __shared__ int sel[8];
    if (tid < 8) sel[tid] = (MODE == 0) ? idxp[hb * 8 + tid] : tid;

    short8 qa[4];
    {
        const float* qrow = Qf + (size_t)(ib * 64 + wid * 16 + l15) * D_ + h * 128;
#pragma unroll
        for (int kk = 0; kk < 4; kk++) {
            const float4 f0 = *(const float4*)(qrow + kk * 32 + g16 * 8);
            const float4 f1 = *(const float4*)(qrow + kk * 32 + g16 * 8 + 4);
            short8 v;
            v[0] = f2bf(f0.x); v[1] = f2bf(f0.y); v[2] = f2bf(f0.z); v[3] = f2bf(f0.w);
            v[4] = f2bf(f1.x); v[5] = f2bf(f1.y); v[6] = f2bf(f1.z); v[7] = f2bf(f1.w);
            qa[kk] = v;
        }
    }

    f32x4 o[8];
#pragma unroll
    for (int n2 = 0; n2 < 8; n2++) o[n2] = (f32x4){0.f, 0.f, 0.f, 0.f};
    float mrow[4] = {-3e38f, -3e38f, -3e38f, -3e38f};
    float lrow[4] = {0.f, 0.f, 0.f, 0.f};
    __syncthreads();

    for (int t = 0; t < 8; t++) {
        const int jb = sel[t];
#pragma unroll
        for (int it = 0; it < 4; it++) {
            const int c = tid + 256 * it;
            const int key = c >> 4, d8 = (c & 15) * 8;
            const float* src = Kf + (size_t)(jb * 64 + key) * D_ + h * 128 + d8;
            const float4 f0 = *(const float4*)src;
            const float4 f1 = *(const float4*)(src + 4);
            short8 v;
            v[0] = f2bf(f0.x); v[1] = f2bf(f0.y); v[2] = f2bf(f0.z); v[3] = f2bf(f0.w);
            v[4] = f2bf(f1.x); v[5] = f2bf(f1.y); v[6] = f2bf(f1.z); v[7] = f2bf(f1.w);
            const int byte = (key * 256 + d8 * 2) ^ ((key & 7) << 4);
            *(short8*)((char*)Ks + byte) = v;
        }
#pragma unroll
        for (int it = 0; it < 4; it++) {
            const int c = tid + 256 * it;
            const int key = c & 63, d8 = (c >> 6) * 8;
            float vv[8];
            if (MODE == 0) {
                const short8 v = *(const short8*)(Vbb + (size_t)(jb * 64 + key) * D_ + h * 128 + d8);
#pragma unroll
                for (int j = 0; j < 8; j++) vv[j] = bf2f(v[j]);
            } else {
                const float* src = Vff + (size_t)(jb * 64 + key) * D_ + h * 128 + d8;
                const float4 f0 = *(const float4*)src;
                const float4 f1 = *(const float4*)(src + 4);
                vv[0] = f0.x; vv[1] = f0.y; vv[2] = f0.z; vv[3] = f0.w;
                vv[4] = f1.x; vv[5] = f1.y; vv[6] = f1.z; vv[7] = f1.w;
            }
#pragma unroll
            for (int j = 0; j < 8; j++) {
                const int dim = d8 + j;
                const int byte = (dim * 128 + key * 2) ^ ((dim & 7) << 4);
                *(short*)((char*)Vst + byte) = f2bf(vv[j]);
            }
        }
        __syncthreads();

        f32x4 s[4];
#pragma unroll
        for (int nt = 0; nt < 4; nt++) {
            f32x4 acc = (f32x4){0.f, 0.f, 0.f, 0.f};
            const int key = nt * 16 + l15;
#pragma unroll
            for (int kk = 0; kk < 4; kk++) {
                const int byte = (key * 256 + (kk * 32 + g16 * 8) * 2) ^ ((key & 7) << 4);
                const short8 b = *(const short8*)((char*)Ks + byte);
                acc = __builtin_amdgcn_mfma_f32_16x16x32_bf16(qa[kk], b, acc, 0, 0, 0);
            }
            s[nt] = acc;
        }
#pragma unroll
        for (int nt = 0; nt < 4; nt++)
#pragma unroll
            for (int rr = 0; rr < 4; rr++) s[nt][rr] *= SCALE_;

        float alpha[4];
#pragma unroll
        for (int rr = 0; rr < 4; rr++) {
            float v = fmaxf(fmaxf(s[0][rr], s[1][rr]), fmaxf(s[2][rr], s[3][rr]));
            v = fmaxf(v, __shfl_xor(v, 1, 64));
            v = fmaxf(v, __shfl_xor(v, 2, 64));
            v = fmaxf(v, __shfl_xor(v, 4, 64));
            v = fmaxf(v, __shfl_xor(v, 8, 64));
            const float mn = fmaxf(mrow[rr], v);
            alpha[rr] = expf(mrow[rr] - mn);
            mrow[rr] = mn;
        }
        float rs[4] = {0.f, 0.f, 0.f, 0.f};
#pragma unroll
        for (int nt = 0; nt < 4; nt++)
#pragma unroll
            for (int rr = 0; rr < 4; rr++) {
                const float p = expf(s[nt][rr] - mrow[rr]);
                s[nt][rr] = p;
                rs[rr] += p;
            }
#pragma unroll
        for (int rr = 0; rr < 4; rr++) {
            float v = rs[rr];
            v += __shfl_xor(v, 1, 64);
            v += __shfl_xor(v, 2, 64);
            v += __shfl_xor(v, 4, 64);
            v += __shfl_xor(v, 8, 64);
            lrow[rr] = lrow[rr] * alpha[rr] + v;
        }
#pragma unroll
        for (int n2 = 0; n2 < 8; n2++)
#pragma unroll
            for (int rr = 0; rr < 4; rr++) o[n2][rr] *= alpha[rr];

#pragma unroll
        for (int nt = 0; nt < 4; nt++)
#pragma unroll
            for (int rr = 0; rr < 4; rr++)
                Ps[(wid * 16 + g16 * 4 + rr) * 80 + nt * 16 + l15] = f2bf(s[nt][rr]);

#pragma unroll
        for (int kk2 = 0; kk2 < 2; kk2++) {
            const short8 pa = *(const short8*)(Ps + (wid * 16 + l15) * 80 + kk2 * 32 + g16 * 8);
#pragma unroll
            for (int n2 = 0; n2 < 8; n2++) {
                const int dim = n2 * 16 + l15;
                const int byte = (dim * 128 + (kk2 * 32 + g16 * 8) * 2) ^ ((dim & 7) << 4);
                const short8 vb = *(const short8*)((char*)Vst + byte);
                o[n2] = __builtin_amdgcn_mfma_f32_16x16x32_bf16(pa, vb, o[n2], 0, 0, 0);
            }
        }
        __syncthreads();
    }

#pragma unroll
    for (int n2 = 0; n2 < 8; n2++) {
        const int col = n2 * 16 + l15;
        const float ocv = (MODE == 0) ? ocp[(size_t)hb * 128 + col] : 0.f;
#pragma unroll
        for (int rr = 0; rr < 4; rr++) {
            const int row = ib * 64 + wid * 16 + g16 * 4 + rr;
            float val = o[n2][rr] / lrow[rr];
            if (MODE == 0)
                val += ocv * bf2f(Gb[(size_t)row * D_ + h * 128 + col]);
            Ob[(size_t)row * D_ + h * 128 + col] = f2bf(val);
        }
    }
}

// ---------------------------------------------------------------------------
extern "C" void kernel_launch(void* const* d_in, const int* in_sizes, int n_in,
                              void* d_out, int out_size, void* d_ws, size_t ws_size,
                              hipStream_t stream)
{
    const float* h_in = (const float*)d_in[0];
    const float* enc  = (const float*)d_in[1];
    const float* temb = (const float*)d_in[2];
    const float* cosT = (const float*)d_in[3];
    const float* sinT = (const float*)d_in[4];
    const float* sst  = (const float*)d_in[5];
    const float* Wq = (const float*)d_in[6];   const float* bq = (const float*)d_in[7];
    const float* Wk = (const float*)d_in[8];   const float* bk = (const float*)d_in[9];
    const float* Wv = (const float*)d_in[10];  const float* bv = (const float*)d_in[11];
    const float* Wg = (const float*)d_in[12];  const float* bg = (const float*)d_in[13];
    const float* Wo = (const float*)d_in[14];  const float* bo = (const float*)d_in[15];
    const float* nq_w  = (const float*)d_in[16];
    const float* nk_w  = (const float*)d_in[17];
    const float* ln1_w = (const float*)d_in[18];
    const float* ln1_b = (const float*)d_in[19];
    const float* cWq = (const float*)d_in[20]; const float* cbq = (const float*)d_in[21];
    const float* cWk = (const float*)d_in[22]; const float* cbk = (const float*)d_in[23];
    const float* cWv = (const float*)d_in[24]; const float* cbv = (const float*)d_in[25];
    const float* cWo = (const float*)d_in[26]; const float* cbo = (const float*)d_in[27];
    const float* cnq_w = (const float*)d_in[28];
    const float* cnk_w = (const float*)d_in[29];
    const float* W1 = (const float*)d_in[30];  const float* b1 = (const float*)d_in[31];
    const float* W2 = (const float*)d_in[32];  const float* b2 = (const float*)d_in[33];
    float* out = (float*)d_out;

    char* base = (char*)d_ws;
    size_t off = 0;
    auto alloc = [&](size_t bytes) {
        char* p = base + off;
        off += (bytes + 255) & ~(size_t)255;
        return p;
    };
    const size_t SD = (size_t)S_ * D_;
    float* e_   = (float*)alloc(6 * D_ * 4);
    float* Q_   = (float*)alloc(SD * 4);       // Q_ and K_ adjacent (EPI4/5)
    float* K_   = (float*)alloc(SD * 4);
    float* CK_  = (float*)alloc((size_t)L_ * D_ * 4);
    float* CV_  = (float*)alloc((size_t)L_ * D_ * 4);
    float* qc_  = (float*)alloc((size_t)H_ * 64 * 128 * 4);
    float* kc_  = (float*)alloc((size_t)H_ * 64 * 128 * 4);
    float* vc_  = (float*)alloc((size_t)H_ * 64 * 128 * 4);
    float* oc_  = (float*)alloc((size_t)H_ * 64 * 128 * 4);
    int*   idx_ = (int*)alloc((size_t)H_ * 64 * TOPK * 4);
    short* Nb   = (short*)alloc(SD * 2);
    // ---- FFC alias region: Nlo .. Wkl (~80 MB, all dead by FFN) ----
    short* Nlo  = (short*)alloc(SD * 2);
    short* Vb   = (short*)alloc(SD * 2);       // Vb and Gb adjacent (EPI4)
    short* Gb   = (short*)alloc(SD * 2);
    short* attn_b = (short*)alloc(SD * 2);
    short* enc_b  = (short*)alloc((size_t)L_ * D_ * 2);
    const size_t WDD = (size_t)D_ * D_;
    short* Wqh = (short*)alloc(WDD * 2);       // Wqh,Wkh,Wvt,Wgt contiguous =
    short* Wkh = (short*)alloc(WDD * 2);       // N=6144 concat B for fused proj
    short* Wvt = (short*)alloc(WDD * 2);
    short* Wgt = (short*)alloc(WDD * 2);
    short* Wql = (short*)alloc(WDD * 2);
    short* Wkl = (short*)alloc(WDD * 2);
    // ---- end alias region ----
    short* Wot = (short*)alloc(WDD * 2);
    short* cWqt = (short*)alloc(WDD * 2); short* cWkt = (short*)alloc(WDD * 2);
    short* cWvt = (short*)alloc(WDD * 2); short* cWot = (short*)alloc(WDD * 2);
    short* W1t = (short*)alloc((size_t)D_ * FF_ * 2);
    short* W2t = (short*)alloc((size_t)D_ * FF_ * 2);
    float* bcat = (float*)alloc(6144 * 4);
    short* FFC = Nlo;   // S x FF bf16 (73.4 MB) over dead region (80 MB)

    const dim3 b256(256);
    const int nSD = S_ * D_;
    const dim3 gSD((nSD + 255) / 256);
    const dim3 gDD(D_ / 64, D_ / 64);
    const dim3 gN1536(D_ / 128, S_ / 128);     // (12,32) = 384 blocks

    add_kernel<<<dim3((6 * D_ + 255) / 256), b256, 0, stream>>>(sst, temb, e_, 6 * D_);
    ln_bf16<1, 1><<<dim3(S_), b256, 0, stream>>>(h_in, Nb, Nlo, e_ + D_, e_);
    fill_bcat<<<dim3(24), b256, 0, stream>>>(bq, bk, bv, bg, bcat);

    transpose_w<1><<<gDD, b256, 0, stream>>>(Wq, Wqh, Wql, D_, D_);
    transpose_w<1><<<gDD, b256, 0, stream>>>(Wk, Wkh, Wkl, D_, D_);
    transpose_w<0><<<gDD, b256, 0, stream>>>(Wv, Wvt, nullptr, D_, D_);
    transpose_w<0><<<gDD, b256, 0, stream>>>(Wg, Wgt, nullptr, D_, D_);
    transpose_w<0><<<gDD, b256, 0, stream>>>(Wo, Wot, nullptr, D_, D_);
    transpose_w<0><<<gDD, b256, 0, stream>>>(cWq, cWqt, nullptr, D_, D_);
    transpose_w<0><<<gDD, b256, 0, stream>>>(cWk, cWkt, nullptr, D_, D_);
    transpose_w<0><<<gDD, b256, 0, stream>>>(cWv, cWvt, nullptr, D_, D_);
    transpose_w<0><<<gDD, b256, 0, stream>>>(cWo, cWot, nullptr, D_, D_);
    transpose_w<0><<<dim3(FF_ / 64, D_ / 64), b256, 0, stream>>>(W1, W1t, nullptr, D_, FF_);
    transpose_w<0><<<dim3(D_ / 64, FF_ / 64), b256, 0, stream>>>(W2, W2t, nullptr, FF_, D_);
    cvt_bf16_kernel<<<dim3((L_ * D_ / 4 + 255) / 256), b256, 0, stream>>>(enc, enc_b, L_ * D_ / 4);

    // fused QKVG projection (hi) + K-concat correction (q,k exactness)
    gemm11<4><<<dim3(6144 / 128, S_ / 128), b256, 0, stream>>>(
        Nb, Wqh, bcat, Q_, Vb, S_, 6144, D_, nullptr, nullptr, nullptr, nullptr);
    gemm11<5><<<dim3(3072 / 128, S_ / 128), b256, 0, stream>>>(
        Nb, Wql, nullptr, Q_, nullptr, S_, 3072, 3072, Nlo, Wqh, Wkl, Wkh);

    // fused rms + rope for q,k
    rmsrope_qk<<<dim3(S_), b256, 0, stream>>>(Q_, K_, nq_w, nk_w, cosT, sinT);

    blockmean_f32<<<dim3(H_ * 64), dim3(128), 0, stream>>>(Q_, qc_);
    blockmean_f32<<<dim3(H_ * 64), dim3(128), 0, stream>>>(K_, kc_);
    blockmean_bf16<<<dim3(H_ * 64), dim3(128), 0, stream>>>(Vb, vc_);
    coarse_kernel<<<dim3(H_ * 64), dim3(64), 0, stream>>>(qc_, kc_, vc_, oc_, idx_);

    attn_mfma<0><<<dim3(H_ * 64), b256, 0, stream>>>(
        Q_, K_, Vb, nullptr, Gb, oc_, idx_, attn_b);

    gemm11<0><<<gN1536, b256, 0, stream>>>(attn_b, Wot, bo, Q_, nullptr, S_, D_, D_,
                                           nullptr, nullptr, nullptr, nullptr);
    residgate_kernel<<<gSD, b256, 0, stream>>>(h_in, Q_, e_ + 2 * D_, K_);

    ln_bf16<0, 0><<<dim3(S_), b256, 0, stream>>>(K_, Nb, nullptr, ln1_w, ln1_b);
    gemm11<0><<<gN1536, b256, 0, stream>>>(Nb, cWqt, cbq, Q_, nullptr, S_, D_, D_,
                                           nullptr, nullptr, nullptr, nullptr);
    rms_kernel<<<dim3(S_), b256, 0, stream>>>(Q_, cnq_w);

    const dim3 gLenc(D_ / 128, L_ / 128);      // (12,4)
    gemm11<0><<<gLenc, b256, 0, stream>>>(enc_b, cWkt, cbk, CK_, nullptr, L_, D_, D_,
                                          nullptr, nullptr, nullptr, nullptr);
    rms_kernel<<<dim3(L_), b256, 0, stream>>>(CK_, cnk_w);
    gemm11<0><<<gLenc, b256, 0, stream>>>(enc_b, cWvt, cbv, CV_, nullptr, L_, D_, D_,
                                          nullptr, nullptr, nullptr, nullptr);

    attn_mfma<1><<<dim3(H_ * 64), b256, 0, stream>>>(
        Q_, CK_, nullptr, CV_, nullptr, nullptr, nullptr, attn_b);
    gemm11<0><<<gN1536, b256, 0, stream>>>(attn_b, cWot, cbo, Q_, nullptr, S_, D_, D_,
                                           nullptr, nullptr, nullptr, nullptr);
    add_kernel<<<gSD, b256, 0, stream>>>(K_, Q_, K_, nSD);

    ln_bf16<1, 0><<<dim3(S_), b256, 0, stream>>>(K_, Nb, nullptr, e_ + 4 * D_, e_ + 3 * D_);
    gemm11<2><<<dim3(FF_ / 128, S_ / 128), b256, 0, stream>>>(
        Nb, W1t, b1, nullptr, FFC, S_, FF_, D_, nullptr, nullptr, nullptr, nullptr);
    gemm11<0><<<gN1536, b256, 0, stream>>>(FFC, W2t, b2, Q_, nullptr, S_, D_, FF_,
                                           nullptr, nullptr, nullptr, nullptr);

    residgate_kernel<<<gSD, b256, 0, stream>>>(K_, Q_, e_ + 5 * D_, out);
}

// Round 13
// 1071.966 us; speedup vs baseline: 1.5192x; 1.2781x over previous
//
#include <hip/hip_runtime.h>
#include <math.h>

// ---------------------------------------------------------------------------
// Round 13: resubmit of round-12 (container died; no data). Cut work:
// (1) Drop split-bf16 q/k correction GEMM (77.5 GF) — coarse-score error
// analysis gives ~0 expected top-k flips with plain bf16.
// (2) Fuse residual/gate epilogues into Wo, cWo, W2 GEMMs.
// GEMM core = r11 (128x128x64, 2 blk/CU, counted vmcnt(8), L2 raster).
// ---------------------------------------------------------------------------

namespace {
constexpr int S_   = 4096;
constexpr int D_   = 1536;
constexpr int H_   = 12;
constexpr int L_   = 512;
constexpr int TOPK = 8;
constexpr int FF_  = 8960;
constexpr float EPS_   = 1e-6f;
constexpr float SCALE_ = 0.08838834764831845f;   // 128^-0.5
}

typedef __attribute__((ext_vector_type(8))) short short8;
typedef __attribute__((ext_vector_type(4))) float f32x4;

#define AS_GLOBAL __attribute__((address_space(1)))
#define AS_LDS    __attribute__((address_space(3)))

__device__ __forceinline__ short f2bf(float x) {
    uint32_t u = __float_as_uint(x);
    uint32_t r = (u + 0x7FFFu + ((u >> 16) & 1u)) >> 16;
    return (short)r;
}
__device__ __forceinline__ float bf2f(short s) {
    return __uint_as_float(((uint32_t)(uint16_t)s) << 16);
}
__device__ __forceinline__ float gelu_tanh(float x) {
    const float t = tanhf(0.7978845608028654f * (x + 0.044715f * x * x * x));
    return 0.5f * x * (1.f + t);
}

// ---------------------------- reductions -----------------------------------
__device__ __forceinline__ float block_sum_256(float v, float* red) {
#pragma unroll
    for (int off = 32; off > 0; off >>= 1) v += __shfl_down(v, off, 64);
    const int lane = threadIdx.x & 63, w = threadIdx.x >> 6;
    if (lane == 0) red[w] = v;
    __syncthreads();
    v = red[0] + red[1] + red[2] + red[3];
    __syncthreads();
    return v;
}

// ===================== 128x128x64 4-wave MFMA GEMM =========================
// C(M,N) = A(M,K) @ Bt(N,K)^T. 256 thr, 4 waves (2x2), per-wave 64x64 out.
// LDS 64 KB dbuf -> 2 blocks/CU. Counted vmcnt(8), issue-early STAGE,
// setprio, both-sides swizzle u^(row&7), XCD swizzle + 4-row M-stripe raster.
// EPI: 0 C=acc+bias ; 2 Cb=bf16(gelu(acc+bias)) ; 3 Cb=bf16(acc+bias)
//      4 fused QKVG (N=6144): seg 0,1 -> f32 C+seg*SD ; seg 2,3 -> bf16 Cb
//      6 C = Rres + (acc+bias)*gate[col]   (resid-gate fusion)
//      7 C += acc + bias                   (residual accumulate)
template <int EPI>
__global__ __launch_bounds__(256, 2) void gemm12(
    const short* __restrict__ A, const short* __restrict__ Bt,
    const float* __restrict__ bias, float* __restrict__ C,
    short* __restrict__ Cb, int M, int N, int K,
    const float* __restrict__ Rres, const float* __restrict__ gate)
{
    __shared__ __align__(16) short As[2][128 * 64];
    __shared__ __align__(16) short Bs[2][128 * 64];
    const int tid = threadIdx.x;
    const int wid = tid >> 6, lane = tid & 63;
    const int wm = wid >> 1, wn = wid & 1;
    const int g16 = lane >> 4, l15 = lane & 15;

    // bijective XCD swizzle + 4-row M-stripe raster (Mt % 4 == 0)
    const int gx = gridDim.x;
    const int nwg = gx * gridDim.y;
    const int bid = blockIdx.y * gx + blockIdx.x;
    const int qq = nwg >> 3, r8 = nwg & 7;
    const int xcd = bid & 7, lid = bid >> 3;
    const int swz = ((xcd < r8) ? xcd * (qq + 1) : r8 * (qq + 1) + (xcd - r8) * qq) + lid;
    const int stripe = swz / (4 * gx);
    const int within = swz - stripe * (4 * gx);
    const int m0 = (stripe * 4 + (within & 3)) * 128;
    const int n0 = (within >> 2) * 128;

    f32x4 acc[4][4];
#pragma unroll
    for (int i = 0; i < 4; i++)
#pragma unroll
        for (int j = 0; j < 4; j++) acc[i][j] = (f32x4){0.f, 0.f, 0.f, 0.f};

    int sr[4], su[4];
#pragma unroll
    for (int i = 0; i < 4; i++) {
        const int c = tid + 256 * i;
        sr[i] = c >> 3;
        su[i] = (c & 7) ^ (sr[i] & 7);
    }

    auto STAGE = [&](int buf, int kt) {
#pragma unroll
        for (int i = 0; i < 4; i++)
            __builtin_amdgcn_global_load_lds(
                (const AS_GLOBAL short*)(A + (size_t)(m0 + sr[i]) * K + kt + su[i] * 8),
                (AS_LDS short*)(&As[buf][(tid + 256 * i) * 8]), 16, 0, 0);
#pragma unroll
        for (int i = 0; i < 4; i++)
            __builtin_amdgcn_global_load_lds(
                (const AS_GLOBAL short*)(Bt + (size_t)(n0 + sr[i]) * K + kt + su[i] * 8),
                (AS_LDS short*)(&Bs[buf][(tid + 256 * i) * 8]), 16, 0, 0);
    };

    const int nk = K >> 6;
    STAGE(0, 0);

    int cur = 0;
    for (int t = 0; t < nk; ++t) {
        if (t + 1 < nk) {
            STAGE(cur ^ 1, (t + 1) << 6);
            asm volatile("s_waitcnt vmcnt(8)" ::: "memory");
        } else {
            asm volatile("s_waitcnt vmcnt(0)" ::: "memory");
        }
        __builtin_amdgcn_s_barrier();
        __builtin_amdgcn_sched_barrier(0);

        short8 a[4][2], b[4][2];
#pragma unroll
        for (int mi = 0; mi < 4; mi++) {
            const int row = wm * 64 + mi * 16 + l15;
#pragma unroll
            for (int kk = 0; kk < 2; kk++) {
                const int u = (kk * 4 + g16) ^ (row & 7);
                a[mi][kk] = *(const short8*)(As[cur] + row * 64 + u * 8);
            }
        }
#pragma unroll
        for (int ni = 0; ni < 4; ni++) {
            const int row = wn * 64 + ni * 16 + l15;
#pragma unroll
            for (int kk = 0; kk < 2; kk++) {
                const int u = (kk * 4 + g16) ^ (row & 7);
                b[ni][kk] = *(const short8*)(Bs[cur] + row * 64 + u * 8);
            }
        }
        asm volatile("s_waitcnt lgkmcnt(0)" ::: "memory");
        __builtin_amdgcn_sched_barrier(0);
        __builtin_amdgcn_s_barrier();
        __builtin_amdgcn_sched_barrier(0);

        __builtin_amdgcn_s_setprio(1);
#pragma unroll
        for (int mi = 0; mi < 4; mi++)
#pragma unroll
            for (int ni = 0; ni < 4; ni++)
#pragma unroll
                for (int kk = 0; kk < 2; kk++)
                    acc[mi][ni] = __builtin_amdgcn_mfma_f32_16x16x32_bf16(
                        a[mi][kk], b[ni][kk], acc[mi][ni], 0, 0, 0);
        __builtin_amdgcn_s_setprio(0);

        cur ^= 1;
    }

    const size_t SD = (size_t)S_ * D_;
#pragma unroll
    for (int mi = 0; mi < 4; mi++) {
#pragma unroll
        for (int ni = 0; ni < 4; ni++) {
            const int col = n0 + wn * 64 + ni * 16 + l15;
            const float bv = bias[col];
#pragma unroll
            for (int rr = 0; rr < 4; rr++) {
                const int row = m0 + wm * 64 + mi * 16 + g16 * 4 + rr;
                const float v = acc[mi][ni][rr];
                if (EPI == 4) {
                    const int seg = col / 1536, cl = col - seg * 1536;
                    const float y = v + bv;
                    if (seg < 2) C[(size_t)seg * SD + (size_t)row * 1536 + cl] = y;
                    else Cb[(size_t)(seg - 2) * SD + (size_t)row * 1536 + cl] = f2bf(y);
                } else {
                    const size_t o = (size_t)row * N + col;
                    if (EPI == 0) C[o] = v + bv;
                    else if (EPI == 2) Cb[o] = f2bf(gelu_tanh(v + bv));
                    else if (EPI == 3) Cb[o] = f2bf(v + bv);
                    else if (EPI == 6) C[o] = Rres[o] + (v + bv) * gate[col];
                    else if (EPI == 7) C[o] += v + bv;
                }
            }
        }
    }
}

// ---------------------- weight transpose / convert -------------------------
__global__ __launch_bounds__(256) void transpose_w(
    const float* __restrict__ W, short* __restrict__ Th, int Kd, int Nd)
{
    __shared__ float tile[64][65];
    const int k0 = blockIdx.y * 64, n0 = blockIdx.x * 64;
    for (int f = threadIdx.x; f < 1024; f += 256) {
        const int rr = f >> 4, c4 = (f & 15) * 4;
        const float4 v = *(const float4*)(W + (size_t)(k0 + rr) * Nd + n0 + c4);
        tile[rr][c4 + 0] = v.x; tile[rr][c4 + 1] = v.y;
        tile[rr][c4 + 2] = v.z; tile[rr][c4 + 3] = v.w;
    }
    __syncthreads();
    for (int f = threadIdx.x; f < 1024; f += 256) {
        const int nn = f >> 4, k4 = (f & 15) * 4;
        short4 hv;
        hv.x = f2bf(tile[k4 + 0][nn]); hv.y = f2bf(tile[k4 + 1][nn]);
        hv.z = f2bf(tile[k4 + 2][nn]); hv.w = f2bf(tile[k4 + 3][nn]);
        *(short4*)(Th + (size_t)(n0 + nn) * Kd + k0 + k4) = hv;
    }
}

__global__ void cvt_bf16_kernel(const float* __restrict__ x, short* __restrict__ y, int n4)
{
    const int i = blockIdx.x * 256 + threadIdx.x;
    if (i >= n4) return;
    const float4 v = *(const float4*)(x + (size_t)i * 4);
    short4 o; o.x = f2bf(v.x); o.y = f2bf(v.y); o.z = f2bf(v.z); o.w = f2bf(v.w);
    *(short4*)(y + (size_t)i * 4) = o;
}

__global__ void fill_bcat(const float* __restrict__ bq, const float* __restrict__ bk,
                          const float* __restrict__ bv, const float* __restrict__ bg,
                          float* __restrict__ bcat)
{
    const int i = blockIdx.x * 256 + threadIdx.x;
    if (i >= 6144) return;
    const int seg = i / 1536, c = i - seg * 1536;
    const float* src = (seg == 0) ? bq : (seg == 1) ? bk : (seg == 2) ? bv : bg;
    bcat[i] = src[c];
}

// --------------------------- LayerNorm (bf16 out) ---------------------------
template <int ADD1>
__global__ __launch_bounds__(256) void ln_bf16(
    const float* __restrict__ x, short* __restrict__ hi,
    const float* __restrict__ g, const float* __restrict__ b)
{
    __shared__ float red[4];
    const size_t s = blockIdx.x;
    const float* xr = x + s * D_;
    float v[6];
    float sm = 0.f;
#pragma unroll
    for (int i = 0; i < 6; i++) { v[i] = xr[threadIdx.x + 256 * i]; sm += v[i]; }
    sm = block_sum_256(sm, red);
    const float mean = sm * (1.f / D_);
    float vs = 0.f;
#pragma unroll
    for (int i = 0; i < 6; i++) { const float d = v[i] - mean; vs += d * d; }
    vs = block_sum_256(vs, red);
    const float rs = rsqrtf(vs * (1.f / D_) + EPS_);
#pragma unroll
    for (int i = 0; i < 6; i++) {
        const int d = threadIdx.x + 256 * i;
        hi[s * D_ + d] = f2bf((v[i] - mean) * rs * (g[d] + (float)ADD1) + b[d]);
    }
}

__global__ __launch_bounds__(256) void rms_kernel(float* __restrict__ x,
                                                  const float* __restrict__ w)
{
    __shared__ float red[4];
    const size_t s = blockIdx.x;
    float* xr = x + s * D_;
    float v[6];
    float ss = 0.f;
#pragma unroll
    for (int i = 0; i < 6; i++) { v[i] = xr[threadIdx.x + 256 * i]; ss += v[i] * v[i]; }
    ss = block_sum_256(ss, red);
    const float rs = rsqrtf(ss * (1.f / D_) + EPS_);
#pragma unroll
    for (int i = 0; i < 6; i++) {
        const int d = threadIdx.x + 256 * i;
        xr[d] = v[i] * rs * w[d];
    }
}

// --------------- fused RMS + RoPE for Q and K (in-place) -------------------
__global__ __launch_bounds__(256) void rmsrope_qk(
    float* __restrict__ Q, float* __restrict__ K,
    const float* __restrict__ nqw, const float* __restrict__ nkw,
    const float* __restrict__ cosT, const float* __restrict__ sinT)
{
    __shared__ float red[4];
    const size_t s = blockIdx.x;
    const int tid = threadIdx.x;

#pragma unroll
    for (int m = 0; m < 2; m++) {
        float* X = m ? K : Q;
        const float* w = m ? nkw : nqw;
        float2 v[3];
        float ss = 0.f;
#pragma unroll
        for (int j = 0; j < 3; j++) {
            v[j] = *(const float2*)(X + s * D_ + 2 * (tid + 256 * j));
            ss += v[j].x * v[j].x + v[j].y * v[j].y;
        }
        ss = block_sum_256(ss, red);
        const float rs = rsqrtf(ss * (1.f / D_) + EPS_);
#pragma unroll
        for (int j = 0; j < 3; j++) {
            const int p = tid + 256 * j;
            const int i = p & 63;
            const float c = cosT[s * 64 + i], sn = sinT[s * 64 + i];
            const float x1 = v[j].x * rs * w[2 * p];
            const float x2 = v[j].y * rs * w[2 * p + 1];
            float2 o;
            o.x = x1 * c - x2 * sn;
            o.y = x2 * c + x1 * sn;
            *(float2*)(X + s * D_ + 2 * p) = o;
        }
    }
}

// --------------------------- elementwise -----------------------------------
__global__ void add_kernel(const float* __restrict__ a, const float* __restrict__ b,
                           float* __restrict__ o, int n)
{
    const int i = blockIdx.x * 256 + threadIdx.x;
    if (i < n) o[i] = a[i] + b[i];
}

// ------------------------- VSA coarse path ---------------------------------
__global__ __launch_bounds__(128) void blockmean_f32(const float* __restrict__ q,
                                                     float* __restrict__ qc)
{
    const int hb = blockIdx.x;
    const int h = hb >> 6, j = hb & 63;
    const int d = threadIdx.x;
    float sum = 0.f;
    for (int t = 0; t < 64; t++)
        sum += q[(size_t)(j * 64 + t) * D_ + h * 128 + d];
    qc[(size_t)hb * 128 + d] = sum * (1.f / 64.f);
}

__global__ __launch_bounds__(128) void blockmean_bf16(const short* __restrict__ q,
                                                      float* __restrict__ qc)
{
    const int hb = blockIdx.x;
    const int h = hb >> 6, j = hb & 63;
    const int d = threadIdx.x;
    float sum = 0.f;
    for (int t = 0; t < 64; t++)
        sum += bf2f(q[(size_t)(j * 64 + t) * D_ + h * 128 + d]);
    qc[(size_t)hb * 128 + d] = sum * (1.f / 64.f);
}

__global__ __launch_bounds__(64) void coarse_kernel(
    const float* __restrict__ qc, const float* __restrict__ kc,
    const float* __restrict__ vc, float* __restrict__ oc, int* __restrict__ idxout)
{
    const int hb = blockIdx.x;
    const int h = hb >> 6, i = hb & 63;
    const int lane = threadIdx.x;
    __shared__ float p[64];

    const float* qv = qc + (size_t)hb * 128;
    const float* kv = kc + (size_t)((h << 6) + lane) * 128;
    float sc = 0.f;
    for (int d = 0; d < 128; d++) sc = fmaf(qv[d], kv[d], sc);
    sc *= SCALE_;

    float mx = sc;
#pragma unroll
    for (int off = 32; off > 0; off >>= 1) mx = fmaxf(mx, __shfl_xor(mx, off, 64));
    const float e = expf(sc - mx);
    float sumv = e;
#pragma unroll
    for (int off = 32; off > 0; off >>= 1) sumv += __shfl_xor(sumv, off, 64);
    const float pv = e / sumv;
    p[lane] = pv;
    __syncthreads();

    float o0 = 0.f, o1 = 0.f;
    for (int j = 0; j < 64; j++) {
        const float pj = p[j];
        const float* vr = vc + (size_t)((h << 6) + j) * 128;
        o0 = fmaf(pj, vr[lane], o0);
        o1 = fmaf(pj, vr[lane + 64], o1);
    }
    oc[(size_t)hb * 128 + lane]      = o0;
    oc[(size_t)hb * 128 + lane + 64] = o1;

    float v = pv;
    for (int t = 0; t < TOPK; t++) {
        float bv = v; int bi = lane;
#pragma unroll
        for (int off = 32; off > 0; off >>= 1) {
            const float ov = __shfl_xor(bv, off, 64);
            const int   oi = __shfl_xor(bi, off, 64);
            if (ov > bv || (ov == bv && oi < bi)) { bv = ov; bi = oi; }
        }
        if (lane == 0) idxout[hb * TOPK + t] = bi;
        if (lane == bi) v = -1.f;
    }
}

// ---------------------- MFMA flash attention -------------------------------
template <int MODE>
__global__ __launch_bounds__(256) void attn_mfma(
    const float* __restrict__ Qf, const float* __restrict__ Kf,
    const short* __restrict__ Vbb, const float* __restrict__ Vff,
    const short* __restrict__ Gb, const float* __restrict__ ocp,
    const int* __restrict__ idxp, short* __restrict__ Ob)
{
    const int hb = blockIdx.x, h = hb >> 6, ib = hb & 63;
    const int tid = threadIdx.x, wid = tid >> 6, lane = tid & 63;
    const int g16 = lane >> 4, l15 = lane & 15;

    __shared__ __align__(16) short Ks[64 * 128];
    __shared__ __align__(16) short Vst[128 * 64];
    __shared__ __align__(16) short Ps[64 * 80];
    __shared__ int sel[8];
    if (tid < 8) sel[tid] = (MODE == 0) ? idxp[hb * 8 + tid] : tid;

    short8 qa[4];
    {
        const float* qrow = Qf + (size_t)(ib * 64 + wid * 16 + l15) * D_ + h * 128;
#pragma unroll
        for (int kk = 0; kk < 4; kk++) {
            const float4 f0 = *(const float4*)(qrow + kk * 32 + g16 * 8);
            const float4 f1 = *(const float4*)(qrow + kk * 32 + g16 * 8 + 4);
            short8 v;
            v[0] = f2bf(f0.x); v[1] = f2bf(f0.y); v[2] = f2bf(f0.z); v[3] = f2bf(f0.w);
            v[4] = f2bf(f1.x); v[5] = f2bf(f1.y); v[6] = f2bf(f1.z); v[7] = f2bf(f1.w);
            qa[kk] = v;
        }
    }

    f32x4 o[8];
#pragma unroll
    for (int n2 = 0; n2 < 8; n2++) o[n2] = (f32x4){0.f, 0.f, 0.f, 0.f};
    float mrow[4] = {-3e38f, -3e38f, -3e38f, -3e38f};
    float lrow[4] = {0.f, 0.f, 0.f, 0.f};
    __syncthreads();

    for (int t = 0; t < 8; t++) {
        const int jb = sel[t];
#pragma unroll
        for (int it = 0; it < 4; it++) {
            const int c = tid + 256 * it;
            const int key = c >> 4, d8 = (c & 15) * 8;
            const float* src = Kf + (size_t)(jb * 64 + key) * D_ + h * 128 + d8;
            const float4 f0 = *(const float4*)src;
            const float4 f1 = *(const float4*)(src + 4);
            short8 v;
            v[0] = f2bf(f0.x); v[1] = f2bf(f0.y); v[2] = f2bf(f0.z); v[3] = f2bf(f0.w);
            v[4] = f2bf(f1.x); v[5] = f2bf(f1.y); v[6] = f2bf(f1.z); v[7] = f2bf(f1.w);
            const int byte = (key * 256 + d8 * 2) ^ ((key & 7) << 4);
            *(short8*)((char*)Ks + byte) = v;
        }
#pragma unroll
        for (int it = 0; it < 4; it++) {
            const int c = tid + 256 * it;
            const int key = c & 63, d8 = (c >> 6) * 8;
            float vv[8];
            if (MODE == 0) {
                const short8 v = *(const short8*)(Vbb + (size_t)(jb * 64 + key) * D_ + h * 128 + d8);
#pragma unroll
                for (int j = 0; j < 8; j++) vv[j] = bf2f(v[j]);
            } else {
                const float* src = Vff + (size_t)(jb * 64 + key) * D_ + h * 128 + d8;
                const float4 f0 = *(const float4*)src;
                const float4 f1 = *(const float4*)(src + 4);
                vv[0] = f0.x; vv[1] = f0.y; vv[2] = f0.z; vv[3] = f0.w;
                vv[4] = f1.x; vv[5] = f1.y; vv[6] = f1.z; vv[7] = f1.w;
            }
#pragma unroll
            for (int j = 0; j < 8; j++) {
                const int dim = d8 + j;
                const int byte = (dim * 128 + key * 2) ^ ((dim & 7) << 4);
                *(short*)((char*)Vst + byte) = f2bf(vv[j]);
            }
        }
        __syncthreads();

        f32x4 s[4];
#pragma unroll
        for (int nt = 0; nt < 4; nt++) {
            f32x4 acc = (f32x4){0.f, 0.f, 0.f, 0.f};
            const int key = nt * 16 + l15;
#pragma unroll
            for (int kk = 0; kk < 4; kk++) {
                const int byte = (key * 256 + (kk * 32 + g16 * 8) * 2) ^ ((key & 7) << 4);
                const short8 b = *(const short8*)((char*)Ks + byte);
                acc = __builtin_amdgcn_mfma_f32_16x16x32_bf16(qa[kk], b, acc, 0, 0, 0);
            }
            s[nt] = acc;
        }
#pragma unroll
        for (int nt = 0; nt < 4; nt++)
#pragma unroll
            for (int rr = 0; rr < 4; rr++) s[nt][rr] *= SCALE_;

        float alpha[4];
#pragma unroll
        for (int rr = 0; rr < 4; rr++) {
            float v = fmaxf(fmaxf(s[0][rr], s[1][rr]), fmaxf(s[2][rr], s[3][rr]));
            v = fmaxf(v, __shfl_xor(v, 1, 64));
            v = fmaxf(v, __shfl_xor(v, 2, 64));
            v = fmaxf(v, __shfl_xor(v, 4, 64));
            v = fmaxf(v, __shfl_xor(v, 8, 64));
            const float mn = fmaxf(mrow[rr], v);
            alpha[rr] = expf(mrow[rr] - mn);
            mrow[rr] = mn;
        }
        float rs[4] = {0.f, 0.f, 0.f, 0.f};
#pragma unroll
        for (int nt = 0; nt < 4; nt++)
#pragma unroll
            for (int rr = 0; rr < 4; rr++) {
                const float p = expf(s[nt][rr] - mrow[rr]);
                s[nt][rr] = p;
                rs[rr] += p;
            }
#pragma unroll
        for (int rr = 0; rr < 4; rr++) {
            float v = rs[rr];
            v += __shfl_xor(v, 1, 64);
            v += __shfl_xor(v, 2, 64);
            v += __shfl_xor(v, 4, 64);
            v += __shfl_xor(v, 8, 64);
            lrow[rr] = lrow[rr] * alpha[rr] + v;
        }
#pragma unroll
        for (int n2 = 0; n2 < 8; n2++)
#pragma unroll
            for (int rr = 0; rr < 4; rr++) o[n2][rr] *= alpha[rr];

#pragma unroll
        for (int nt = 0; nt < 4; nt++)
#pragma unroll
            for (int rr = 0; rr < 4; rr++)
                Ps[(wid * 16 + g16 * 4 + rr) * 80 + nt * 16 + l15] = f2bf(s[nt][rr]);

#pragma unroll
        for (int kk2 = 0; kk2 < 2; kk2++) {
            const short8 pa = *(const short8*)(Ps + (wid * 16 + l15) * 80 + kk2 * 32 + g16 * 8);
#pragma unroll
            for (int n2 = 0; n2 < 8; n2++) {
                const int dim = n2 * 16 + l15;
                const int byte = (dim * 128 + (kk2 * 32 + g16 * 8) * 2) ^ ((dim & 7) << 4);
                const short8 vb = *(const short8*)((char*)Vst + byte);
                o[n2] = __builtin_amdgcn_mfma_f32_16x16x32_bf16(pa, vb, o[n2], 0, 0, 0);
            }
        }
        __syncthreads();
    }

#pragma unroll
    for (int n2 = 0; n2 < 8; n2++) {
        const int col = n2 * 16 + l15;
        const float ocv = (MODE == 0) ? ocp[(size_t)hb * 128 + col] : 0.f;
#pragma unroll
        for (int rr = 0; rr < 4; rr++) {
            const int row = ib * 64 + wid * 16 + g16 * 4 + rr;
            float val = o[n2][rr] / lrow[rr];
            if (MODE == 0)
                val += ocv * bf2f(Gb[(size_t)row * D_ + h * 128 + col]);
            Ob[(size_t)row * D_ + h * 128 + col] = f2bf(val);
        }
    }
}

// ---------------------------------------------------------------------------
extern "C" void kernel_launch(void* const* d_in, const int* in_sizes, int n_in,
                              void* d_out, int out_size, void* d_ws, size_t ws_size,
                              hipStream_t stream)
{
    const float* h_in = (const float*)d_in[0];
    const float* enc  = (const float*)d_in[1];
    const float* temb = (const float*)d_in[2];
    const float* cosT = (const float*)d_in[3];
    const float* sinT = (const float*)d_in[4];
    const float* sst  = (const float*)d_in[5];
    const float* Wq = (const float*)d_in[6];   const float* bq = (const float*)d_in[7];
    const float* Wk = (const float*)d_in[8];   const float* bk = (const float*)d_in[9];
    const float* Wv = (const float*)d_in[10];  const float* bv = (const float*)d_in[11];
    const float* Wg = (const float*)d_in[12];  const float* bg = (const float*)d_in[13];
    const float* Wo = (const float*)d_in[14];  const float* bo = (const float*)d_in[15];
    const float* nq_w  = (const float*)d_in[16];
    const float* nk_w  = (const float*)d_in[17];
    const float* ln1_w = (const float*)d_in[18];
    const float* ln1_b = (const float*)d_in[19];
    const float* cWq = (const float*)d_in[20]; const float* cbq = (const float*)d_in[21];
    const float* cWk = (const float*)d_in[22]; const float* cbk = (const float*)d_in[23];
    const float* cWv = (const float*)d_in[24]; const float* cbv = (const float*)d_in[25];
    const float* cWo = (const float*)d_in[26]; const float* cbo = (const float*)d_in[27];
    const float* cnq_w = (const float*)d_in[28];
    const float* cnk_w = (const float*)d_in[29];
    const float* W1 = (const float*)d_in[30];  const float* b1 = (const float*)d_in[31];
    const float* W2 = (const float*)d_in[32];  const float* b2 = (const float*)d_in[33];
    float* out = (float*)d_out;

    char* base = (char*)d_ws;
    size_t off = 0;
    auto alloc = [&](size_t bytes) {
        char* p = base + off;
        off += (bytes + 255) & ~(size_t)255;
        return p;
    };
    const size_t SD = (size_t)S_ * D_;
    float* e_   = (float*)alloc(6 * D_ * 4);
    float* Q_   = (float*)alloc(SD * 4);       // Q_ and K_ adjacent (EPI4)
    float* K_   = (float*)alloc(SD * 4);
    float* CK_  = (float*)alloc((size_t)L_ * D_ * 4);
    float* CV_  = (float*)alloc((size_t)L_ * D_ * 4);
    float* qc_  = (float*)alloc((size_t)H_ * 64 * 128 * 4);
    float* kc_  = (float*)alloc((size_t)H_ * 64 * 128 * 4);
    float* vc_  = (float*)alloc((size_t)H_ * 64 * 128 * 4);
    float* oc_  = (float*)alloc((size_t)H_ * 64 * 128 * 4);
    int*   idx_ = (int*)alloc((size_t)H_ * 64 * TOPK * 4);
    short* Nb   = (short*)alloc(SD * 2);       // live during W1 (norm3)
    // ---- FFC alias region: Vb .. Wgt (~96 MB, all dead by FFN) ----
    short* Vb   = (short*)alloc(SD * 2);       // Vb and Gb adjacent (EPI4)
    short* Gb   = (short*)alloc(SD * 2);
    short* attn_b = (short*)alloc(SD * 2);
    short* enc_b  = (short*)alloc((size_t)L_ * D_ * 2);
    const size_t WDD = (size_t)D_ * D_;
    short* Wqt = (short*)alloc(WDD * 2);       // Wqt,Wkt,Wvt,Wgt contiguous =
    short* Wkt = (short*)alloc(WDD * 2);       // N=6144 concat B for fused proj
    short* Wvt = (short*)alloc(WDD * 2);
    short* Wgt = (short*)alloc(WDD * 2);
    // ---- end alias region ----
    short* Wot = (short*)alloc(WDD * 2);
    short* cWqt = (short*)alloc(WDD * 2); short* cWkt = (short*)alloc(WDD * 2);
    short* cWvt = (short*)alloc(WDD * 2); short* cWot = (short*)alloc(WDD * 2);
    short* W1t = (short*)alloc((size_t)D_ * FF_ * 2);
    short* W2t = (short*)alloc((size_t)D_ * FF_ * 2);
    float* bcat = (float*)alloc(6144 * 4);
    short* FFC = Vb;    // S x FF bf16 (73.4 MB) over dead region (~96 MB)

    const dim3 b256(256);
    const int nSD = S_ * D_;
    const dim3 gDD(D_ / 64, D_ / 64);
    const dim3 gN1536(D_ / 128, S_ / 128);     // 384 blocks

    add_kernel<<<dim3((6 * D_ + 255) / 256), b256, 0, stream>>>(sst, temb, e_, 6 * D_);
    ln_bf16<1><<<dim3(S_), b256, 0, stream>>>(h_in, Nb, e_ + D_, e_);
    fill_bcat<<<dim3(24), b256, 0, stream>>>(bq, bk, bv, bg, bcat);

    transpose_w<<<gDD, b256, 0, stream>>>(Wq, Wqt, D_, D_);
    transpose_w<<<gDD, b256, 0, stream>>>(Wk, Wkt, D_, D_);
    transpose_w<<<gDD, b256, 0, stream>>>(Wv, Wvt, D_, D_);
    transpose_w<<<gDD, b256, 0, stream>>>(Wg, Wgt, D_, D_);
    transpose_w<<<gDD, b256, 0, stream>>>(Wo, Wot, D_, D_);
    transpose_w<<<gDD, b256, 0, stream>>>(cWq, cWqt, D_, D_);
    transpose_w<<<gDD, b256, 0, stream>>>(cWk, cWkt, D_, D_);
    transpose_w<<<gDD, b256, 0, stream>>>(cWv, cWvt, D_, D_);
    transpose_w<<<gDD, b256, 0, stream>>>(cWo, cWot, D_, D_);
    transpose_w<<<dim3(FF_ / 64, D_ / 64), b256, 0, stream>>>(W1, W1t, D_, FF_);
    transpose_w<<<dim3(D_ / 64, FF_ / 64), b256, 0, stream>>>(W2, W2t, FF_, D_);
    cvt_bf16_kernel<<<dim3((L_ * D_ / 4 + 255) / 256), b256, 0, stream>>>(enc, enc_b, L_ * D_ / 4);

    // fused QKVG projection (plain bf16; top-k flip analysis: ~0 expected)
    gemm12<4><<<dim3(6144 / 128, S_ / 128), b256, 0, stream>>>(
        Nb, Wqt, bcat, Q_, Vb, S_, 6144, D_, nullptr, nullptr);

    // fused rms + rope for q,k
    rmsrope_qk<<<dim3(S_), b256, 0, stream>>>(Q_, K_, nq_w, nk_w, cosT, sinT);

    blockmean_f32<<<dim3(H_ * 64), dim3(128), 0, stream>>>(Q_, qc_);
    blockmean_f32<<<dim3(H_ * 64), dim3(128), 0, stream>>>(K_, kc_);
    blockmean_bf16<<<dim3(H_ * 64), dim3(128), 0, stream>>>(Vb, vc_);
    coarse_kernel<<<dim3(H_ * 64), dim3(64), 0, stream>>>(qc_, kc_, vc_, oc_, idx_);

    attn_mfma<0><<<dim3(H_ * 64), b256, 0, stream>>>(
        Q_, K_, Vb, nullptr, Gb, oc_, idx_, attn_b);

    // Wo fused with resid-gate: K_ = h_in + (attn@Wo + bo) * gate
    gemm12<6><<<gN1536, b256, 0, stream>>>(attn_b, Wot, bo, K_, nullptr, S_, D_, D_,
                                           h_in, e_ + 2 * D_);

    ln_bf16<0><<<dim3(S_), b256, 0, stream>>>(K_, Nb, ln1_w, ln1_b);
    gemm12<0><<<gN1536, b256, 0, stream>>>(Nb, cWqt, cbq, Q_, nullptr, S_, D_, D_,
                                           nullptr, nullptr);
    rms_kernel<<<dim3(S_), b256, 0, stream>>>(Q_, cnq_w);

    const dim3 gLenc(D_ / 128, L_ / 128);
    gemm12<0><<<gLenc, b256, 0, stream>>>(enc_b, cWkt, cbk, CK_, nullptr, L_, D_, D_,
                                          nullptr, nullptr);
    rms_kernel<<<dim3(L_), b256, 0, stream>>>(CK_, cnk_w);
    gemm12<0><<<gLenc, b256, 0, stream>>>(enc_b, cWvt, cbv, CV_, nullptr, L_, D_, D_,
                                          nullptr, nullptr);

    attn_mfma<1><<<dim3(H_ * 64), b256, 0, stream>>>(
        Q_, CK_, nullptr, CV_, nullptr, nullptr, nullptr, attn_b);

    // cWo fused with residual: K_ += cout@cWo + cbo   (resid2 in place)
    gemm12<7><<<gN1536, b256, 0, stream>>>(attn_b, cWot, cbo, K_, nullptr, S_, D_, D_,
                                           nullptr, nullptr);

    // norm3 -> Nb ; FFN: W1(gelu->FFC bf16) ; W2 fused with final resid-gate
    ln_bf16<1><<<dim3(S_), b256, 0, stream>>>(K_, Nb, e_ + 4 * D_, e_ + 3 * D_);
    gemm12<2><<<dim3(FF_ / 128, S_ / 128), b256, 0, stream>>>(
        Nb, W1t, b1, nullptr, FFC, S_, FF_, D_, nullptr, nullptr);
    gemm12<6><<<gN1536, b256, 0, stream>>>(FFC, W2t, b2, out, nullptr, S_, D_, FF_,
                                           K_, e_ + 5 * D_);
}

// Round 15
// 930.221 us; speedup vs baseline: 1.7507x; 1.1524x over previous
//
#include <hip/hip_runtime.h>
#include <math.h>

// ---------------------------------------------------------------------------
// Round 15: resubmit of round-14 (container died; no data).
// (1) GEMM BN 128->64, LDS 48KB -> 3 blocks/CU. Counted vmcnt(6).
// (2) q/k/v/g all bf16 end-to-end. Cross-attn path unchanged f32.
// ---------------------------------------------------------------------------

namespace {
constexpr int S_   = 4096;
constexpr int D_   = 1536;
constexpr int H_   = 12;
constexpr int L_   = 512;
constexpr int TOPK = 8;
constexpr int FF_  = 8960;
constexpr float EPS_   = 1e-6f;
constexpr float SCALE_ = 0.08838834764831845f;   // 128^-0.5
}

typedef __attribute__((ext_vector_type(8))) short short8;
typedef __attribute__((ext_vector_type(4))) float f32x4;

#define AS_GLOBAL __attribute__((address_space(1)))
#define AS_LDS    __attribute__((address_space(3)))

__device__ __forceinline__ short f2bf(float x) {
    uint32_t u = __float_as_uint(x);
    uint32_t r = (u + 0x7FFFu + ((u >> 16) & 1u)) >> 16;
    return (short)r;
}
__device__ __forceinline__ float bf2f(short s) {
    return __uint_as_float(((uint32_t)(uint16_t)s) << 16);
}
__device__ __forceinline__ float gelu_tanh(float x) {
    const float t = tanhf(0.7978845608028654f * (x + 0.044715f * x * x * x));
    return 0.5f * x * (1.f + t);
}

// ---------------------------- reductions -----------------------------------
__device__ __forceinline__ float block_sum_256(float v, float* red) {
#pragma unroll
    for (int off = 32; off > 0; off >>= 1) v += __shfl_down(v, off, 64);
    const int lane = threadIdx.x & 63, w = threadIdx.x >> 6;
    if (lane == 0) red[w] = v;
    __syncthreads();
    v = red[0] + red[1] + red[2] + red[3];
    __syncthreads();
    return v;
}

// ====================== 128x64x64 4-wave MFMA GEMM =========================
// C(M,N) = A(M,K) @ Bt(N,K)^T. 256 thr, 4 waves; per-wave 64x32 out (wm 2
// M-halves, wn 2 N-halves), acc[4][2]. LDS: A[2][128x64] 32KB + B[2][64x64]
// 16KB = 48KB -> 3 blocks/CU. Counted vmcnt(6), issue-early STAGE, setprio,
// swizzle u^(row&7) both sides, XCD swizzle + 4-row M-stripe raster.
// EPI: 0 C=acc+bias(f32) ; 2 Cb=bf16(gelu(acc+bias)) ;
//      4 QKVG (N=6144): Cb[seg*SD + row*1536 + cl] = bf16(acc+bias)
//      6 C = Rres + (acc+bias)*gate[col] ; 7 C += acc + bias
template <int EPI>
__global__ __launch_bounds__(256, 3) void gemm14(
    const short* __restrict__ A, const short* __restrict__ Bt,
    const float* __restrict__ bias, float* __restrict__ C,
    short* __restrict__ Cb, int M, int N, int K,
    const float* __restrict__ Rres, const float* __restrict__ gate)
{
    __shared__ __align__(16) short As[2][128 * 64];
    __shared__ __align__(16) short Bs[2][64 * 64];
    const int tid = threadIdx.x;
    const int wid = tid >> 6, lane = tid & 63;
    const int wm = wid >> 1, wn = wid & 1;
    const int g16 = lane >> 4, l15 = lane & 15;

    // bijective XCD swizzle + 4-row M-stripe raster
    const int gx = gridDim.x;
    const int nwg = gx * gridDim.y;
    const int bid = blockIdx.y * gx + blockIdx.x;
    const int qq = nwg >> 3, r8 = nwg & 7;
    const int xcd = bid & 7, lid = bid >> 3;
    const int swz = ((xcd < r8) ? xcd * (qq + 1) : r8 * (qq + 1) + (xcd - r8) * qq) + lid;
    const int stripe = swz / (4 * gx);
    const int within = swz - stripe * (4 * gx);
    const int m0 = (stripe * 4 + (within & 3)) * 128;
    const int n0 = (within >> 2) * 64;

    f32x4 acc[4][2];
#pragma unroll
    for (int i = 0; i < 4; i++)
#pragma unroll
        for (int j = 0; j < 2; j++) acc[i][j] = (f32x4){0.f, 0.f, 0.f, 0.f};

    // staging maps: A 1024 units (4/thr), B 512 units (2/thr)
    int ar[4], au[4], br[2], bu[2];
#pragma unroll
    for (int i = 0; i < 4; i++) {
        const int c = tid + 256 * i;
        ar[i] = c >> 3;
        au[i] = (c & 7) ^ (ar[i] & 7);
    }
#pragma unroll
    for (int i = 0; i < 2; i++) {
        const int c = tid + 256 * i;
        br[i] = c >> 3;
        bu[i] = (c & 7) ^ (br[i] & 7);
    }

    auto STAGE = [&](int buf, int kt) {
#pragma unroll
        for (int i = 0; i < 4; i++)
            __builtin_amdgcn_global_load_lds(
                (const AS_GLOBAL short*)(A + (size_t)(m0 + ar[i]) * K + kt + au[i] * 8),
                (AS_LDS short*)(&As[buf][(tid + 256 * i) * 8]), 16, 0, 0);
#pragma unroll
        for (int i = 0; i < 2; i++)
            __builtin_amdgcn_global_load_lds(
                (const AS_GLOBAL short*)(Bt + (size_t)(n0 + br[i]) * K + kt + bu[i] * 8),
                (AS_LDS short*)(&Bs[buf][(tid + 256 * i) * 8]), 16, 0, 0);
    };

    const int nk = K >> 6;
    STAGE(0, 0);

    int cur = 0;
    for (int t = 0; t < nk; ++t) {
        if (t + 1 < nk) {
            STAGE(cur ^ 1, (t + 1) << 6);
            asm volatile("s_waitcnt vmcnt(6)" ::: "memory");
        } else {
            asm volatile("s_waitcnt vmcnt(0)" ::: "memory");
        }
        __builtin_amdgcn_s_barrier();
        __builtin_amdgcn_sched_barrier(0);

        short8 a[4][2], b[2][2];
#pragma unroll
        for (int mi = 0; mi < 4; mi++) {
            const int row = wm * 64 + mi * 16 + l15;
#pragma unroll
            for (int kk = 0; kk < 2; kk++) {
                const int u = (kk * 4 + g16) ^ (row & 7);
                a[mi][kk] = *(const short8*)(As[cur] + row * 64 + u * 8);
            }
        }
#pragma unroll
        for (int ni = 0; ni < 2; ni++) {
            const int row = wn * 32 + ni * 16 + l15;
#pragma unroll
            for (int kk = 0; kk < 2; kk++) {
                const int u = (kk * 4 + g16) ^ (row & 7);
                b[ni][kk] = *(const short8*)(Bs[cur] + row * 64 + u * 8);
            }
        }
        asm volatile("s_waitcnt lgkmcnt(0)" ::: "memory");
        __builtin_amdgcn_sched_barrier(0);
        __builtin_amdgcn_s_barrier();
        __builtin_amdgcn_sched_barrier(0);

        __builtin_amdgcn_s_setprio(1);
#pragma unroll
        for (int mi = 0; mi < 4; mi++)
#pragma unroll
            for (int ni = 0; ni < 2; ni++)
#pragma unroll
                for (int kk = 0; kk < 2; kk++)
                    acc[mi][ni] = __builtin_amdgcn_mfma_f32_16x16x32_bf16(
                        a[mi][kk], b[ni][kk], acc[mi][ni], 0, 0, 0);
        __builtin_amdgcn_s_setprio(0);

        cur ^= 1;
    }

    const size_t SD = (size_t)S_ * D_;
#pragma unroll
    for (int mi = 0; mi < 4; mi++) {
#pragma unroll
        for (int ni = 0; ni < 2; ni++) {
            const int col = n0 + wn * 32 + ni * 16 + l15;
            const float bv = bias[col];
#pragma unroll
            for (int rr = 0; rr < 4; rr++) {
                const int row = m0 + wm * 64 + mi * 16 + g16 * 4 + rr;
                const float v = acc[mi][ni][rr];
                if (EPI == 4) {
                    const int seg = col / 1536, cl = col - seg * 1536;
                    Cb[(size_t)seg * SD + (size_t)row * 1536 + cl] = f2bf(v + bv);
                } else {
                    const size_t o = (size_t)row * N + col;
                    if (EPI == 0) C[o] = v + bv;
                    else if (EPI == 2) Cb[o] = f2bf(gelu_tanh(v + bv));
                    else if (EPI == 6) C[o] = Rres[o] + (v + bv) * gate[col];
                    else if (EPI == 7) C[o] += v + bv;
                }
            }
        }
    }
}

// ---------------------- weight transpose / convert -------------------------
__global__ __launch_bounds__(256) void transpose_w(
    const float* __restrict__ W, short* __restrict__ Th, int Kd, int Nd)
{
    __shared__ float tile[64][65];
    const int k0 = blockIdx.y * 64, n0 = blockIdx.x * 64;
    for (int f = threadIdx.x; f < 1024; f += 256) {
        const int rr = f >> 4, c4 = (f & 15) * 4;
        const float4 v = *(const float4*)(W + (size_t)(k0 + rr) * Nd + n0 + c4);
        tile[rr][c4 + 0] = v.x; tile[rr][c4 + 1] = v.y;
        tile[rr][c4 + 2] = v.z; tile[rr][c4 + 3] = v.w;
    }
    __syncthreads();
    for (int f = threadIdx.x; f < 1024; f += 256) {
        const int nn = f >> 4, k4 = (f & 15) * 4;
        short4 hv;
        hv.x = f2bf(tile[k4 + 0][nn]); hv.y = f2bf(tile[k4 + 1][nn]);
        hv.z = f2bf(tile[k4 + 2][nn]); hv.w = f2bf(tile[k4 + 3][nn]);
        *(short4*)(Th + (size_t)(n0 + nn) * Kd + k0 + k4) = hv;
    }
}

__global__ void cvt_bf16_kernel(const float* __restrict__ x, short* __restrict__ y, int n4)
{
    const int i = blockIdx.x * 256 + threadIdx.x;
    if (i >= n4) return;
    const float4 v = *(const float4*)(x + (size_t)i * 4);
    short4 o; o.x = f2bf(v.x); o.y = f2bf(v.y); o.z = f2bf(v.z); o.w = f2bf(v.w);
    *(short4*)(y + (size_t)i * 4) = o;
}

__global__ void fill_bcat(const float* __restrict__ bq, const float* __restrict__ bk,
                          const float* __restrict__ bv, const float* __restrict__ bg,
                          float* __restrict__ bcat)
{
    const int i = blockIdx.x * 256 + threadIdx.x;
    if (i >= 6144) return;
    const int seg = i / 1536, c = i - seg * 1536;
    const float* src = (seg == 0) ? bq : (seg == 1) ? bk : (seg == 2) ? bv : bg;
    bcat[i] = src[c];
}

// --------------------------- LayerNorm (bf16 out) ---------------------------
template <int ADD1>
__global__ __launch_bounds__(256) void ln_bf16(
    const float* __restrict__ x, short* __restrict__ hi,
    const float* __restrict__ g, const float* __restrict__ b)
{
    __shared__ float red[4];
    const size_t s = blockIdx.x;
    const float* xr = x + s * D_;
    float v[6];
    float sm = 0.f;
#pragma unroll
    for (int i = 0; i < 6; i++) { v[i] = xr[threadIdx.x + 256 * i]; sm += v[i]; }
    sm = block_sum_256(sm, red);
    const float mean = sm * (1.f / D_);
    float vs = 0.f;
#pragma unroll
    for (int i = 0; i < 6; i++) { const float d = v[i] - mean; vs += d * d; }
    vs = block_sum_256(vs, red);
    const float rs = rsqrtf(vs * (1.f / D_) + EPS_);
#pragma unroll
    for (int i = 0; i < 6; i++) {
        const int d = threadIdx.x + 256 * i;
        hi[s * D_ + d] = f2bf((v[i] - mean) * rs * (g[d] + (float)ADD1) + b[d]);
    }
}

__global__ __launch_bounds__(256) void rms_kernel(float* __restrict__ x,
                                                  const float* __restrict__ w)
{
    __shared__ float red[4];
    const size_t s = blockIdx.x;
    float* xr = x + s * D_;
    float v[6];
    float ss = 0.f;
#pragma unroll
    for (int i = 0; i < 6; i++) { v[i] = xr[threadIdx.x + 256 * i]; ss += v[i] * v[i]; }
    ss = block_sum_256(ss, red);
    const float rs = rsqrtf(ss * (1.f / D_) + EPS_);
#pragma unroll
    for (int i = 0; i < 6; i++) {
        const int d = threadIdx.x + 256 * i;
        xr[d] = v[i] * rs * w[d];
    }
}

// ------------- fused RMS + RoPE for bf16 Q and K (in-place) ----------------
__global__ __launch_bounds__(256) void rmsrope_qk_bf16(
    short* __restrict__ Q, short* __restrict__ K,
    const float* __restrict__ nqw, const float* __restrict__ nkw,
    const float* __restrict__ cosT, const float* __restrict__ sinT)
{
    __shared__ float red[4];
    const size_t s = blockIdx.x;
    const int tid = threadIdx.x;

#pragma unroll
    for (int m = 0; m < 2; m++) {
        short* X = m ? K : Q;
        const float* w = m ? nkw : nqw;
        float v1[3], v2[3];
        float ss = 0.f;
#pragma unroll
        for (int j = 0; j < 3; j++) {
            const short2 p2 = *(const short2*)(X + s * D_ + 2 * (tid + 256 * j));
            v1[j] = bf2f(p2.x); v2[j] = bf2f(p2.y);
            ss += v1[j] * v1[j] + v2[j] * v2[j];
        }
        ss = block_sum_256(ss, red);
        const float rs = rsqrtf(ss * (1.f / D_) + EPS_);
#pragma unroll
        for (int j = 0; j < 3; j++) {
            const int p = tid + 256 * j;
            const int i = p & 63;
            const float c = cosT[s * 64 + i], sn = sinT[s * 64 + i];
            const float x1 = v1[j] * rs * w[2 * p];
            const float x2 = v2[j] * rs * w[2 * p + 1];
            short2 o;
            o.x = f2bf(x1 * c - x2 * sn);
            o.y = f2bf(x2 * c + x1 * sn);
            *(short2*)(X + s * D_ + 2 * p) = o;
        }
    }
}

// --------------------------- elementwise -----------------------------------
__global__ void add_kernel(const float* __restrict__ a, const float* __restrict__ b,
                           float* __restrict__ o, int n)
{
    const int i = blockIdx.x * 256 + threadIdx.x;
    if (i < n) o[i] = a[i] + b[i];
}

// ------------------------- VSA coarse path ---------------------------------
__global__ __launch_bounds__(128) void blockmean_bf16(const short* __restrict__ q,
                                                      float* __restrict__ qc)
{
    const int hb = blockIdx.x;
    const int h = hb >> 6, j = hb & 63;
    const int d = threadIdx.x;
    float sum = 0.f;
    for (int t = 0; t < 64; t++)
        sum += bf2f(q[(size_t)(j * 64 + t) * D_ + h * 128 + d]);
    qc[(size_t)hb * 128 + d] = sum * (1.f / 64.f);
}

__global__ __launch_bounds__(64) void coarse_kernel(
    const float* __restrict__ qc, const float* __restrict__ kc,
    const float* __restrict__ vc, float* __restrict__ oc, int* __restrict__ idxout)
{
    const int hb = blockIdx.x;
    const int h = hb >> 6, i = hb & 63;
    const int lane = threadIdx.x;
    __shared__ float p[64];

    const float* qv = qc + (size_t)hb * 128;
    const float* kv = kc + (size_t)((h << 6) + lane) * 128;
    float sc = 0.f;
    for (int d = 0; d < 128; d++) sc = fmaf(qv[d], kv[d], sc);
    sc *= SCALE_;

    float mx = sc;
#pragma unroll
    for (int off = 32; off > 0; off >>= 1) mx = fmaxf(mx, __shfl_xor(mx, off, 64));
    const float e = expf(sc - mx);
    float sumv = e;
#pragma unroll
    for (int off = 32; off > 0; off >>= 1) sumv += __shfl_xor(sumv, off, 64);
    const float pv = e / sumv;
    p[lane] = pv;
    __syncthreads();

    float o0 = 0.f, o1 = 0.f;
    for (int j = 0; j < 64; j++) {
        const float pj = p[j];
        const float* vr = vc + (size_t)((h << 6) + j) * 128;
        o0 = fmaf(pj, vr[lane], o0);
        o1 = fmaf(pj, vr[lane + 64], o1);
    }
    oc[(size_t)hb * 128 + lane]      = o0;
    oc[(size_t)hb * 128 + lane + 64] = o1;

    float v = pv;
    for (int t = 0; t < TOPK; t++) {
        float bv = v; int bi = lane;
#pragma unroll
        for (int off = 32; off > 0; off >>= 1) {
            const float ov = __shfl_xor(bv, off, 64);
            const int   oi = __shfl_xor(bi, off, 64);
            if (ov > bv || (ov == bv && oi < bi)) { bv = ov; bi = oi; }
        }
        if (lane == 0) idxout[hb * TOPK + t] = bi;
        if (lane == bi) v = -1.f;
    }
}

// ---------------------- MFMA flash attention -------------------------------
// MODE 0: fine VSA — Q,K,V bf16 (Qb,Kb,Vb), epilogue += oc*g.
// MODE 1: cross-attn — Q,K,V f32 (Q_, CK_, CV_).
template <int MODE>
__global__ __launch_bounds__(256) void attn_mfma(
    const short* __restrict__ Qb, const short* __restrict__ Kb,
    const short* __restrict__ Vbb,
    const float* __restrict__ Qf, const float* __restrict__ Kf,
    const float* __restrict__ Vff,
    const short* __restrict__ Gb, const float* __restrict__ ocp,
    const int* __restrict__ idxp, short* __restrict__ Ob)
{
    const int hb = blockIdx.x, h = hb >> 6, ib = hb & 63;
    const int tid = threadIdx.x, wid = tid >> 6, lane = tid & 63;
    const int g16 = lane >> 4, l15 = lane & 15;

    __shared__ __align__(16) short Ks[64 * 128];
    __shared__ __align__(16) short Vst[128 * 64];
    __shared__ __align__(16) short Ps[64 * 80];
    __shared__ int sel[8];
    if (tid < 8) sel[tid] = (MODE == 0) ? idxp[hb * 8 + tid] : tid;

    short8 qa[4];
    if (MODE == 0) {
        const short* qrow = Qb + (size_t)(ib * 64 + wid * 16 + l15) * D_ + h * 128;
#pragma unroll
        for (int kk = 0; kk < 4; kk++)
            qa[kk] = *(const short8*)(qrow + kk * 32 + g16 * 8);
    } else {
        const float* qrow = Qf + (size_t)(ib * 64 + wid * 16 + l15) * D_ + h * 128;
#pragma unroll
        for (int kk = 0; kk < 4; kk++) {
            const float4 f0 = *(const float4*)(qrow + kk * 32 + g16 * 8);
            const float4 f1 = *(const float4*)(qrow + kk * 32 + g16 * 8 + 4);
            short8 v;
            v[0] = f2bf(f0.x); v[1] = f2bf(f0.y); v[2] = f2bf(f0.z); v[3] = f2bf(f0.w);
            v[4] = f2bf(f1.x); v[5] = f2bf(f1.y); v[6] = f2bf(f1.z); v[7] = f2bf(f1.w);
            qa[kk] = v;
        }
    }

    f32x4 o[8];
#pragma unroll
    for (int n2 = 0; n2 < 8; n2++) o[n2] = (f32x4){0.f, 0.f, 0.f, 0.f};
    float mrow[4] = {-3e38f, -3e38f, -3e38f, -3e38f};
    float lrow[4] = {0.f, 0.f, 0.f, 0.f};
    __syncthreads();

    for (int t = 0; t < 8; t++) {
        const int jb = sel[t];
        // stage K tile (swizzled); MODE0 pure bf16 copy, MODE1 cvt from f32
#pragma unroll
        for (int it = 0; it < 4; it++) {
            const int c = tid + 256 * it;
            const int key = c >> 4, u16 = c & 15;
            const int byte = (key * 256 + u16 * 16) ^ ((key & 7) << 4);
            if (MODE == 0) {
                *(short8*)((char*)Ks + byte) =
                    *(const short8*)(Kb + (size_t)(jb * 64 + key) * D_ + h * 128 + u16 * 8);
            } else {
                const float* src = Kf + (size_t)(jb * 64 + key) * D_ + h * 128 + u16 * 8;
                const float4 f0 = *(const float4*)src;
                const float4 f1 = *(const float4*)(src + 4);
                short8 v;
                v[0] = f2bf(f0.x); v[1] = f2bf(f0.y); v[2] = f2bf(f0.z); v[3] = f2bf(f0.w);
                v[4] = f2bf(f1.x); v[5] = f2bf(f1.y); v[6] = f2bf(f1.z); v[7] = f2bf(f1.w);
                *(short8*)((char*)Ks + byte) = v;
            }
        }
        // stage V transposed (swizzled)
#pragma unroll
        for (int it = 0; it < 4; it++) {
            const int c = tid + 256 * it;
            const int key = c & 63, d8 = (c >> 6) * 8;
            float vv[8];
            if (MODE == 0) {
                const short8 v = *(const short8*)(Vbb + (size_t)(jb * 64 + key) * D_ + h * 128 + d8);
#pragma unroll
                for (int j = 0; j < 8; j++) vv[j] = bf2f(v[j]);
            } else {
                const float* src = Vff + (size_t)(jb * 64 + key) * D_ + h * 128 + d8;
                const float4 f0 = *(const float4*)src;
                const float4 f1 = *(const float4*)(src + 4);
                vv[0] = f0.x; vv[1] = f0.y; vv[2] = f0.z; vv[3] = f0.w;
                vv[4] = f1.x; vv[5] = f1.y; vv[6] = f1.z; vv[7] = f1.w;
            }
#pragma unroll
            for (int j = 0; j < 8; j++) {
                const int dim = d8 + j;
                const int byte = (dim * 128 + key * 2) ^ ((dim & 7) << 4);
                *(short*)((char*)Vst + byte) = f2bf(vv[j]);
            }
        }
        __syncthreads();

        f32x4 s[4];
#pragma unroll
        for (int nt = 0; nt < 4; nt++) {
            f32x4 acc = (f32x4){0.f, 0.f, 0.f, 0.f};
            const int key = nt * 16 + l15;
#pragma unroll
            for (int kk = 0; kk < 4; kk++) {
                const int byte = (key * 256 + (kk * 32 + g16 * 8) * 2) ^ ((key & 7) << 4);
                const short8 b = *(const short8*)((char*)Ks + byte);
                acc = __builtin_amdgcn_mfma_f32_16x16x32_bf16(qa[kk], b, acc, 0, 0, 0);
            }
            s[nt] = acc;
        }
#pragma unroll
        for (int nt = 0; nt < 4; nt++)
#pragma unroll
            for (int rr = 0; rr < 4; rr++) s[nt][rr] *= SCALE_;

        float alpha[4];
#pragma unroll
        for (int rr = 0; rr < 4; rr++) {
            float v = fmaxf(fmaxf(s[0][rr], s[1][rr]), fmaxf(s[2][rr], s[3][rr]));
            v = fmaxf(v, __shfl_xor(v, 1, 64));
            v = fmaxf(v, __shfl_xor(v, 2, 64));
            v = fmaxf(v, __shfl_xor(v, 4, 64));
            v = fmaxf(v, __shfl_xor(v, 8, 64));
            const float mn = fmaxf(mrow[rr], v);
            alpha[rr] = expf(mrow[rr] - mn);
            mrow[rr] = mn;
        }
        float rs[4] = {0.f, 0.f, 0.f, 0.f};
#pragma unroll
        for (int nt = 0; nt < 4; nt++)
#pragma unroll
            for (int rr = 0; rr < 4; rr++) {
                const float p = expf(s[nt][rr] - mrow[rr]);
                s[nt][rr] = p;
                rs[rr] += p;
            }
#pragma unroll
        for (int rr = 0; rr < 4; rr++) {
            float v = rs[rr];
            v += __shfl_xor(v, 1, 64);
            v += __shfl_xor(v, 2, 64);
            v += __shfl_xor(v, 4, 64);
            v += __shfl_xor(v, 8, 64);
            lrow[rr] = lrow[rr] * alpha[rr] + v;
        }
#pragma unroll
        for (int n2 = 0; n2 < 8; n2++)
#pragma unroll
            for (int rr = 0; rr < 4; rr++) o[n2][rr] *= alpha[rr];

#pragma unroll
        for (int nt = 0; nt < 4; nt++)
#pragma unroll
            for (int rr = 0; rr < 4; rr++)
                Ps[(wid * 16 + g16 * 4 + rr) * 80 + nt * 16 + l15] = f2bf(s[nt][rr]);

#pragma unroll
        for (int kk2 = 0; kk2 < 2; kk2++) {
            const short8 pa = *(const short8*)(Ps + (wid * 16 + l15) * 80 + kk2 * 32 + g16 * 8);
#pragma unroll
            for (int n2 = 0; n2 < 8; n2++) {
                const int dim = n2 * 16 + l15;
                const int byte = (dim * 128 + (kk2 * 32 + g16 * 8) * 2) ^ ((dim & 7) << 4);
                const short8 vb = *(const short8*)((char*)Vst + byte);
                o[n2] = __builtin_amdgcn_mfma_f32_16x16x32_bf16(pa, vb, o[n2], 0, 0, 0);
            }
        }
        __syncthreads();
    }

#pragma unroll
    for (int n2 = 0; n2 < 8; n2++) {
        const int col = n2 * 16 + l15;
        const float ocv = (MODE == 0) ? ocp[(size_t)hb * 128 + col] : 0.f;
#pragma unroll
        for (int rr = 0; rr < 4; rr++) {
            const int row = ib * 64 + wid * 16 + g16 * 4 + rr;
            float val = o[n2][rr] / lrow[rr];
            if (MODE == 0)
                val += ocv * bf2f(Gb[(size_t)row * D_ + h * 128 + col]);
            Ob[(size_t)row * D_ + h * 128 + col] = f2bf(val);
        }
    }
}

// ---------------------------------------------------------------------------
extern "C" void kernel_launch(void* const* d_in, const int* in_sizes, int n_in,
                              void* d_out, int out_size, void* d_ws, size_t ws_size,
                              hipStream_t stream)
{
    const float* h_in = (const float*)d_in[0];
    const float* enc  = (const float*)d_in[1];
    const float* temb = (const float*)d_in[2];
    const float* cosT = (const float*)d_in[3];
    const float* sinT = (const float*)d_in[4];
    const float* sst  = (const float*)d_in[5];
    const float* Wq = (const float*)d_in[6];   const float* bq = (const float*)d_in[7];
    const float* Wk = (const float*)d_in[8];   const float* bk = (const float*)d_in[9];
    const float* Wv = (const float*)d_in[10];  const float* bv = (const float*)d_in[11];
    const float* Wg = (const float*)d_in[12];  const float* bg = (const float*)d_in[13];
    const float* Wo = (const float*)d_in[14];  const float* bo = (const float*)d_in[15];
    const float* nq_w  = (const float*)d_in[16];
    const float* nk_w  = (const float*)d_in[17];
    const float* ln1_w = (const float*)d_in[18];
    const float* ln1_b = (const float*)d_in[19];
    const float* cWq = (const float*)d_in[20]; const float* cbq = (const float*)d_in[21];
    const float* cWk = (const float*)d_in[22]; const float* cbk = (const float*)d_in[23];
    const float* cWv = (const float*)d_in[24]; const float* cbv = (const float*)d_in[25];
    const float* cWo = (const float*)d_in[26]; const float* cbo = (const float*)d_in[27];
    const float* cnq_w = (const float*)d_in[28];
    const float* cnk_w = (const float*)d_in[29];
    const float* W1 = (const float*)d_in[30];  const float* b1 = (const float*)d_in[31];
    const float* W2 = (const float*)d_in[32];  const float* b2 = (const float*)d_in[33];
    float* out = (float*)d_out;

    char* base = (char*)d_ws;
    size_t off = 0;
    auto alloc = [&](size_t bytes) {
        char* p = base + off;
        off += (bytes + 255) & ~(size_t)255;
        return p;
    };
    const size_t SD = (size_t)S_ * D_;
    float* e_   = (float*)alloc(6 * D_ * 4);
    float* Q_   = (float*)alloc(SD * 4);       // cq (cross path)
    float* K_   = (float*)alloc(SD * 4);       // resid1/resid2
    float* CK_  = (float*)alloc((size_t)L_ * D_ * 4);
    float* CV_  = (float*)alloc((size_t)L_ * D_ * 4);
    float* qc_  = (float*)alloc((size_t)H_ * 64 * 128 * 4);
    float* kc_  = (float*)alloc((size_t)H_ * 64 * 128 * 4);
    float* vc_  = (float*)alloc((size_t)H_ * 64 * 128 * 4);
    float* oc_  = (float*)alloc((size_t)H_ * 64 * 128 * 4);
    int*   idx_ = (int*)alloc((size_t)H_ * 64 * TOPK * 4);
    short* Nb   = (short*)alloc(SD * 2);       // live during W1 (norm3)
    // ---- FFC alias region: QKVGb .. Wgt (~83 MB, all dead by FFN) ----
    short* QKVGb = (short*)alloc(4 * SD * 2);  // q|k|v|g bf16, seg stride SD
    short* attn_b = (short*)alloc(SD * 2);
    short* enc_b  = (short*)alloc((size_t)L_ * D_ * 2);
    const size_t WDD = (size_t)D_ * D_;
    short* Wqt = (short*)alloc(WDD * 2);       // Wqt,Wkt,Wvt,Wgt contiguous
    short* Wkt = (short*)alloc(WDD * 2);
    short* Wvt = (short*)alloc(WDD * 2);
    short* Wgt = (short*)alloc(WDD * 2);
    // ---- end alias region ----
    short* Wot = (short*)alloc(WDD * 2);
    short* cWqt = (short*)alloc(WDD * 2); short* cWkt = (short*)alloc(WDD * 2);
    short* cWvt = (short*)alloc(WDD * 2); short* cWot = (short*)alloc(WDD * 2);
    short* W1t = (short*)alloc((size_t)D_ * FF_ * 2);
    short* W2t = (short*)alloc((size_t)D_ * FF_ * 2);
    float* bcat = (float*)alloc(6144 * 4);
    short* FFC = QKVGb;   // S x FF bf16 (73.4 MB) over dead region (~83 MB)
    short* Qb = QKVGb;
    short* Kb = QKVGb + SD;
    short* Vb = QKVGb + 2 * SD;
    short* Gb = QKVGb + 3 * SD;

    const dim3 b256(256);
    const dim3 gDD(D_ / 64, D_ / 64);
    const dim3 gN1536(D_ / 64, S_ / 128);      // 24 x 32 = 768 blocks

    add_kernel<<<dim3((6 * D_ + 255) / 256), b256, 0, stream>>>(sst, temb, e_, 6 * D_);
    ln_bf16<1><<<dim3(S_), b256, 0, stream>>>(h_in, Nb, e_ + D_, e_);
    fill_bcat<<<dim3(24), b256, 0, stream>>>(bq, bk, bv, bg, bcat);

    transpose_w<<<gDD, b256, 0, stream>>>(Wq, Wqt, D_, D_);
    transpose_w<<<gDD, b256, 0, stream>>>(Wk, Wkt, D_, D_);
    transpose_w<<<gDD, b256, 0, stream>>>(Wv, Wvt, D_, D_);
    transpose_w<<<gDD, b256, 0, stream>>>(Wg, Wgt, D_, D_);
    transpose_w<<<gDD, b256, 0, stream>>>(Wo, Wot, D_, D_);
    transpose_w<<<gDD, b256, 0, stream>>>(cWq, cWqt, D_, D_);
    transpose_w<<<gDD, b256, 0, stream>>>(cWk, cWkt, D_, D_);
    transpose_w<<<gDD, b256, 0, stream>>>(cWv, cWvt, D_, D_);
    transpose_w<<<gDD, b256, 0, stream>>>(cWo, cWot, D_, D_);
    transpose_w<<<dim3(FF_ / 64, D_ / 64), b256, 0, stream>>>(W1, W1t, D_, FF_);
    transpose_w<<<dim3(D_ / 64, FF_ / 64), b256, 0, stream>>>(W2, W2t, FF_, D_);
    cvt_bf16_kernel<<<dim3((L_ * D_ / 4 + 255) / 256), b256, 0, stream>>>(enc, enc_b, L_ * D_ / 4);

    // fused QKVG projection -> QKVGb (all bf16)
    gemm14<4><<<dim3(6144 / 64, S_ / 128), b256, 0, stream>>>(
        Nb, Wqt, bcat, nullptr, QKVGb, S_, 6144, D_, nullptr, nullptr);

    // fused rms + rope for q,k (bf16 in-place)
    rmsrope_qk_bf16<<<dim3(S_), b256, 0, stream>>>(Qb, Kb, nq_w, nk_w, cosT, sinT);

    blockmean_bf16<<<dim3(H_ * 64), dim3(128), 0, stream>>>(Qb, qc_);
    blockmean_bf16<<<dim3(H_ * 64), dim3(128), 0, stream>>>(Kb, kc_);
    blockmean_bf16<<<dim3(H_ * 64), dim3(128), 0, stream>>>(Vb, vc_);
    coarse_kernel<<<dim3(H_ * 64), dim3(64), 0, stream>>>(qc_, kc_, vc_, oc_, idx_);

    attn_mfma<0><<<dim3(H_ * 64), b256, 0, stream>>>(
        Qb, Kb, Vb, nullptr, nullptr, nullptr, Gb, oc_, idx_, attn_b);

    // Wo fused with resid-gate: K_ = h_in + (attn@Wo + bo) * gate
    gemm14<6><<<gN1536, b256, 0, stream>>>(attn_b, Wot, bo, K_, nullptr, S_, D_, D_,
                                           h_in, e_ + 2 * D_);

    ln_bf16<0><<<dim3(S_), b256, 0, stream>>>(K_, Nb, ln1_w, ln1_b);
    gemm14<0><<<gN1536, b256, 0, stream>>>(Nb, cWqt, cbq, Q_, nullptr, S_, D_, D_,
                                           nullptr, nullptr);
    rms_kernel<<<dim3(S_), b256, 0, stream>>>(Q_, cnq_w);

    const dim3 gLenc(D_ / 64, L_ / 128);
    gemm14<0><<<gLenc, b256, 0, stream>>>(enc_b, cWkt, cbk, CK_, nullptr, L_, D_, D_,
                                          nullptr, nullptr);
    rms_kernel<<<dim3(L_), b256, 0, stream>>>(CK_, cnk_w);
    gemm14<0><<<gLenc, b256, 0, stream>>>(enc_b, cWvt, cbv, CV_, nullptr, L_, D_, D_,
                                          nullptr, nullptr);

    attn_mfma<1><<<dim3(H_ * 64), b256, 0, stream>>>(
        nullptr, nullptr, nullptr, Q_, CK_, CV_, nullptr, nullptr, nullptr, attn_b);

    // cWo fused with residual: K_ += cout@cWo + cbo
    gemm14<7><<<gN1536, b256, 0, stream>>>(attn_b, cWot, cbo, K_, nullptr, S_, D_, D_,
                                           nullptr, nullptr);

    // norm3 -> Nb ; FFN: W1(gelu->FFC bf16) ; W2 fused with final resid-gate
    ln_bf16<1><<<dim3(S_), b256, 0, stream>>>(K_, Nb, e_ + 4 * D_, e_ + 3 * D_);
    gemm14<2><<<dim3(FF_ / 64, S_ / 128), b256, 0, stream>>>(
        Nb, W1t, b1, nullptr, FFC, S_, FF_, D_, nullptr, nullptr);
    gemm14<6><<<gN1536, b256, 0, stream>>>(FFC, W2t, b2, out, nullptr, S_, D_, FF_,
                                           K_, e_ + 5 * D_);
}